// Round 1
// baseline (8641.179 us; speedup 1.0000x reference)
//
#include <hip/hip_runtime.h>

#define HDIM 224
#define WDIM 224
#define PPIX 50176      // 224*224
#define BATCH 8
#define NPIX 401408     // 8*50176
#define KTOP 15052      // max(int(0.3*224*224), 64)
#define NELEM 25690112  // 8*64*50176

// ---------------- prep: tiny derived coefficients + zero stats ----------------
__global__ __launch_bounds__(256) void prep_kernel(
    const float* __restrict__ w_in, const float* __restrict__ b_in,
    const float* __restrict__ imp_w1, const float* __restrict__ imp_b1,
    const float* __restrict__ fin_w, const float* __restrict__ fin_b,
    float* __restrict__ coeffs, float* __restrict__ stats)
{
    int t = threadIdx.x;
    if (t < 16) {
        float a = 0.f, d = 0.f;
        for (int c = 0; c < 64; c++) {
            a += imp_w1[t * 64 + c] * w_in[64 + c];
            d += imp_w1[t * 64 + c] * b_in[64 + c];
        }
        coeffs[t] = a;
        coeffs[16 + t] = d + imp_b1[t];
    }
    if (t < 64) {
        float a = 0.f, d = 0.f;
        for (int c = 0; c < 64; c++) {
            a += fin_w[t * 64 + c] * w_in[c];
            d += fin_w[t * 64 + c] * b_in[c];
        }
        coeffs[32 + t] = a;
        coeffs[96 + t] = d + fin_b[t];
    }
    for (int i = t; i < 384; i += 256) stats[i] = 0.f;
}

// ---------------- importance map: sigmoid(conv3x3(relu(x*a+d), w2)+b2) --------
__global__ __launch_bounds__(256) void imp_kernel(
    const float* __restrict__ x, const float* __restrict__ coeffs,
    const float* __restrict__ imp_w2, const float* __restrict__ imp_b2,
    float* __restrict__ imp)
{
    int idx = blockIdx.x * 256 + threadIdx.x;
    int b = idx / PPIX, p = idx % PPIX;
    int h = p / WDIM, w = p % WDIM;
    float acc = imp_b2[0];
    for (int ky = 0; ky < 3; ky++) {
        int hh = h + ky - 1;
        if (hh < 0 || hh >= HDIM) continue;
        for (int kx = 0; kx < 3; kx++) {
            int ww = w + kx - 1;
            if (ww < 0 || ww >= WDIM) continue;
            float xv = x[b * PPIX + hh * WDIM + ww];
            #pragma unroll
            for (int c = 0; c < 16; c++) {
                float r = fmaxf(xv * coeffs[c] + coeffs[16 + c], 0.f);
                acc += r * imp_w2[c * 9 + ky * 3 + kx];
            }
        }
    }
    imp[idx] = 1.f / (1.f + expf(-acc));
}

// ---------------- exact top-k -> binary mask (one block per batch) ------------
__global__ __launch_bounds__(256) void topk_kernel(
    const float* __restrict__ imp, float* __restrict__ mask)
{
    int b = blockIdx.x;
    const float* v = imp + b * PPIX;
    float* m = mask + b * PPIX;
    int t = threadIdx.x;
    __shared__ unsigned int hist[256];
    __shared__ unsigned int sh_prefix;
    __shared__ int sh_rem;
    __shared__ int wtot[4];

    unsigned int prefix = 0u;
    int remaining = KTOP;
    for (int pass = 0; pass < 4; pass++) {
        int shift = 24 - 8 * pass;
        hist[t] = 0u;
        __syncthreads();
        unsigned int himask = (pass == 0) ? 0u : (0xFFFFFFFFu << (shift + 8));
        for (int i = t; i < PPIX; i += 256) {
            unsigned int bits = __float_as_uint(v[i]);
            if ((bits & himask) == prefix)
                atomicAdd(&hist[(bits >> shift) & 255u], 1u);
        }
        __syncthreads();
        if (t == 0) {
            int rem = remaining;
            unsigned int bsel = 0u;
            for (int bin = 255; bin >= 0; bin--) {
                int c = (int)hist[bin];
                if (c >= rem) { bsel = (unsigned int)bin; break; }
                rem -= c;
            }
            sh_rem = rem;
            sh_prefix = prefix | (bsel << shift);
        }
        __syncthreads();
        prefix = sh_prefix;
        remaining = sh_rem;
        __syncthreads();
    }
    // prefix == bit pattern of k-th largest value T; remaining = #ties(==T) to keep
    unsigned int T = prefix;
    int base = 0;
    int lane = t & 63, wv = t >> 6;
    for (int i0 = 0; i0 < PPIX; i0 += 256) {
        int i = i0 + t; // PPIX % 256 == 0
        unsigned int bits = __float_as_uint(v[i]);
        int flag = (bits == T) ? 1 : 0;
        unsigned long long bal = __ballot(flag);
        if (lane == 0) wtot[wv] = __popcll(bal);
        __syncthreads();
        int wbase = 0, tot = 0;
        for (int q = 0; q < 4; q++) { int c = wtot[q]; if (q < wv) wbase += c; tot += c; }
        int excl = wbase + __popcll(bal & ((1ull << lane) - 1ull));
        float mout = 0.f;
        if (bits > T) mout = 1.f;
        else if (flag && (base + excl) < remaining) mout = 1.f;
        m[i] = mout;
        base += tot;
        __syncthreads();
    }
}

// ---------------- level: dwconv -> 1x1 conv, emit y + bn stats ----------------
__global__ __launch_bounds__(256) void level_kernel(
    const float* __restrict__ x, const float* __restrict__ mask,
    const float* __restrict__ w_in, const float* __restrict__ b_in,
    const float* __restrict__ prev_y, const float* __restrict__ bnp_prev,
    const float* __restrict__ dw_w, const float* __restrict__ pw_w,
    const float* __restrict__ pw_b,
    float* __restrict__ y_out, float* __restrict__ stats,
    int ksz, int dil, int level)
{
    __shared__ float D[64][64];
    __shared__ float sPW[4096];
    int t = threadIdx.x;
    int blk = blockIdx.x;
    int b = blk / 784;
    int lane = t & 63, og = t >> 6;
    int p = (blk % 784) * 64 + lane;
    int h = p / WDIM, w = p % WDIM;
    for (int i = t; i < 4096; i += 256) sPW[i] = pw_w[i];

    int pad = (ksz / 2) * dil;
    for (int j = 0; j < 16; j++) {
        int c = og * 16 + j;
        const float* dwr = dw_w + c * ksz * ksz;
        float wk = 0.f, bk = 0.f, sc = 0.f, sh = 0.f;
        if (level == 0) { wk = w_in[64 + c]; bk = b_in[64 + c]; }
        else { sc = bnp_prev[c]; sh = bnp_prev[64 + c]; }
        float acc = 0.f;
        for (int ky = 0; ky < ksz; ky++) {
            int hh = h + ky * dil - pad;
            if (hh < 0 || hh >= HDIM) continue;
            for (int kx = 0; kx < ksz; kx++) {
                int ww = w + kx * dil - pad;
                if (ww < 0 || ww >= WDIM) continue;
                int pp = hh * WDIM + ww;
                float in;
                if (level == 0) {
                    in = mask[b * PPIX + pp] * (x[b * PPIX + pp] * wk + bk);
                } else {
                    in = fmaxf(sc * prev_y[(b * 64 + c) * PPIX + pp] + sh, 0.f);
                }
                acc += in * dwr[ky * ksz + kx];
            }
        }
        D[c][lane] = acc;
    }
    __syncthreads();

    float d[64];
    #pragma unroll
    for (int c = 0; c < 64; c++) d[c] = D[c][lane];

    for (int j = 0; j < 16; j++) {
        int o = og * 16 + j;
        float acc = pw_b[o];
        #pragma unroll
        for (int c = 0; c < 64; c++) acc += sPW[o * 64 + c] * d[c];
        y_out[(b * 64 + o) * PPIX + p] = acc;
        float s = acc, s2 = acc * acc;
        #pragma unroll
        for (int off = 32; off > 0; off >>= 1) {
            s += __shfl_down(s, off);
            s2 += __shfl_down(s2, off);
        }
        if (lane == 0) {
            atomicAdd(&stats[o * 2], s);
            atomicAdd(&stats[o * 2 + 1], s2);
        }
    }
}

// ---------------- bn finalize: scale/shift per channel -----------------------
__global__ void bnfin_kernel(const float* __restrict__ stats,
                             const float* __restrict__ g, const float* __restrict__ be,
                             float* __restrict__ bnp)
{
    int c = threadIdx.x;
    if (c >= 64) return;
    const float inv_n = 1.f / (float)NPIX;
    float mu = stats[c * 2] * inv_n;
    float var = stats[c * 2 + 1] * inv_n - mu * mu;
    float sc = g[c] * rsqrtf(var + 1e-5f);
    bnp[c] = sc;
    bnp[64 + c] = be[c] - mu * sc;
}

// ---------------- K_global: per (b,c) spatial mean of relu(bn(y2)) ------------
__global__ __launch_bounds__(256) void kglobal_kernel(
    const float* __restrict__ y2, const float* __restrict__ bnp2,
    float* __restrict__ kg)
{
    int bc = blockIdx.x; // 0..511
    int c = bc & 63;
    int t = threadIdx.x;
    const float* row = y2 + (size_t)bc * PPIX;
    float sc = bnp2[c], sh = bnp2[64 + c];
    float s = 0.f;
    for (int i = t; i < PPIX; i += 256) s += fmaxf(sc * row[i] + sh, 0.f);
    #pragma unroll
    for (int off = 32; off > 0; off >>= 1) s += __shfl_down(s, off);
    __shared__ float wsum[4];
    int lane = t & 63, wv = t >> 6;
    if (lane == 0) wsum[wv] = s;
    __syncthreads();
    if (t == 0) kg[bc] = (wsum[0] + wsum[1] + wsum[2] + wsum[3]) * (1.f / (float)PPIX);
}

// ---------------- final: aggregate + V + QV + out + x_proj --------------------
__global__ __launch_bounds__(256) void final_kernel(
    const float* __restrict__ x, const float* __restrict__ w_in,
    const float* __restrict__ b_in,
    const float* __restrict__ y0, const float* __restrict__ y1,
    const float* __restrict__ y2,
    const float* __restrict__ bnp, const float* __restrict__ kg,
    const float* __restrict__ val_w, const float* __restrict__ val_b,
    const float* __restrict__ out_w, const float* __restrict__ out_b,
    const float* __restrict__ coeffs, float* __restrict__ out)
{
    __shared__ float KF[64][64];
    __shared__ float sVW[4096];
    __shared__ float sOW[4096];
    int t = threadIdx.x;
    int blk = blockIdx.x;
    int b = blk / 784;
    int lane = t & 63, og = t >> 6;
    int p = (blk % 784) * 64 + lane;
    for (int i = t; i < 4096; i += 256) { sVW[i] = val_w[i]; sOW[i] = out_w[i]; }

    float xv = x[b * PPIX + p];
    float g0 = xv * w_in[128] + b_in[128];
    float g1 = xv * w_in[129] + b_in[129];
    float g2 = xv * w_in[130] + b_in[130];
    float g3 = xv * w_in[131] + b_in[131];
    float mx = fmaxf(fmaxf(g0, g1), fmaxf(g2, g3));
    float e0 = expf(g0 - mx), e1 = expf(g1 - mx), e2 = expf(g2 - mx), e3 = expf(g3 - mx);
    float inv = 1.f / (e0 + e1 + e2 + e3);
    float G0 = e0 * inv, G1 = e1 * inv, G2 = e2 * inv, G3 = e3 * inv;

    for (int j = 0; j < 16; j++) {
        int c = og * 16 + j;
        size_t idx = (size_t)(b * 64 + c) * PPIX + p;
        float f0 = fmaxf(bnp[c] * y0[idx] + bnp[64 + c], 0.f);
        float f1 = fmaxf(bnp[128 + c] * y1[idx] + bnp[192 + c], 0.f);
        float f2 = fmaxf(bnp[256 + c] * y2[idx] + bnp[320 + c], 0.f);
        KF[c][lane] = G0 * f0 + G1 * f1 + G2 * f2 + G3 * kg[b * 64 + c];
    }
    __syncthreads();

    float kf[64];
    #pragma unroll
    for (int c = 0; c < 64; c++) kf[c] = KF[c][lane];

    float V[16];
    for (int j = 0; j < 16; j++) {
        int o = og * 16 + j;
        float acc = val_b[o];
        #pragma unroll
        for (int c = 0; c < 64; c++) acc += sVW[o * 64 + c] * kf[c];
        V[j] = acc;
    }
    __syncthreads();
    for (int j = 0; j < 16; j++) {
        int o = og * 16 + j;
        float q = xv * w_in[o] + b_in[o];
        KF[o][lane] = q * V[j];
    }
    __syncthreads();

    float tq[64];
    #pragma unroll
    for (int c = 0; c < 64; c++) tq[c] = KF[c][lane];

    for (int j = 0; j < 16; j++) {
        int o = og * 16 + j;
        float acc = out_b[o];
        #pragma unroll
        for (int c = 0; c < 64; c++) acc += sOW[o * 64 + c] * tq[c];
        out[(size_t)(b * 64 + o) * PPIX + p] = acc + xv * coeffs[32 + o] + coeffs[96 + o];
    }
}

extern "C" void kernel_launch(void* const* d_in, const int* in_sizes, int n_in,
                              void* d_out, int out_size, void* d_ws, size_t ws_size,
                              hipStream_t stream)
{
    (void)in_sizes; (void)n_in; (void)out_size; (void)ws_size;
    const float* x      = (const float*)d_in[0];
    const float* w_in   = (const float*)d_in[1];
    const float* b_in   = (const float*)d_in[2];
    const float* dw0    = (const float*)d_in[3];
    const float* pw0_w  = (const float*)d_in[4];
    const float* pw0_b  = (const float*)d_in[5];
    const float* bn0_g  = (const float*)d_in[6];
    const float* bn0_b  = (const float*)d_in[7];
    const float* dw1    = (const float*)d_in[8];
    const float* pw1_w  = (const float*)d_in[9];
    const float* pw1_b  = (const float*)d_in[10];
    const float* bn1_g  = (const float*)d_in[11];
    const float* bn1_b  = (const float*)d_in[12];
    const float* dw2    = (const float*)d_in[13];
    const float* pw2_w  = (const float*)d_in[14];
    const float* pw2_b  = (const float*)d_in[15];
    const float* bn2_g  = (const float*)d_in[16];
    const float* bn2_b  = (const float*)d_in[17];
    const float* imp_w1 = (const float*)d_in[18];
    const float* imp_b1 = (const float*)d_in[19];
    const float* imp_w2 = (const float*)d_in[20];
    const float* imp_b2 = (const float*)d_in[21];
    const float* val_w  = (const float*)d_in[22];
    const float* val_b  = (const float*)d_in[23];
    const float* out_w  = (const float*)d_in[24];
    const float* out_b  = (const float*)d_in[25];
    const float* fin_w  = (const float*)d_in[26];
    const float* fin_b  = (const float*)d_in[27];

    float* ws   = (float*)d_ws;
    float* y0   = ws;
    float* y1   = ws + (size_t)NELEM;
    float* imp  = ws + (size_t)2 * NELEM;
    float* mask = imp + NPIX;
    float* stats = mask + NPIX;   // 3*128
    float* bnp   = stats + 384;   // 3*128
    float* kg    = bnp + 384;     // 512
    float* coeffs = kg + 512;     // 160
    float* y2 = (float*)d_out;

    prep_kernel<<<1, 256, 0, stream>>>(w_in, b_in, imp_w1, imp_b1, fin_w, fin_b, coeffs, stats);
    imp_kernel<<<NPIX / 256, 256, 0, stream>>>(x, coeffs, imp_w2, imp_b2, imp);
    topk_kernel<<<BATCH, 256, 0, stream>>>(imp, mask);

    level_kernel<<<6272, 256, 0, stream>>>(x, mask, w_in, b_in, nullptr, nullptr,
                                           dw0, pw0_w, pw0_b, y0, stats, 3, 1, 0);
    bnfin_kernel<<<1, 64, 0, stream>>>(stats, bn0_g, bn0_b, bnp);
    level_kernel<<<6272, 256, 0, stream>>>(x, mask, w_in, b_in, y0, bnp,
                                           dw1, pw1_w, pw1_b, y1, stats + 128, 5, 2, 1);
    bnfin_kernel<<<1, 64, 0, stream>>>(stats + 128, bn1_g, bn1_b, bnp + 128);
    level_kernel<<<6272, 256, 0, stream>>>(x, mask, w_in, b_in, y1, bnp + 128,
                                           dw2, pw2_w, pw2_b, y2, stats + 256, 7, 4, 2);
    bnfin_kernel<<<1, 64, 0, stream>>>(stats + 256, bn2_g, bn2_b, bnp + 256);

    kglobal_kernel<<<512, 256, 0, stream>>>(y2, bnp + 256, kg);
    final_kernel<<<6272, 256, 0, stream>>>(x, w_in, b_in, y0, y1, y2, bnp, kg,
                                           val_w, val_b, out_w, out_b, coeffs, y2);
}

// Round 2
// 7907.753 us; speedup vs baseline: 1.0927x; 1.0927x over previous
//
#include <hip/hip_runtime.h>

#define HDIM 224
#define WDIM 224
#define PPIX 50176      // 224*224
#define BATCH 8
#define NPIX 401408     // 8*50176
#define KTOP 15052      // max(int(0.3*224*224), 64)
#define NELEM 25690112  // 8*64*50176

// ---------------- prep: tiny derived coefficients + zero stats ----------------
__global__ __launch_bounds__(256) void prep_kernel(
    const float* __restrict__ w_in, const float* __restrict__ b_in,
    const float* __restrict__ imp_w1, const float* __restrict__ imp_b1,
    const float* __restrict__ fin_w, const float* __restrict__ fin_b,
    float* __restrict__ coeffs, float* __restrict__ stats)
{
    int t = threadIdx.x;
    if (t < 16) {
        float a = 0.f, d = 0.f;
        for (int c = 0; c < 64; c++) {
            a += imp_w1[t * 64 + c] * w_in[64 + c];
            d += imp_w1[t * 64 + c] * b_in[64 + c];
        }
        coeffs[t] = a;
        coeffs[16 + t] = d + imp_b1[t];
    }
    if (t < 64) {
        float a = 0.f, d = 0.f;
        for (int c = 0; c < 64; c++) {
            a += fin_w[t * 64 + c] * w_in[c];
            d += fin_w[t * 64 + c] * b_in[c];
        }
        coeffs[32 + t] = a;
        coeffs[96 + t] = d + fin_b[t];
    }
    for (int i = t; i < 384; i += 256) stats[i] = 0.f;
}

// ---------------- importance map: sigmoid(conv3x3(relu(x*a+d), w2)+b2) --------
__global__ __launch_bounds__(256) void imp_kernel(
    const float* __restrict__ x, const float* __restrict__ coeffs,
    const float* __restrict__ imp_w2, const float* __restrict__ imp_b2,
    float* __restrict__ imp)
{
    int idx = blockIdx.x * 256 + threadIdx.x;
    int b = idx / PPIX, p = idx % PPIX;
    int h = p / WDIM, w = p % WDIM;
    float acc = imp_b2[0];
    #pragma unroll
    for (int ky = 0; ky < 3; ky++) {
        int hh = h + ky - 1;
        float okh = (hh >= 0 && hh < HDIM) ? 1.f : 0.f;
        int hc = min(max(hh, 0), HDIM - 1);
        #pragma unroll
        for (int kx = 0; kx < 3; kx++) {
            int ww = w + kx - 1;
            float ok = okh * ((ww >= 0 && ww < WDIM) ? 1.f : 0.f);
            int wc = min(max(ww, 0), WDIM - 1);
            float xv = x[b * PPIX + hc * WDIM + wc] * ok;
            #pragma unroll
            for (int c = 0; c < 16; c++) {
                float r = fmaxf(xv * coeffs[c] + coeffs[16 + c] * ok, 0.f);
                acc += r * imp_w2[c * 9 + ky * 3 + kx];
            }
        }
    }
    imp[idx] = 1.f / (1.f + expf(-acc));
}

// ---------------- exact top-k -> binary mask (one block per batch) ------------
__global__ __launch_bounds__(256) void topk_kernel(
    const float* __restrict__ imp, float* __restrict__ mask)
{
    int b = blockIdx.x;
    const float* v = imp + b * PPIX;
    float* m = mask + b * PPIX;
    int t = threadIdx.x;
    __shared__ unsigned int hist[256];
    __shared__ unsigned int sh_prefix;
    __shared__ int sh_rem;
    __shared__ int wtot[4];

    unsigned int prefix = 0u;
    int remaining = KTOP;
    for (int pass = 0; pass < 4; pass++) {
        int shift = 24 - 8 * pass;
        hist[t] = 0u;
        __syncthreads();
        unsigned int himask = (pass == 0) ? 0u : (0xFFFFFFFFu << (shift + 8));
        for (int i = t; i < PPIX; i += 256) {
            unsigned int bits = __float_as_uint(v[i]);
            if ((bits & himask) == prefix)
                atomicAdd(&hist[(bits >> shift) & 255u], 1u);
        }
        __syncthreads();
        if (t == 0) {
            int rem = remaining;
            unsigned int bsel = 0u;
            for (int bin = 255; bin >= 0; bin--) {
                int c = (int)hist[bin];
                if (c >= rem) { bsel = (unsigned int)bin; break; }
                rem -= c;
            }
            sh_rem = rem;
            sh_prefix = prefix | (bsel << shift);
        }
        __syncthreads();
        prefix = sh_prefix;
        remaining = sh_rem;
        __syncthreads();
    }
    unsigned int T = prefix;
    int base = 0;
    int lane = t & 63, wv = t >> 6;
    for (int i0 = 0; i0 < PPIX; i0 += 256) {
        int i = i0 + t;
        unsigned int bits = __float_as_uint(v[i]);
        int flag = (bits == T) ? 1 : 0;
        unsigned long long bal = __ballot(flag);
        if (lane == 0) wtot[wv] = __popcll(bal);
        __syncthreads();
        int wbase = 0, tot = 0;
        for (int q = 0; q < 4; q++) { int c = wtot[q]; if (q < wv) wbase += c; tot += c; }
        int excl = wbase + __popcll(bal & ((1ull << lane) - 1ull));
        float mout = 0.f;
        if (bits > T) mout = 1.f;
        else if (flag && (base + excl) < remaining) mout = 1.f;
        m[i] = mout;
        base += tot;
        __syncthreads();
    }
}

// ---------------- level: dwconv -> 1x1 conv, emit y + bn stats ----------------
template<int KSZ, int DIL, int LEVEL>
__global__ __launch_bounds__(256, 2) void level_kernel(
    const float* __restrict__ x, const float* __restrict__ mask,
    const float* __restrict__ w_in, const float* __restrict__ b_in,
    const float* __restrict__ prev_y, const float* __restrict__ bnp_prev,
    const float* __restrict__ dw_w, const float* __restrict__ pw_w,
    const float* __restrict__ pw_b,
    float* __restrict__ y_out, float* __restrict__ stats)
{
    constexpr int PAD = (KSZ / 2) * DIL;
    constexpr int NT = KSZ * KSZ;
    __shared__ float D[64][64];
    __shared__ float4 sW[1024];
    int t = threadIdx.x;
    // XCD-chunked swizzle: grid = 8*784; XCD k owns batch image k (halo stays L2-hot)
    int swz = (blockIdx.x & 7) * 784 + (blockIdx.x >> 3);
    int b = swz / 784;
    int lane = t & 63, og = t >> 6;
    int p = (swz % 784) * 64 + lane;
    int h = p / WDIM, w = p % WDIM;
    for (int i = t; i < 1024; i += 256) sW[i] = ((const float4*)pw_w)[i];

    // clamped tap addressing, validity as 0/1 floats (no divergent branches)
    int rowoff[KSZ]; float okhf[KSZ];
    int wcs[KSZ]; float okwf[KSZ];
    #pragma unroll
    for (int k = 0; k < KSZ; k++) {
        int hh = h + k * DIL - PAD;
        okhf[k] = (hh >= 0 && hh < HDIM) ? 1.f : 0.f;
        rowoff[k] = min(max(hh, 0), HDIM - 1) * WDIM;
        int ww = w + k * DIL - PAD;
        okwf[k] = (ww >= 0 && ww < WDIM) ? 1.f : 0.f;
        wcs[k] = min(max(ww, 0), WDIM - 1);
    }

    if constexpr (LEVEL == 0) {
        // in = mask*(x*wk+bk): hoist loads across channels.
        float mv[NT], mxv[NT];
        const float* mb = mask + b * PPIX;
        const float* xb = x + b * PPIX;
        #pragma unroll
        for (int ky = 0; ky < KSZ; ky++) {
            #pragma unroll
            for (int kx = 0; kx < KSZ; kx++) {
                int a = rowoff[ky] + wcs[kx];
                float mm = mb[a] * (okhf[ky] * okwf[kx]);
                mv[ky * KSZ + kx] = mm;
                mxv[ky * KSZ + kx] = mm * xb[a];
            }
        }
        #pragma unroll
        for (int j = 0; j < 16; j++) {
            int c = og * 16 + j;
            float wk = w_in[64 + c], bk = b_in[64 + c];
            const float* dwr = dw_w + c * NT;
            float a0 = 0.f, a1 = 0.f;
            #pragma unroll
            for (int tp = 0; tp < NT; tp++) {
                float dv = dwr[tp];
                a0 += dv * mxv[tp];
                a1 += dv * mv[tp];
            }
            D[c][lane] = wk * a0 + bk * a1;
        }
    } else {
        #pragma unroll 1   // keep code size sane; inner taps fully unrolled -> batched loads
        for (int j = 0; j < 16; j++) {
            int c = og * 16 + j;
            float sc = bnp_prev[c], sh = bnp_prev[64 + c];
            const float* plane = prev_y + (size_t)(b * 64 + c) * PPIX;
            const float* dwr = dw_w + c * NT;
            float acc = 0.f;
            #pragma unroll
            for (int ky = 0; ky < KSZ; ky++) {
                #pragma unroll
                for (int kx = 0; kx < KSZ; kx++) {
                    float v = plane[rowoff[ky] + wcs[kx]];
                    // OOB tap contributes exactly 0 (zero-pad is on relu'd input)
                    float q = fmaxf(sc * v + sh, 0.f) * (okhf[ky] * okwf[kx]);
                    acc += q * dwr[ky * KSZ + kx];
                }
            }
            D[c][lane] = acc;
        }
    }
    __syncthreads();

    float d[64];
    #pragma unroll
    for (int c = 0; c < 64; c++) d[c] = D[c][lane];

    #pragma unroll
    for (int j = 0; j < 16; j++) {
        int o = og * 16 + j;
        float acc = pw_b[o];
        #pragma unroll
        for (int c4 = 0; c4 < 16; c4++) {
            float4 wv = sW[o * 16 + c4];
            acc += wv.x * d[4 * c4] + wv.y * d[4 * c4 + 1]
                 + wv.z * d[4 * c4 + 2] + wv.w * d[4 * c4 + 3];
        }
        y_out[(size_t)(b * 64 + o) * PPIX + p] = acc;
        float s = acc, s2 = acc * acc;
        #pragma unroll
        for (int off = 32; off > 0; off >>= 1) {
            s += __shfl_down(s, off);
            s2 += __shfl_down(s2, off);
        }
        if (lane == 0) {
            atomicAdd(&stats[o * 2], s);
            atomicAdd(&stats[o * 2 + 1], s2);
        }
    }
}

// ---------------- bn finalize: scale/shift per channel -----------------------
__global__ void bnfin_kernel(const float* __restrict__ stats,
                             const float* __restrict__ g, const float* __restrict__ be,
                             float* __restrict__ bnp)
{
    int c = threadIdx.x;
    if (c >= 64) return;
    const float inv_n = 1.f / (float)NPIX;
    float mu = stats[c * 2] * inv_n;
    float var = stats[c * 2 + 1] * inv_n - mu * mu;
    float sc = g[c] * rsqrtf(var + 1e-5f);
    bnp[c] = sc;
    bnp[64 + c] = be[c] - mu * sc;
}

// ---------------- K_global: per (b,c) spatial mean of relu(bn(y2)) ------------
__global__ __launch_bounds__(256) void kglobal_kernel(
    const float* __restrict__ y2, const float* __restrict__ bnp2,
    float* __restrict__ kg)
{
    int bc = blockIdx.x; // 0..511
    int c = bc & 63;
    int t = threadIdx.x;
    const float* row = y2 + (size_t)bc * PPIX;
    float sc = bnp2[c], sh = bnp2[64 + c];
    float s = 0.f;
    for (int i = t; i < PPIX; i += 256) s += fmaxf(sc * row[i] + sh, 0.f);
    #pragma unroll
    for (int off = 32; off > 0; off >>= 1) s += __shfl_down(s, off);
    __shared__ float wsum[4];
    int lane = t & 63, wv = t >> 6;
    if (lane == 0) wsum[wv] = s;
    __syncthreads();
    if (t == 0) kg[bc] = (wsum[0] + wsum[1] + wsum[2] + wsum[3]) * (1.f / (float)PPIX);
}

// ---------------- final: aggregate + V + QV + out + x_proj --------------------
__global__ __launch_bounds__(256, 2) void final_kernel(
    const float* __restrict__ x, const float* __restrict__ w_in,
    const float* __restrict__ b_in,
    const float* __restrict__ y0, const float* __restrict__ y1,
    const float* __restrict__ y2,
    const float* __restrict__ bnp, const float* __restrict__ kg,
    const float* __restrict__ val_w, const float* __restrict__ val_b,
    const float* __restrict__ out_w, const float* __restrict__ out_b,
    const float* __restrict__ coeffs, float* __restrict__ out)
{
    __shared__ float KF[64][64];
    __shared__ float4 sVW[1024];
    __shared__ float4 sOW[1024];
    int t = threadIdx.x;
    int blk = blockIdx.x;
    int b = blk / 784;
    int lane = t & 63, og = t >> 6;
    int p = (blk % 784) * 64 + lane;
    for (int i = t; i < 1024; i += 256) {
        sVW[i] = ((const float4*)val_w)[i];
        sOW[i] = ((const float4*)out_w)[i];
    }

    float xv = x[b * PPIX + p];
    float g0 = xv * w_in[128] + b_in[128];
    float g1 = xv * w_in[129] + b_in[129];
    float g2 = xv * w_in[130] + b_in[130];
    float g3 = xv * w_in[131] + b_in[131];
    float mx = fmaxf(fmaxf(g0, g1), fmaxf(g2, g3));
    float e0 = expf(g0 - mx), e1 = expf(g1 - mx), e2 = expf(g2 - mx), e3 = expf(g3 - mx);
    float inv = 1.f / (e0 + e1 + e2 + e3);
    float G0 = e0 * inv, G1 = e1 * inv, G2 = e2 * inv, G3 = e3 * inv;

    #pragma unroll
    for (int j = 0; j < 16; j++) {
        int c = og * 16 + j;
        size_t idx = (size_t)(b * 64 + c) * PPIX + p;
        float f0 = fmaxf(bnp[c] * y0[idx] + bnp[64 + c], 0.f);
        float f1 = fmaxf(bnp[128 + c] * y1[idx] + bnp[192 + c], 0.f);
        float f2 = fmaxf(bnp[256 + c] * y2[idx] + bnp[320 + c], 0.f);
        KF[c][lane] = G0 * f0 + G1 * f1 + G2 * f2 + G3 * kg[b * 64 + c];
    }
    __syncthreads();

    float kf[64];
    #pragma unroll
    for (int c = 0; c < 64; c++) kf[c] = KF[c][lane];

    float V[16];
    #pragma unroll
    for (int j = 0; j < 16; j++) {
        int o = og * 16 + j;
        float acc = val_b[o];
        #pragma unroll
        for (int c4 = 0; c4 < 16; c4++) {
            float4 wv = sVW[o * 16 + c4];
            acc += wv.x * kf[4 * c4] + wv.y * kf[4 * c4 + 1]
                 + wv.z * kf[4 * c4 + 2] + wv.w * kf[4 * c4 + 3];
        }
        V[j] = acc;
    }
    __syncthreads();
    #pragma unroll
    for (int j = 0; j < 16; j++) {
        int o = og * 16 + j;
        float q = xv * w_in[o] + b_in[o];
        KF[o][lane] = q * V[j];
    }
    __syncthreads();

    float tq[64];
    #pragma unroll
    for (int c = 0; c < 64; c++) tq[c] = KF[c][lane];

    #pragma unroll
    for (int j = 0; j < 16; j++) {
        int o = og * 16 + j;
        float acc = out_b[o];
        #pragma unroll
        for (int c4 = 0; c4 < 16; c4++) {
            float4 wv = sOW[o * 16 + c4];
            acc += wv.x * tq[4 * c4] + wv.y * tq[4 * c4 + 1]
                 + wv.z * tq[4 * c4 + 2] + wv.w * tq[4 * c4 + 3];
        }
        out[(size_t)(b * 64 + o) * PPIX + p] = acc + xv * coeffs[32 + o] + coeffs[96 + o];
    }
}

extern "C" void kernel_launch(void* const* d_in, const int* in_sizes, int n_in,
                              void* d_out, int out_size, void* d_ws, size_t ws_size,
                              hipStream_t stream)
{
    (void)in_sizes; (void)n_in; (void)out_size; (void)ws_size;
    const float* x      = (const float*)d_in[0];
    const float* w_in   = (const float*)d_in[1];
    const float* b_in   = (const float*)d_in[2];
    const float* dw0    = (const float*)d_in[3];
    const float* pw0_w  = (const float*)d_in[4];
    const float* pw0_b  = (const float*)d_in[5];
    const float* bn0_g  = (const float*)d_in[6];
    const float* bn0_b  = (const float*)d_in[7];
    const float* dw1    = (const float*)d_in[8];
    const float* pw1_w  = (const float*)d_in[9];
    const float* pw1_b  = (const float*)d_in[10];
    const float* bn1_g  = (const float*)d_in[11];
    const float* bn1_b  = (const float*)d_in[12];
    const float* dw2    = (const float*)d_in[13];
    const float* pw2_w  = (const float*)d_in[14];
    const float* pw2_b  = (const float*)d_in[15];
    const float* bn2_g  = (const float*)d_in[16];
    const float* bn2_b  = (const float*)d_in[17];
    const float* imp_w1 = (const float*)d_in[18];
    const float* imp_b1 = (const float*)d_in[19];
    const float* imp_w2 = (const float*)d_in[20];
    const float* imp_b2 = (const float*)d_in[21];
    const float* val_w  = (const float*)d_in[22];
    const float* val_b  = (const float*)d_in[23];
    const float* out_w  = (const float*)d_in[24];
    const float* out_b  = (const float*)d_in[25];
    const float* fin_w  = (const float*)d_in[26];
    const float* fin_b  = (const float*)d_in[27];

    float* ws   = (float*)d_ws;
    float* y0   = ws;
    float* y1   = ws + (size_t)NELEM;
    float* imp  = ws + (size_t)2 * NELEM;
    float* mask = imp + NPIX;
    float* stats = mask + NPIX;   // 3*128
    float* bnp   = stats + 384;   // 3*128
    float* kg    = bnp + 384;     // 512
    float* coeffs = kg + 512;     // 160
    float* y2 = (float*)d_out;

    prep_kernel<<<1, 256, 0, stream>>>(w_in, b_in, imp_w1, imp_b1, fin_w, fin_b, coeffs, stats);
    imp_kernel<<<NPIX / 256, 256, 0, stream>>>(x, coeffs, imp_w2, imp_b2, imp);
    topk_kernel<<<BATCH, 256, 0, stream>>>(imp, mask);

    level_kernel<3, 1, 0><<<6272, 256, 0, stream>>>(x, mask, w_in, b_in, nullptr, nullptr,
                                                    dw0, pw0_w, pw0_b, y0, stats);
    bnfin_kernel<<<1, 64, 0, stream>>>(stats, bn0_g, bn0_b, bnp);
    level_kernel<5, 2, 1><<<6272, 256, 0, stream>>>(x, mask, w_in, b_in, y0, bnp,
                                                    dw1, pw1_w, pw1_b, y1, stats + 128);
    bnfin_kernel<<<1, 64, 0, stream>>>(stats + 128, bn1_g, bn1_b, bnp + 128);
    level_kernel<7, 4, 2><<<6272, 256, 0, stream>>>(x, mask, w_in, b_in, y1, bnp + 128,
                                                    dw2, pw2_w, pw2_b, y2, stats + 256);
    bnfin_kernel<<<1, 64, 0, stream>>>(stats + 256, bn2_g, bn2_b, bnp + 256);

    kglobal_kernel<<<512, 256, 0, stream>>>(y2, bnp + 256, kg);
    final_kernel<<<6272, 256, 0, stream>>>(x, w_in, b_in, y0, y1, y2, bnp, kg,
                                           val_w, val_b, out_w, out_b, coeffs, y2);
}

// Round 3
// 2898.094 us; speedup vs baseline: 2.9817x; 2.7286x over previous
//
#include <hip/hip_runtime.h>

#define HDIM 224
#define WDIM 224
#define PPIX 50176      // 224*224
#define BATCH 8
#define NPIX 401408     // 8*50176
#define KTOP 15052      // max(int(0.3*224*224), 64)
#define NELEM 25690112  // 8*64*50176
#define NBLK 6272       // 8*784 level/final grid

// ---------------- prep: tiny derived coefficients ----------------------------
__global__ __launch_bounds__(256) void prep_kernel(
    const float* __restrict__ w_in, const float* __restrict__ b_in,
    const float* __restrict__ imp_w1, const float* __restrict__ imp_b1,
    const float* __restrict__ fin_w, const float* __restrict__ fin_b,
    float* __restrict__ coeffs)
{
    int t = threadIdx.x;
    if (t < 16) {
        float a = 0.f, d = 0.f;
        for (int c = 0; c < 64; c++) {
            a += imp_w1[t * 64 + c] * w_in[64 + c];
            d += imp_w1[t * 64 + c] * b_in[64 + c];
        }
        coeffs[t] = a;
        coeffs[16 + t] = d + imp_b1[t];
    }
    if (t < 64) {
        float a = 0.f, d = 0.f;
        for (int c = 0; c < 64; c++) {
            a += fin_w[t * 64 + c] * w_in[c];
            d += fin_w[t * 64 + c] * b_in[c];
        }
        coeffs[32 + t] = a;
        coeffs[96 + t] = d + fin_b[t];
    }
}

// ---------------- importance map: sigmoid(conv3x3(relu(x*a+d), w2)+b2) --------
__global__ __launch_bounds__(256) void imp_kernel(
    const float* __restrict__ x, const float* __restrict__ coeffs,
    const float* __restrict__ imp_w2, const float* __restrict__ imp_b2,
    float* __restrict__ imp)
{
    int idx = blockIdx.x * 256 + threadIdx.x;
    int b = idx / PPIX, p = idx % PPIX;
    int h = p / WDIM, w = p % WDIM;
    float acc = imp_b2[0];
    #pragma unroll
    for (int ky = 0; ky < 3; ky++) {
        int hh = h + ky - 1;
        float okh = (hh >= 0 && hh < HDIM) ? 1.f : 0.f;
        int hc = min(max(hh, 0), HDIM - 1);
        #pragma unroll
        for (int kx = 0; kx < 3; kx++) {
            int ww = w + kx - 1;
            float ok = okh * ((ww >= 0 && ww < WDIM) ? 1.f : 0.f);
            int wc = min(max(ww, 0), WDIM - 1);
            float xv = x[b * PPIX + hc * WDIM + wc] * ok;
            #pragma unroll
            for (int c = 0; c < 16; c++) {
                float r = fmaxf(xv * coeffs[c] + coeffs[16 + c] * ok, 0.f);
                acc += r * imp_w2[c * 9 + ky * 3 + kx];
            }
        }
    }
    imp[idx] = 1.f / (1.f + expf(-acc));
}

// ---------------- exact top-k -> binary mask (one block per batch) ------------
__global__ __launch_bounds__(256) void topk_kernel(
    const float* __restrict__ imp, float* __restrict__ mask)
{
    int b = blockIdx.x;
    const float* v = imp + b * PPIX;
    float* m = mask + b * PPIX;
    int t = threadIdx.x;
    __shared__ unsigned int hist[256];
    __shared__ unsigned int sh_prefix;
    __shared__ int sh_rem;
    __shared__ int wtot[4];

    unsigned int prefix = 0u;
    int remaining = KTOP;
    for (int pass = 0; pass < 4; pass++) {
        int shift = 24 - 8 * pass;
        hist[t] = 0u;
        __syncthreads();
        unsigned int himask = (pass == 0) ? 0u : (0xFFFFFFFFu << (shift + 8));
        for (int i = t; i < PPIX; i += 256) {
            unsigned int bits = __float_as_uint(v[i]);
            if ((bits & himask) == prefix)
                atomicAdd(&hist[(bits >> shift) & 255u], 1u);
        }
        __syncthreads();
        if (t == 0) {
            int rem = remaining;
            unsigned int bsel = 0u;
            for (int bin = 255; bin >= 0; bin--) {
                int c = (int)hist[bin];
                if (c >= rem) { bsel = (unsigned int)bin; break; }
                rem -= c;
            }
            sh_rem = rem;
            sh_prefix = prefix | (bsel << shift);
        }
        __syncthreads();
        prefix = sh_prefix;
        remaining = sh_rem;
        __syncthreads();
    }
    unsigned int T = prefix;
    int base = 0;
    int lane = t & 63, wv = t >> 6;
    for (int i0 = 0; i0 < PPIX; i0 += 256) {
        int i = i0 + t;
        unsigned int bits = __float_as_uint(v[i]);
        int flag = (bits == T) ? 1 : 0;
        unsigned long long bal = __ballot(flag);
        if (lane == 0) wtot[wv] = __popcll(bal);
        __syncthreads();
        int wbase = 0, tot = 0;
        for (int q = 0; q < 4; q++) { int c = wtot[q]; if (q < wv) wbase += c; tot += c; }
        int excl = wbase + __popcll(bal & ((1ull << lane) - 1ull));
        float mout = 0.f;
        if (bits > T) mout = 1.f;
        else if (flag && (base + excl) < remaining) mout = 1.f;
        m[i] = mout;
        base += tot;
        __syncthreads();
    }
}

// ---------------- level: dwconv -> 1x1 conv, emit y + per-block bn partials ---
template<int KSZ, int DIL, int LEVEL>
__global__ __launch_bounds__(256, 4) void level_kernel(
    const float* __restrict__ x, const float* __restrict__ mask,
    const float* __restrict__ w_in, const float* __restrict__ b_in,
    const float* __restrict__ prev_y, const float* __restrict__ bnp_prev,
    const float* __restrict__ dw_w, const float* __restrict__ pw_w,
    const float* __restrict__ pw_b,
    float* __restrict__ y_out, float* __restrict__ partials)
{
    constexpr int PAD = (KSZ / 2) * DIL;
    constexpr int NT = KSZ * KSZ;
    __shared__ float D[64][64];
    __shared__ float4 sW[1024];
    __shared__ float sred[128];
    int t = threadIdx.x;
    // XCD-chunked swizzle: grid = 8*784; XCD k owns batch image k (halo stays L2-hot)
    int swz = (blockIdx.x & 7) * 784 + (blockIdx.x >> 3);
    int b = swz / 784;
    int lane = t & 63, og = t >> 6;
    int p = (swz % 784) * 64 + lane;
    int h = p / WDIM, w = p % WDIM;
    for (int i = t; i < 1024; i += 256) sW[i] = ((const float4*)pw_w)[i];

    // clamped tap addressing, validity as 0/1 floats (no divergent branches)
    int rowoff[KSZ]; float okhf[KSZ];
    int wcs[KSZ]; float okwf[KSZ];
    #pragma unroll
    for (int k = 0; k < KSZ; k++) {
        int hh = h + k * DIL - PAD;
        okhf[k] = (hh >= 0 && hh < HDIM) ? 1.f : 0.f;
        rowoff[k] = min(max(hh, 0), HDIM - 1) * WDIM;
        int ww = w + k * DIL - PAD;
        okwf[k] = (ww >= 0 && ww < WDIM) ? 1.f : 0.f;
        wcs[k] = min(max(ww, 0), WDIM - 1);
    }

    if constexpr (LEVEL == 0) {
        // in = mask*(x*wk+bk): hoist loads across channels.
        float mv[NT], mxv[NT];
        const float* mb = mask + b * PPIX;
        const float* xb = x + b * PPIX;
        #pragma unroll
        for (int ky = 0; ky < KSZ; ky++) {
            #pragma unroll
            for (int kx = 0; kx < KSZ; kx++) {
                int a = rowoff[ky] + wcs[kx];
                float mm = mb[a] * (okhf[ky] * okwf[kx]);
                mv[ky * KSZ + kx] = mm;
                mxv[ky * KSZ + kx] = mm * xb[a];
            }
        }
        #pragma unroll
        for (int j = 0; j < 16; j++) {
            int c = og * 16 + j;
            float wk = w_in[64 + c], bk = b_in[64 + c];
            const float* dwr = dw_w + c * NT;
            float a0 = 0.f, a1 = 0.f;
            #pragma unroll
            for (int tp = 0; tp < NT; tp++) {
                float dv = dwr[tp];
                a0 += dv * mxv[tp];
                a1 += dv * mv[tp];
            }
            D[c][lane] = wk * a0 + bk * a1;
        }
    } else {
        #pragma unroll 1   // keep code size sane; inner taps fully unrolled -> batched loads
        for (int j = 0; j < 16; j++) {
            int c = og * 16 + j;
            float sc = bnp_prev[c], sh = bnp_prev[64 + c];
            const float* plane = prev_y + (size_t)(b * 64 + c) * PPIX;
            const float* dwr = dw_w + c * NT;
            float acc = 0.f;
            #pragma unroll
            for (int ky = 0; ky < KSZ; ky++) {
                #pragma unroll
                for (int kx = 0; kx < KSZ; kx++) {
                    float v = plane[rowoff[ky] + wcs[kx]];
                    // OOB tap contributes exactly 0 (zero-pad is on relu'd input)
                    float q = fmaxf(sc * v + sh, 0.f) * (okhf[ky] * okwf[kx]);
                    acc += q * dwr[ky * KSZ + kx];
                }
            }
            D[c][lane] = acc;
        }
    }
    __syncthreads();

    float d[64];
    #pragma unroll
    for (int c = 0; c < 64; c++) d[c] = D[c][lane];

    #pragma unroll
    for (int j = 0; j < 16; j++) {
        int o = og * 16 + j;
        float acc = pw_b[o];
        #pragma unroll
        for (int c4 = 0; c4 < 16; c4++) {
            float4 wv = sW[o * 16 + c4];
            acc += wv.x * d[4 * c4] + wv.y * d[4 * c4 + 1]
                 + wv.z * d[4 * c4 + 2] + wv.w * d[4 * c4 + 3];
        }
        y_out[(size_t)(b * 64 + o) * PPIX + p] = acc;
        float s = acc, s2 = acc * acc;
        #pragma unroll
        for (int off = 32; off > 0; off >>= 1) {
            s += __shfl_down(s, off);
            s2 += __shfl_down(s2, off);
        }
        if (lane == 0) { sred[2 * o] = s; sred[2 * o + 1] = s2; }
    }
    __syncthreads();
    // one coalesced 512B row per block -- NO global atomics
    if (t < 128) partials[(size_t)blockIdx.x * 128 + t] = sred[t];
}

// ---------------- bn finalize: tree-reduce partials, one block per channel ----
__global__ __launch_bounds__(256) void bnfin_kernel(
    const float* __restrict__ partials,
    const float* __restrict__ g, const float* __restrict__ be,
    float* __restrict__ bnp)
{
    int c = blockIdx.x; // 0..63
    int t = threadIdx.x;
    float s = 0.f, s2 = 0.f;
    for (int blk = t; blk < NBLK; blk += 256) {
        s  += partials[(size_t)blk * 128 + 2 * c];
        s2 += partials[(size_t)blk * 128 + 2 * c + 1];
    }
    #pragma unroll
    for (int off = 32; off > 0; off >>= 1) {
        s += __shfl_down(s, off);
        s2 += __shfl_down(s2, off);
    }
    __shared__ float wsm[8];
    int lane = t & 63, wv = t >> 6;
    if (lane == 0) { wsm[wv] = s; wsm[4 + wv] = s2; }
    __syncthreads();
    if (t == 0) {
        s = wsm[0] + wsm[1] + wsm[2] + wsm[3];
        s2 = wsm[4] + wsm[5] + wsm[6] + wsm[7];
        const float inv_n = 1.f / (float)NPIX;
        float mu = s * inv_n;
        float var = s2 * inv_n - mu * mu;
        float sc = g[c] * rsqrtf(var + 1e-5f);
        bnp[c] = sc;
        bnp[64 + c] = be[c] - mu * sc;
    }
}

// ---------------- K_global: per (b,c) spatial mean of relu(bn(y2)) ------------
__global__ __launch_bounds__(256) void kglobal_kernel(
    const float* __restrict__ y2, const float* __restrict__ bnp2,
    float* __restrict__ kg)
{
    int bc = blockIdx.x; // 0..511
    int c = bc & 63;
    int t = threadIdx.x;
    const float* row = y2 + (size_t)bc * PPIX;
    float sc = bnp2[c], sh = bnp2[64 + c];
    float s = 0.f;
    for (int i = t; i < PPIX; i += 256) s += fmaxf(sc * row[i] + sh, 0.f);
    #pragma unroll
    for (int off = 32; off > 0; off >>= 1) s += __shfl_down(s, off);
    __shared__ float wsum[4];
    int lane = t & 63, wv = t >> 6;
    if (lane == 0) wsum[wv] = s;
    __syncthreads();
    if (t == 0) kg[bc] = (wsum[0] + wsum[1] + wsum[2] + wsum[3]) * (1.f / (float)PPIX);
}

// ---------------- final: aggregate + V + QV + out + x_proj --------------------
__global__ __launch_bounds__(256, 2) void final_kernel(
    const float* __restrict__ x, const float* __restrict__ w_in,
    const float* __restrict__ b_in,
    const float* __restrict__ y0, const float* __restrict__ y1,
    const float* __restrict__ y2,
    const float* __restrict__ bnp, const float* __restrict__ kg,
    const float* __restrict__ val_w, const float* __restrict__ val_b,
    const float* __restrict__ out_w, const float* __restrict__ out_b,
    const float* __restrict__ coeffs, float* __restrict__ out)
{
    __shared__ float KF[64][64];
    __shared__ float4 sVW[1024];
    __shared__ float4 sOW[1024];
    int t = threadIdx.x;
    int blk = blockIdx.x;
    int b = blk / 784;
    int lane = t & 63, og = t >> 6;
    int p = (blk % 784) * 64 + lane;
    for (int i = t; i < 1024; i += 256) {
        sVW[i] = ((const float4*)val_w)[i];
        sOW[i] = ((const float4*)out_w)[i];
    }

    float xv = x[b * PPIX + p];
    float g0 = xv * w_in[128] + b_in[128];
    float g1 = xv * w_in[129] + b_in[129];
    float g2 = xv * w_in[130] + b_in[130];
    float g3 = xv * w_in[131] + b_in[131];
    float mx = fmaxf(fmaxf(g0, g1), fmaxf(g2, g3));
    float e0 = expf(g0 - mx), e1 = expf(g1 - mx), e2 = expf(g2 - mx), e3 = expf(g3 - mx);
    float inv = 1.f / (e0 + e1 + e2 + e3);
    float G0 = e0 * inv, G1 = e1 * inv, G2 = e2 * inv, G3 = e3 * inv;

    #pragma unroll
    for (int j = 0; j < 16; j++) {
        int c = og * 16 + j;
        size_t idx = (size_t)(b * 64 + c) * PPIX + p;
        float f0 = fmaxf(bnp[c] * y0[idx] + bnp[64 + c], 0.f);
        float f1 = fmaxf(bnp[128 + c] * y1[idx] + bnp[192 + c], 0.f);
        float f2 = fmaxf(bnp[256 + c] * y2[idx] + bnp[320 + c], 0.f);
        KF[c][lane] = G0 * f0 + G1 * f1 + G2 * f2 + G3 * kg[b * 64 + c];
    }
    __syncthreads();

    float kf[64];
    #pragma unroll
    for (int c = 0; c < 64; c++) kf[c] = KF[c][lane];

    float V[16];
    #pragma unroll
    for (int j = 0; j < 16; j++) {
        int o = og * 16 + j;
        float acc = val_b[o];
        #pragma unroll
        for (int c4 = 0; c4 < 16; c4++) {
            float4 wv = sVW[o * 16 + c4];
            acc += wv.x * kf[4 * c4] + wv.y * kf[4 * c4 + 1]
                 + wv.z * kf[4 * c4 + 2] + wv.w * kf[4 * c4 + 3];
        }
        V[j] = acc;
    }
    __syncthreads();
    #pragma unroll
    for (int j = 0; j < 16; j++) {
        int o = og * 16 + j;
        float q = xv * w_in[o] + b_in[o];
        KF[o][lane] = q * V[j];
    }
    __syncthreads();

    float tq[64];
    #pragma unroll
    for (int c = 0; c < 64; c++) tq[c] = KF[c][lane];

    #pragma unroll
    for (int j = 0; j < 16; j++) {
        int o = og * 16 + j;
        float acc = out_b[o];
        #pragma unroll
        for (int c4 = 0; c4 < 16; c4++) {
            float4 wv = sOW[o * 16 + c4];
            acc += wv.x * tq[4 * c4] + wv.y * tq[4 * c4 + 1]
                 + wv.z * tq[4 * c4 + 2] + wv.w * tq[4 * c4 + 3];
        }
        out[(size_t)(b * 64 + o) * PPIX + p] = acc + xv * coeffs[32 + o] + coeffs[96 + o];
    }
}

extern "C" void kernel_launch(void* const* d_in, const int* in_sizes, int n_in,
                              void* d_out, int out_size, void* d_ws, size_t ws_size,
                              hipStream_t stream)
{
    (void)in_sizes; (void)n_in; (void)out_size; (void)ws_size;
    const float* x      = (const float*)d_in[0];
    const float* w_in   = (const float*)d_in[1];
    const float* b_in   = (const float*)d_in[2];
    const float* dw0    = (const float*)d_in[3];
    const float* pw0_w  = (const float*)d_in[4];
    const float* pw0_b  = (const float*)d_in[5];
    const float* bn0_g  = (const float*)d_in[6];
    const float* bn0_b  = (const float*)d_in[7];
    const float* dw1    = (const float*)d_in[8];
    const float* pw1_w  = (const float*)d_in[9];
    const float* pw1_b  = (const float*)d_in[10];
    const float* bn1_g  = (const float*)d_in[11];
    const float* bn1_b  = (const float*)d_in[12];
    const float* dw2    = (const float*)d_in[13];
    const float* pw2_w  = (const float*)d_in[14];
    const float* pw2_b  = (const float*)d_in[15];
    const float* bn2_g  = (const float*)d_in[16];
    const float* bn2_b  = (const float*)d_in[17];
    const float* imp_w1 = (const float*)d_in[18];
    const float* imp_b1 = (const float*)d_in[19];
    const float* imp_w2 = (const float*)d_in[20];
    const float* imp_b2 = (const float*)d_in[21];
    const float* val_w  = (const float*)d_in[22];
    const float* val_b  = (const float*)d_in[23];
    const float* out_w  = (const float*)d_in[24];
    const float* out_b  = (const float*)d_in[25];
    const float* fin_w  = (const float*)d_in[26];
    const float* fin_b  = (const float*)d_in[27];

    float* ws   = (float*)d_ws;
    float* y0   = ws;
    float* y1   = ws + (size_t)NELEM;
    float* imp  = ws + (size_t)2 * NELEM;
    float* mask = imp + NPIX;
    float* partials = mask + NPIX;          // 6272*128 = 802816 floats
    float* bnp   = partials + (size_t)NBLK * 128; // 3*128
    float* kg    = bnp + 384;               // 512
    float* coeffs = kg + 512;               // 160
    float* y2 = (float*)d_out;

    prep_kernel<<<1, 256, 0, stream>>>(w_in, b_in, imp_w1, imp_b1, fin_w, fin_b, coeffs);
    imp_kernel<<<NPIX / 256, 256, 0, stream>>>(x, coeffs, imp_w2, imp_b2, imp);
    topk_kernel<<<BATCH, 256, 0, stream>>>(imp, mask);

    level_kernel<3, 1, 0><<<NBLK, 256, 0, stream>>>(x, mask, w_in, b_in, nullptr, nullptr,
                                                    dw0, pw0_w, pw0_b, y0, partials);
    bnfin_kernel<<<64, 256, 0, stream>>>(partials, bn0_g, bn0_b, bnp);
    level_kernel<5, 2, 1><<<NBLK, 256, 0, stream>>>(x, mask, w_in, b_in, y0, bnp,
                                                    dw1, pw1_w, pw1_b, y1, partials);
    bnfin_kernel<<<64, 256, 0, stream>>>(partials, bn1_g, bn1_b, bnp + 128);
    level_kernel<7, 4, 2><<<NBLK, 256, 0, stream>>>(x, mask, w_in, b_in, y1, bnp + 128,
                                                    dw2, pw2_w, pw2_b, y2, partials);
    bnfin_kernel<<<64, 256, 0, stream>>>(partials, bn2_g, bn2_b, bnp + 256);

    kglobal_kernel<<<512, 256, 0, stream>>>(y2, bnp + 256, kg);
    final_kernel<<<NBLK, 256, 0, stream>>>(x, w_in, b_in, y0, y1, y2, bnp, kg,
                                           val_w, val_b, out_w, out_b, coeffs, y2);
}

// Round 4
// 1144.688 us; speedup vs baseline: 7.5489x; 2.5318x over previous
//
#include <hip/hip_runtime.h>

#define HDIM 224
#define WDIM 224
#define PPIX 50176      // 224*224
#define BATCH 8
#define NPIX 401408     // 8*50176
#define KTOP 15052      // max(int(0.3*224*224), 64)
#define NELEM 25690112  // 8*64*50176
#define NBLK 6272       // 8*784 strip grid
#define NBAND 14        // 224/16
#define NDWBLK 7168     // 8*64*14

// ---------------- prep: tiny derived coefficients ----------------------------
__global__ __launch_bounds__(256) void prep_kernel(
    const float* __restrict__ w_in, const float* __restrict__ b_in,
    const float* __restrict__ imp_w1, const float* __restrict__ imp_b1,
    const float* __restrict__ fin_w, const float* __restrict__ fin_b,
    float* __restrict__ coeffs)
{
    int t = threadIdx.x;
    if (t < 16) {
        float a = 0.f, d = 0.f;
        for (int c = 0; c < 64; c++) {
            a += imp_w1[t * 64 + c] * w_in[64 + c];
            d += imp_w1[t * 64 + c] * b_in[64 + c];
        }
        coeffs[t] = a;
        coeffs[16 + t] = d + imp_b1[t];
    }
    if (t < 64) {
        float a = 0.f, d = 0.f;
        for (int c = 0; c < 64; c++) {
            a += fin_w[t * 64 + c] * w_in[c];
            d += fin_w[t * 64 + c] * b_in[c];
        }
        coeffs[32 + t] = a;
        coeffs[96 + t] = d + fin_b[t];
    }
}

// ---------------- importance map: sigmoid(conv3x3(relu(x*a+d), w2)+b2) --------
__global__ __launch_bounds__(256) void imp_kernel(
    const float* __restrict__ x, const float* __restrict__ coeffs,
    const float* __restrict__ imp_w2, const float* __restrict__ imp_b2,
    float* __restrict__ imp)
{
    int idx = blockIdx.x * 256 + threadIdx.x;
    int b = idx / PPIX, p = idx % PPIX;
    int h = p / WDIM, w = p % WDIM;
    float acc = imp_b2[0];
    #pragma unroll
    for (int ky = 0; ky < 3; ky++) {
        int hh = h + ky - 1;
        float okh = (hh >= 0 && hh < HDIM) ? 1.f : 0.f;
        int hc = min(max(hh, 0), HDIM - 1);
        #pragma unroll
        for (int kx = 0; kx < 3; kx++) {
            int ww = w + kx - 1;
            float ok = okh * ((ww >= 0 && ww < WDIM) ? 1.f : 0.f);
            int wc = min(max(ww, 0), WDIM - 1);
            float xv = x[b * PPIX + hc * WDIM + wc] * ok;
            #pragma unroll
            for (int c = 0; c < 16; c++) {
                float r = fmaxf(xv * coeffs[c] + coeffs[16 + c] * ok, 0.f);
                acc += r * imp_w2[c * 9 + ky * 3 + kx];
            }
        }
    }
    imp[idx] = 1.f / (1.f + expf(-acc));
}

// ---------------- exact top-k -> binary mask (one block per batch) ------------
__global__ __launch_bounds__(256) void topk_kernel(
    const float* __restrict__ imp, float* __restrict__ mask)
{
    int b = blockIdx.x;
    const float* v = imp + b * PPIX;
    float* m = mask + b * PPIX;
    int t = threadIdx.x;
    __shared__ unsigned int hist[256];
    __shared__ unsigned int sh_prefix;
    __shared__ int sh_rem;
    __shared__ int wtot[4];

    unsigned int prefix = 0u;
    int remaining = KTOP;
    for (int pass = 0; pass < 4; pass++) {
        int shift = 24 - 8 * pass;
        hist[t] = 0u;
        __syncthreads();
        unsigned int himask = (pass == 0) ? 0u : (0xFFFFFFFFu << (shift + 8));
        for (int i = t; i < PPIX; i += 256) {
            unsigned int bits = __float_as_uint(v[i]);
            if ((bits & himask) == prefix)
                atomicAdd(&hist[(bits >> shift) & 255u], 1u);
        }
        __syncthreads();
        if (t == 0) {
            int rem = remaining;
            unsigned int bsel = 0u;
            for (int bin = 255; bin >= 0; bin--) {
                int c = (int)hist[bin];
                if (c >= rem) { bsel = (unsigned int)bin; break; }
                rem -= c;
            }
            sh_rem = rem;
            sh_prefix = prefix | (bsel << shift);
        }
        __syncthreads();
        prefix = sh_prefix;
        remaining = sh_rem;
        __syncthreads();
    }
    unsigned int T = prefix;
    int base = 0;
    int lane = t & 63, wv = t >> 6;
    for (int i0 = 0; i0 < PPIX; i0 += 256) {
        int i = i0 + t;
        unsigned int bits = __float_as_uint(v[i]);
        int flag = (bits == T) ? 1 : 0;
        unsigned long long bal = __ballot(flag);
        if (lane == 0) wtot[wv] = __popcll(bal);
        __syncthreads();
        int wbase = 0, tot = 0;
        for (int q = 0; q < 4; q++) { int c = wtot[q]; if (q < wv) wbase += c; tot += c; }
        int excl = wbase + __popcll(bal & ((1ull << lane) - 1ull));
        float mout = 0.f;
        if (bits > T) mout = 1.f;
        else if (flag && (base + excl) < remaining) mout = 1.f;
        m[i] = mout;
        base += tot;
        __syncthreads();
    }
}

// ---------------- level 0 fused: masked dwconv3x3 -> 1x1, y0 + partials -------
__global__ __launch_bounds__(256, 4) void level0_kernel(
    const float* __restrict__ x, const float* __restrict__ mask,
    const float* __restrict__ w_in, const float* __restrict__ b_in,
    const float* __restrict__ dw_w, const float* __restrict__ pw_w,
    const float* __restrict__ pw_b,
    float* __restrict__ y_out, float* __restrict__ partials)
{
    __shared__ float D[64][64];
    __shared__ float4 sW[1024];
    __shared__ float sred[128];
    int t = threadIdx.x;
    int swz = (blockIdx.x & 7) * 784 + (blockIdx.x >> 3);
    int b = swz / 784;
    int lane = t & 63, og = t >> 6;
    int p = (swz % 784) * 64 + lane;
    int h = p / WDIM, w = p % WDIM;
    for (int i = t; i < 1024; i += 256) sW[i] = ((const float4*)pw_w)[i];

    int rowoff[3]; float okhf[3];
    int wcs[3]; float okwf[3];
    #pragma unroll
    for (int k = 0; k < 3; k++) {
        int hh = h + k - 1;
        okhf[k] = (hh >= 0 && hh < HDIM) ? 1.f : 0.f;
        rowoff[k] = min(max(hh, 0), HDIM - 1) * WDIM;
        int ww = w + k - 1;
        okwf[k] = (ww >= 0 && ww < WDIM) ? 1.f : 0.f;
        wcs[k] = min(max(ww, 0), WDIM - 1);
    }

    float mv[9], mxv[9];
    const float* mb = mask + b * PPIX;
    const float* xb = x + b * PPIX;
    #pragma unroll
    for (int ky = 0; ky < 3; ky++) {
        #pragma unroll
        for (int kx = 0; kx < 3; kx++) {
            int a = rowoff[ky] + wcs[kx];
            float mm = mb[a] * (okhf[ky] * okwf[kx]);
            mv[ky * 3 + kx] = mm;
            mxv[ky * 3 + kx] = mm * xb[a];
        }
    }
    #pragma unroll
    for (int j = 0; j < 16; j++) {
        int c = og * 16 + j;
        float wk = w_in[64 + c], bk = b_in[64 + c];
        const float* dwr = dw_w + c * 9;
        float a0 = 0.f, a1 = 0.f;
        #pragma unroll
        for (int tp = 0; tp < 9; tp++) {
            float dv = dwr[tp];
            a0 += dv * mxv[tp];
            a1 += dv * mv[tp];
        }
        D[c][lane] = wk * a0 + bk * a1;
    }
    __syncthreads();

    float d[64];
    #pragma unroll
    for (int c = 0; c < 64; c++) d[c] = D[c][lane];

    #pragma unroll
    for (int j = 0; j < 16; j++) {
        int o = og * 16 + j;
        float acc = pw_b[o];
        #pragma unroll
        for (int c4 = 0; c4 < 16; c4++) {
            float4 wv = sW[o * 16 + c4];
            acc += wv.x * d[4 * c4] + wv.y * d[4 * c4 + 1]
                 + wv.z * d[4 * c4 + 2] + wv.w * d[4 * c4 + 3];
        }
        y_out[(size_t)(b * 64 + o) * PPIX + p] = acc;
        float s = acc, s2 = acc * acc;
        #pragma unroll
        for (int off = 32; off > 0; off >>= 1) {
            s += __shfl_down(s, off);
            s2 += __shfl_down(s2, off);
        }
        if (lane == 0) { sred[2 * o] = s; sred[2 * o + 1] = s2; }
    }
    __syncthreads();
    if (t < 128) partials[(size_t)blockIdx.x * 128 + t] = sred[t];
}

// ---------------- dilated dwconv: LDS-staged band, relu(bn(prev)) input -------
// block = one (b, c, 16-row band); input zero-padded into LDS; output coalesced
template<int KSZ, int DIL>
__global__ __launch_bounds__(256, 4) void dw_kernel(
    const float* __restrict__ in, const float* __restrict__ bnp,
    const float* __restrict__ dw_w, float* __restrict__ out)
{
    constexpr int PAD = (KSZ / 2) * DIL;
    constexpr int BH = 16;
    constexpr int LR = BH + 2 * PAD;        // staged rows
    constexpr int SW = WDIM + 2 * PAD;      // padded width
    __shared__ float sIn[LR * SW];

    int t = threadIdx.x;
    // XCD-chunk: 7168 blocks -> 896 consecutive (bc,band) per XCD; vertically
    // adjacent bands of a plane dispatch back-to-back -> halo rows L2-hot.
    int swz = (blockIdx.x & 7) * (NDWBLK / 8) + (blockIdx.x >> 3);
    int bc = swz / NBAND, band = swz % NBAND;
    int c = bc & 63;
    int r0 = band * BH;
    float sc = bnp[c], sh = bnp[64 + c];
    const float* plane = in + (size_t)bc * PPIX;

    for (int i = t; i < LR * SW; i += 256) sIn[i] = 0.f;
    __syncthreads();
    for (int i = t; i < LR * 56; i += 256) {
        int sr = i / 56, q = i % 56;
        int gr = r0 - PAD + sr;
        if (gr >= 0 && gr < HDIM) {
            float4 v = ((const float4*)(plane + gr * WDIM))[q];
            float* drow = sIn + sr * SW + PAD + 4 * q;
            drow[0] = fmaxf(sc * v.x + sh, 0.f);
            drow[1] = fmaxf(sc * v.y + sh, 0.f);
            drow[2] = fmaxf(sc * v.z + sh, 0.f);
            drow[3] = fmaxf(sc * v.w + sh, 0.f);
        }
    }
    __syncthreads();

    // depthwise weights: block-uniform address -> scalar loads
    const float* dwr = dw_w + c * KSZ * KSZ;
    float wk[KSZ * KSZ];
    #pragma unroll
    for (int i = 0; i < KSZ * KSZ; i++) wk[i] = dwr[i];

    float* oplane = out + (size_t)bc * PPIX + r0 * WDIM;
    for (int oi = 0; oi < (BH * WDIM) / 256; oi++) {
        int o = oi * 256 + t;
        int orow = o / WDIM, ocol = o % WDIM;
        const float* sbase = sIn + orow * SW + ocol;   // 49 taps at imm offsets
        float acc = 0.f;
        #pragma unroll
        for (int ky = 0; ky < KSZ; ky++)
            #pragma unroll
            for (int kx = 0; kx < KSZ; kx++)
                acc += sbase[(ky * DIL) * SW + kx * DIL] * wk[ky * KSZ + kx];
        oplane[o] = acc;
    }
}

// ---------------- pointwise 64x64 matvec, IN-PLACE, + bn partials -------------
__global__ __launch_bounds__(256, 2) void pw_kernel(
    const float* __restrict__ pw_w, const float* __restrict__ pw_b,
    float* __restrict__ y, float* __restrict__ partials)
{
    __shared__ float D[64][64];
    __shared__ float4 sW[1024];
    __shared__ float sred[128];
    int t = threadIdx.x;
    int swz = (blockIdx.x & 7) * 784 + (blockIdx.x >> 3);
    int b = swz / 784;
    int lane = t & 63, og = t >> 6;
    int p0 = (swz % 784) * 64;
    for (int i = t; i < 1024; i += 256) sW[i] = ((const float4*)pw_w)[i];

    float* ybase = y + (size_t)b * 64 * PPIX + p0;
    for (int i = t; i < 1024; i += 256) {
        int cc = i >> 4, q = i & 15;
        float4 v = *(const float4*)(ybase + (size_t)cc * PPIX + 4 * q);
        ((float4*)&D[cc][0])[q] = v;
    }
    __syncthreads();   // all reads complete before any in-place write

    float d[64];
    #pragma unroll
    for (int cq = 0; cq < 64; cq++) d[cq] = D[cq][lane];

    #pragma unroll
    for (int j = 0; j < 16; j++) {
        int o = og * 16 + j;
        float acc = pw_b[o];
        #pragma unroll
        for (int c4 = 0; c4 < 16; c4++) {
            float4 wv = sW[o * 16 + c4];
            acc += wv.x * d[4 * c4] + wv.y * d[4 * c4 + 1]
                 + wv.z * d[4 * c4 + 2] + wv.w * d[4 * c4 + 3];
        }
        ybase[(size_t)o * PPIX + lane] = acc;
        float s = acc, s2 = acc * acc;
        #pragma unroll
        for (int off = 32; off > 0; off >>= 1) {
            s += __shfl_down(s, off);
            s2 += __shfl_down(s2, off);
        }
        if (lane == 0) { sred[2 * o] = s; sred[2 * o + 1] = s2; }
    }
    __syncthreads();
    if (t < 128) partials[(size_t)blockIdx.x * 128 + t] = sred[t];
}

// ---------------- bn finalize: tree-reduce partials, one block per channel ----
__global__ __launch_bounds__(256) void bnfin_kernel(
    const float* __restrict__ partials,
    const float* __restrict__ g, const float* __restrict__ be,
    float* __restrict__ bnp)
{
    int c = blockIdx.x; // 0..63
    int t = threadIdx.x;
    float s = 0.f, s2 = 0.f;
    for (int blk = t; blk < NBLK; blk += 256) {
        s  += partials[(size_t)blk * 128 + 2 * c];
        s2 += partials[(size_t)blk * 128 + 2 * c + 1];
    }
    #pragma unroll
    for (int off = 32; off > 0; off >>= 1) {
        s += __shfl_down(s, off);
        s2 += __shfl_down(s2, off);
    }
    __shared__ float wsm[8];
    int lane = t & 63, wv = t >> 6;
    if (lane == 0) { wsm[wv] = s; wsm[4 + wv] = s2; }
    __syncthreads();
    if (t == 0) {
        s = wsm[0] + wsm[1] + wsm[2] + wsm[3];
        s2 = wsm[4] + wsm[5] + wsm[6] + wsm[7];
        const float inv_n = 1.f / (float)NPIX;
        float mu = s * inv_n;
        float var = s2 * inv_n - mu * mu;
        float sc = g[c] * rsqrtf(var + 1e-5f);
        bnp[c] = sc;
        bnp[64 + c] = be[c] - mu * sc;
    }
}

// ---------------- K_global: per (b,c) spatial mean of relu(bn(y2)) ------------
__global__ __launch_bounds__(256) void kglobal_kernel(
    const float* __restrict__ y2, const float* __restrict__ bnp2,
    float* __restrict__ kg)
{
    int bc = blockIdx.x; // 0..511
    int c = bc & 63;
    int t = threadIdx.x;
    const float* row = y2 + (size_t)bc * PPIX;
    float sc = bnp2[c], sh = bnp2[64 + c];
    float s = 0.f;
    for (int i = t; i < PPIX; i += 256) s += fmaxf(sc * row[i] + sh, 0.f);
    #pragma unroll
    for (int off = 32; off > 0; off >>= 1) s += __shfl_down(s, off);
    __shared__ float wsum[4];
    int lane = t & 63, wv = t >> 6;
    if (lane == 0) wsum[wv] = s;
    __syncthreads();
    if (t == 0) kg[bc] = (wsum[0] + wsum[1] + wsum[2] + wsum[3]) * (1.f / (float)PPIX);
}

// ---------------- final: aggregate + V + QV + out + x_proj --------------------
__global__ __launch_bounds__(256, 2) void final_kernel(
    const float* __restrict__ x, const float* __restrict__ w_in,
    const float* __restrict__ b_in,
    const float* __restrict__ y0, const float* __restrict__ y1,
    const float* __restrict__ y2,
    const float* __restrict__ bnp, const float* __restrict__ kg,
    const float* __restrict__ val_w, const float* __restrict__ val_b,
    const float* __restrict__ out_w, const float* __restrict__ out_b,
    const float* __restrict__ coeffs, float* __restrict__ out)
{
    __shared__ float KF[64][64];
    __shared__ float4 sVW[1024];
    __shared__ float4 sOW[1024];
    int t = threadIdx.x;
    int blk = blockIdx.x;
    int b = blk / 784;
    int lane = t & 63, og = t >> 6;
    int p = (blk % 784) * 64 + lane;
    for (int i = t; i < 1024; i += 256) {
        sVW[i] = ((const float4*)val_w)[i];
        sOW[i] = ((const float4*)out_w)[i];
    }

    float xv = x[b * PPIX + p];
    float g0 = xv * w_in[128] + b_in[128];
    float g1 = xv * w_in[129] + b_in[129];
    float g2 = xv * w_in[130] + b_in[130];
    float g3 = xv * w_in[131] + b_in[131];
    float mx = fmaxf(fmaxf(g0, g1), fmaxf(g2, g3));
    float e0 = expf(g0 - mx), e1 = expf(g1 - mx), e2 = expf(g2 - mx), e3 = expf(g3 - mx);
    float inv = 1.f / (e0 + e1 + e2 + e3);
    float G0 = e0 * inv, G1 = e1 * inv, G2 = e2 * inv, G3 = e3 * inv;

    #pragma unroll
    for (int j = 0; j < 16; j++) {
        int c = og * 16 + j;
        size_t idx = (size_t)(b * 64 + c) * PPIX + p;
        float f0 = fmaxf(bnp[c] * y0[idx] + bnp[64 + c], 0.f);
        float f1 = fmaxf(bnp[128 + c] * y1[idx] + bnp[192 + c], 0.f);
        float f2 = fmaxf(bnp[256 + c] * y2[idx] + bnp[320 + c], 0.f);
        KF[c][lane] = G0 * f0 + G1 * f1 + G2 * f2 + G3 * kg[b * 64 + c];
    }
    __syncthreads();

    float kf[64];
    #pragma unroll
    for (int c = 0; c < 64; c++) kf[c] = KF[c][lane];

    float V[16];
    #pragma unroll
    for (int j = 0; j < 16; j++) {
        int o = og * 16 + j;
        float acc = val_b[o];
        #pragma unroll
        for (int c4 = 0; c4 < 16; c4++) {
            float4 wv = sVW[o * 16 + c4];
            acc += wv.x * kf[4 * c4] + wv.y * kf[4 * c4 + 1]
                 + wv.z * kf[4 * c4 + 2] + wv.w * kf[4 * c4 + 3];
        }
        V[j] = acc;
    }
    __syncthreads();
    #pragma unroll
    for (int j = 0; j < 16; j++) {
        int o = og * 16 + j;
        float q = xv * w_in[o] + b_in[o];
        KF[o][lane] = q * V[j];
    }
    __syncthreads();

    float tq[64];
    #pragma unroll
    for (int c = 0; c < 64; c++) tq[c] = KF[c][lane];

    #pragma unroll
    for (int j = 0; j < 16; j++) {
        int o = og * 16 + j;
        float acc = out_b[o];
        #pragma unroll
        for (int c4 = 0; c4 < 16; c4++) {
            float4 wv = sOW[o * 16 + c4];
            acc += wv.x * tq[4 * c4] + wv.y * tq[4 * c4 + 1]
                 + wv.z * tq[4 * c4 + 2] + wv.w * tq[4 * c4 + 3];
        }
        out[(size_t)(b * 64 + o) * PPIX + p] = acc + xv * coeffs[32 + o] + coeffs[96 + o];
    }
}

extern "C" void kernel_launch(void* const* d_in, const int* in_sizes, int n_in,
                              void* d_out, int out_size, void* d_ws, size_t ws_size,
                              hipStream_t stream)
{
    (void)in_sizes; (void)n_in; (void)out_size; (void)ws_size;
    const float* x      = (const float*)d_in[0];
    const float* w_in   = (const float*)d_in[1];
    const float* b_in   = (const float*)d_in[2];
    const float* dw0    = (const float*)d_in[3];
    const float* pw0_w  = (const float*)d_in[4];
    const float* pw0_b  = (const float*)d_in[5];
    const float* bn0_g  = (const float*)d_in[6];
    const float* bn0_b  = (const float*)d_in[7];
    const float* dw1    = (const float*)d_in[8];
    const float* pw1_w  = (const float*)d_in[9];
    const float* pw1_b  = (const float*)d_in[10];
    const float* bn1_g  = (const float*)d_in[11];
    const float* bn1_b  = (const float*)d_in[12];
    const float* dw2    = (const float*)d_in[13];
    const float* pw2_w  = (const float*)d_in[14];
    const float* pw2_b  = (const float*)d_in[15];
    const float* bn2_g  = (const float*)d_in[16];
    const float* bn2_b  = (const float*)d_in[17];
    const float* imp_w1 = (const float*)d_in[18];
    const float* imp_b1 = (const float*)d_in[19];
    const float* imp_w2 = (const float*)d_in[20];
    const float* imp_b2 = (const float*)d_in[21];
    const float* val_w  = (const float*)d_in[22];
    const float* val_b  = (const float*)d_in[23];
    const float* out_w  = (const float*)d_in[24];
    const float* out_b  = (const float*)d_in[25];
    const float* fin_w  = (const float*)d_in[26];
    const float* fin_b  = (const float*)d_in[27];

    float* ws   = (float*)d_ws;
    float* y0   = ws;
    float* y1   = ws + (size_t)NELEM;
    float* imp  = ws + (size_t)2 * NELEM;
    float* mask = imp + NPIX;
    float* partials = mask + NPIX;                // 6272*128
    float* bnp   = partials + (size_t)NBLK * 128; // 3*128
    float* kg    = bnp + 384;                     // 512
    float* coeffs = kg + 512;                     // 160
    float* y2 = (float*)d_out;

    prep_kernel<<<1, 256, 0, stream>>>(w_in, b_in, imp_w1, imp_b1, fin_w, fin_b, coeffs);
    imp_kernel<<<NPIX / 256, 256, 0, stream>>>(x, coeffs, imp_w2, imp_b2, imp);
    topk_kernel<<<BATCH, 256, 0, stream>>>(imp, mask);

    level0_kernel<<<NBLK, 256, 0, stream>>>(x, mask, w_in, b_in, dw0, pw0_w, pw0_b,
                                            y0, partials);
    bnfin_kernel<<<64, 256, 0, stream>>>(partials, bn0_g, bn0_b, bnp);

    dw_kernel<5, 2><<<NDWBLK, 256, 0, stream>>>(y0, bnp, dw1, y1);
    pw_kernel<<<NBLK, 256, 0, stream>>>(pw1_w, pw1_b, y1, partials);
    bnfin_kernel<<<64, 256, 0, stream>>>(partials, bn1_g, bn1_b, bnp + 128);

    dw_kernel<7, 4><<<NDWBLK, 256, 0, stream>>>(y1, bnp + 128, dw2, y2);
    pw_kernel<<<NBLK, 256, 0, stream>>>(pw2_w, pw2_b, y2, partials);
    bnfin_kernel<<<64, 256, 0, stream>>>(partials, bn2_g, bn2_b, bnp + 256);

    kglobal_kernel<<<512, 256, 0, stream>>>(y2, bnp + 256, kg);
    final_kernel<<<NBLK, 256, 0, stream>>>(x, w_in, b_in, y0, y1, y2, bnp, kg,
                                           val_w, val_b, out_w, out_b, coeffs, y2);
}

// Round 5
// 999.750 us; speedup vs baseline: 8.6433x; 1.1450x over previous
//
#include <hip/hip_runtime.h>

#define HDIM 224
#define WDIM 224
#define PPIX 50176      // 224*224
#define BATCH 8
#define NPIX 401408     // 8*50176
#define KTOP 15052      // max(int(0.3*224*224), 64)
#define NELEM 25690112  // 8*64*50176
#define NBLK 6272       // 8*784 strip grid
#define NBAND 14        // 224/16
#define NDWBLK 7168     // 8*64*14
#define NCHUNK 49       // PPIX / 1024

// ---------------- prep: tiny derived coefficients + topk state init ----------
__global__ __launch_bounds__(256) void prep_kernel(
    const float* __restrict__ w_in, const float* __restrict__ b_in,
    const float* __restrict__ imp_w1, const float* __restrict__ imp_b1,
    const float* __restrict__ fin_w, const float* __restrict__ fin_b,
    float* __restrict__ coeffs, unsigned int* __restrict__ ghist,
    unsigned int* __restrict__ pfx, int* __restrict__ rem)
{
    int t = threadIdx.x;
    if (t < 16) {
        float a = 0.f, d = 0.f;
        for (int c = 0; c < 64; c++) {
            a += imp_w1[t * 64 + c] * w_in[64 + c];
            d += imp_w1[t * 64 + c] * b_in[64 + c];
        }
        coeffs[t] = a;
        coeffs[16 + t] = d + imp_b1[t];
    }
    if (t < 64) {
        float a = 0.f, d = 0.f;
        for (int c = 0; c < 64; c++) {
            a += fin_w[t * 64 + c] * w_in[c];
            d += fin_w[t * 64 + c] * b_in[c];
        }
        coeffs[32 + t] = a;
        coeffs[96 + t] = d + fin_b[t];
    }
    for (int i = t; i < 2048; i += 256) ghist[i] = 0u;
    if (t < BATCH) { pfx[t] = 0u; rem[t] = KTOP; }
}

// ---------------- importance map: sigmoid(conv3x3(relu(x*a+d), w2)+b2) --------
__global__ __launch_bounds__(256) void imp_kernel(
    const float* __restrict__ x, const float* __restrict__ coeffs,
    const float* __restrict__ imp_w2, const float* __restrict__ imp_b2,
    float* __restrict__ imp)
{
    int idx = blockIdx.x * 256 + threadIdx.x;
    int b = idx / PPIX, p = idx % PPIX;
    int h = p / WDIM, w = p % WDIM;
    float acc = imp_b2[0];
    #pragma unroll
    for (int ky = 0; ky < 3; ky++) {
        int hh = h + ky - 1;
        float okh = (hh >= 0 && hh < HDIM) ? 1.f : 0.f;
        int hc = min(max(hh, 0), HDIM - 1);
        #pragma unroll
        for (int kx = 0; kx < 3; kx++) {
            int ww = w + kx - 1;
            float ok = okh * ((ww >= 0 && ww < WDIM) ? 1.f : 0.f);
            int wc = min(max(ww, 0), WDIM - 1);
            float xv = x[b * PPIX + hc * WDIM + wc] * ok;
            #pragma unroll
            for (int c = 0; c < 16; c++) {
                float r = fmaxf(xv * coeffs[c] + coeffs[16 + c] * ok, 0.f);
                acc += r * imp_w2[c * 9 + ky * 3 + kx];
            }
        }
    }
    imp[idx] = 1.f / (1.f + expf(-acc));
}

// ---------------- parallel exact top-k: radix histogram pass ------------------
__global__ __launch_bounds__(256) void topk_hist(
    const float* __restrict__ imp, const unsigned int* __restrict__ pfx,
    unsigned int* __restrict__ ghist, int shift)
{
    int b = blockIdx.x / NCHUNK, ch = blockIdx.x % NCHUNK;
    int t = threadIdx.x;
    __shared__ unsigned int hist[256];
    hist[t] = 0u;
    __syncthreads();
    unsigned int prefix = pfx[b];
    unsigned int himask = (shift == 24) ? 0u : (0xFFFFFFFFu << (shift + 8));
    float4 v = ((const float4*)(imp + b * PPIX + ch * 1024))[t];
    unsigned int bb[4] = {__float_as_uint(v.x), __float_as_uint(v.y),
                          __float_as_uint(v.z), __float_as_uint(v.w)};
    #pragma unroll
    for (int k = 0; k < 4; k++)
        if ((bb[k] & himask) == prefix)
            atomicAdd(&hist[(bb[k] >> shift) & 255u], 1u);
    __syncthreads();
    unsigned int c = hist[t];
    if (c) atomicAdd(&ghist[b * 256 + t], c);
}

// ---------------- top-k: select bin, update prefix/remaining, zero hist -------
__global__ __launch_bounds__(256) void topk_select(
    unsigned int* __restrict__ ghist, unsigned int* __restrict__ pfx,
    int* __restrict__ rem, int shift)
{
    int b = blockIdx.x;
    int t = threadIdx.x;
    __shared__ unsigned int h[256];
    h[t] = ghist[b * 256 + t];
    ghist[b * 256 + t] = 0u;          // ready for next pass
    __syncthreads();
    if (t == 0) {
        int r = rem[b];
        unsigned int bsel = 0u;
        for (int bin = 255; bin >= 0; bin--) {
            int c = (int)h[bin];
            if (c >= r) { bsel = (unsigned int)bin; break; }
            r -= c;
        }
        rem[b] = r;
        pfx[b] |= bsel << shift;
    }
}

// ---------------- top-k: write mask for >T, count ties per chunk --------------
__global__ __launch_bounds__(256) void topk_mask1(
    const float* __restrict__ imp, const unsigned int* __restrict__ pfx,
    float* __restrict__ mask, int* __restrict__ blocktie)
{
    int b = blockIdx.x / NCHUNK, ch = blockIdx.x % NCHUNK;
    int t = threadIdx.x;
    unsigned int T = pfx[b];
    float4 v = ((const float4*)(imp + b * PPIX + ch * 1024))[t];
    unsigned int bb[4] = {__float_as_uint(v.x), __float_as_uint(v.y),
                          __float_as_uint(v.z), __float_as_uint(v.w)};
    float4 mo;
    float* mp = &mo.x;
    int cnt = 0;
    #pragma unroll
    for (int k = 0; k < 4; k++) {
        mp[k] = (bb[k] > T) ? 1.f : 0.f;
        cnt += (bb[k] == T) ? 1 : 0;
    }
    ((float4*)(mask + b * PPIX + ch * 1024))[t] = mo;
    #pragma unroll
    for (int off = 32; off > 0; off >>= 1) cnt += __shfl_down(cnt, off);
    __shared__ int ws4[4];
    int lane = t & 63, wv = t >> 6;
    if (lane == 0) ws4[wv] = cnt;
    __syncthreads();
    if (t == 0) blocktie[b * NCHUNK + ch] = ws4[0] + ws4[1] + ws4[2] + ws4[3];
}

// ---------------- top-k: set first `rem` ties in index order ------------------
__global__ __launch_bounds__(256) void topk_mask2(
    const float* __restrict__ imp, const unsigned int* __restrict__ pfx,
    const int* __restrict__ rem_, const int* __restrict__ blocktie,
    float* __restrict__ mask)
{
    int b = blockIdx.x;
    int t = threadIdx.x, lane = t & 63, wv = t >> 6;
    unsigned int T = pfx[b];
    int rem = rem_[b];
    __shared__ int sbase[NCHUNK], scnt[NCHUNK];
    if (t == 0) {
        int s = 0;
        for (int i = 0; i < NCHUNK; i++) {
            sbase[i] = s;
            int c = blocktie[b * NCHUNK + i];
            scnt[i] = c;
            s += c;
        }
    }
    __syncthreads();
    __shared__ int wtot[4];
    for (int ch = 0; ch < NCHUNK; ch++) {
        if (scnt[ch] == 0) continue;       // uniform across block
        int base = sbase[ch];
        if (base >= rem) break;            // uniform across block
        for (int g = 0; g < 4; g++) {
            int i = b * PPIX + ch * 1024 + g * 256 + t;
            int flag = (__float_as_uint(imp[i]) == T) ? 1 : 0;
            unsigned long long bal = __ballot(flag);
            if (lane == 0) wtot[wv] = __popcll(bal);
            __syncthreads();
            int wbase = 0, tot = 0;
            for (int q = 0; q < 4; q++) { int c = wtot[q]; if (q < wv) wbase += c; tot += c; }
            if (flag && base + wbase + __popcll(bal & ((1ull << lane) - 1ull)) < rem)
                mask[i] = 1.f;
            base += tot;
            __syncthreads();
        }
    }
}

// ---------------- level 0 fused: masked dwconv3x3 -> 1x1, y0 + partials -------
__global__ __launch_bounds__(256, 4) void level0_kernel(
    const float* __restrict__ x, const float* __restrict__ mask,
    const float* __restrict__ w_in, const float* __restrict__ b_in,
    const float* __restrict__ dw_w, const float* __restrict__ pw_w,
    const float* __restrict__ pw_b,
    float* __restrict__ y_out, float* __restrict__ partials)
{
    __shared__ float D[64][64];
    __shared__ float4 sW[1024];
    __shared__ float sred[128];
    int t = threadIdx.x;
    int swz = (blockIdx.x & 7) * 784 + (blockIdx.x >> 3);
    int b = swz / 784;
    int lane = t & 63, og = t >> 6;
    int p = (swz % 784) * 64 + lane;
    int h = p / WDIM, w = p % WDIM;
    for (int i = t; i < 1024; i += 256) sW[i] = ((const float4*)pw_w)[i];

    int rowoff[3]; float okhf[3];
    int wcs[3]; float okwf[3];
    #pragma unroll
    for (int k = 0; k < 3; k++) {
        int hh = h + k - 1;
        okhf[k] = (hh >= 0 && hh < HDIM) ? 1.f : 0.f;
        rowoff[k] = min(max(hh, 0), HDIM - 1) * WDIM;
        int ww = w + k - 1;
        okwf[k] = (ww >= 0 && ww < WDIM) ? 1.f : 0.f;
        wcs[k] = min(max(ww, 0), WDIM - 1);
    }

    float mv[9], mxv[9];
    const float* mb = mask + b * PPIX;
    const float* xb = x + b * PPIX;
    #pragma unroll
    for (int ky = 0; ky < 3; ky++) {
        #pragma unroll
        for (int kx = 0; kx < 3; kx++) {
            int a = rowoff[ky] + wcs[kx];
            float mm = mb[a] * (okhf[ky] * okwf[kx]);
            mv[ky * 3 + kx] = mm;
            mxv[ky * 3 + kx] = mm * xb[a];
        }
    }
    #pragma unroll
    for (int j = 0; j < 16; j++) {
        int c = og * 16 + j;
        float wk = w_in[64 + c], bk = b_in[64 + c];
        const float* dwr = dw_w + c * 9;
        float a0 = 0.f, a1 = 0.f;
        #pragma unroll
        for (int tp = 0; tp < 9; tp++) {
            float dv = dwr[tp];
            a0 += dv * mxv[tp];
            a1 += dv * mv[tp];
        }
        D[c][lane] = wk * a0 + bk * a1;
    }
    __syncthreads();

    float d[64];
    #pragma unroll
    for (int c = 0; c < 64; c++) d[c] = D[c][lane];

    #pragma unroll
    for (int j = 0; j < 16; j++) {
        int o = og * 16 + j;
        float acc = pw_b[o];
        #pragma unroll
        for (int c4 = 0; c4 < 16; c4++) {
            float4 wv = sW[o * 16 + c4];
            acc += wv.x * d[4 * c4] + wv.y * d[4 * c4 + 1]
                 + wv.z * d[4 * c4 + 2] + wv.w * d[4 * c4 + 3];
        }
        y_out[(size_t)(b * 64 + o) * PPIX + p] = acc;
        float s = acc, s2 = acc * acc;
        #pragma unroll
        for (int off = 32; off > 0; off >>= 1) {
            s += __shfl_down(s, off);
            s2 += __shfl_down(s2, off);
        }
        if (lane == 0) { sred[2 * o] = s; sred[2 * o + 1] = s2; }
    }
    __syncthreads();
    if (t < 128) partials[(size_t)blockIdx.x * 128 + t] = sred[t];
}

// ---------------- dilated dwconv: LDS-staged band, relu(bn(prev)) input -------
template<int KSZ, int DIL>
__global__ __launch_bounds__(256, 4) void dw_kernel(
    const float* __restrict__ in, const float* __restrict__ bnp,
    const float* __restrict__ dw_w, float* __restrict__ out)
{
    constexpr int PAD = (KSZ / 2) * DIL;
    constexpr int BH = 16;
    constexpr int LR = BH + 2 * PAD;        // staged rows
    constexpr int SW = WDIM + 2 * PAD;      // padded width
    __shared__ float sIn[LR * SW];

    int t = threadIdx.x;
    int swz = (blockIdx.x & 7) * (NDWBLK / 8) + (blockIdx.x >> 3);
    int bc = swz / NBAND, band = swz % NBAND;
    int c = bc & 63;
    int r0 = band * BH;
    float sc = bnp[c], sh = bnp[64 + c];
    const float* plane = in + (size_t)bc * PPIX;

    for (int i = t; i < LR * SW; i += 256) sIn[i] = 0.f;
    __syncthreads();
    for (int i = t; i < LR * 56; i += 256) {
        int sr = i / 56, q = i % 56;
        int gr = r0 - PAD + sr;
        if (gr >= 0 && gr < HDIM) {
            float4 v = ((const float4*)(plane + gr * WDIM))[q];
            float* drow = sIn + sr * SW + PAD + 4 * q;
            drow[0] = fmaxf(sc * v.x + sh, 0.f);
            drow[1] = fmaxf(sc * v.y + sh, 0.f);
            drow[2] = fmaxf(sc * v.z + sh, 0.f);
            drow[3] = fmaxf(sc * v.w + sh, 0.f);
        }
    }
    __syncthreads();

    const float* dwr = dw_w + c * KSZ * KSZ;
    float wk[KSZ * KSZ];
    #pragma unroll
    for (int i = 0; i < KSZ * KSZ; i++) wk[i] = dwr[i];

    float* oplane = out + (size_t)bc * PPIX + r0 * WDIM;
    for (int oi = 0; oi < (BH * WDIM) / 256; oi++) {
        int o = oi * 256 + t;
        int orow = o / WDIM, ocol = o % WDIM;
        const float* sbase = sIn + orow * SW + ocol;
        float acc = 0.f;
        #pragma unroll
        for (int ky = 0; ky < KSZ; ky++)
            #pragma unroll
            for (int kx = 0; kx < KSZ; kx++)
                acc += sbase[(ky * DIL) * SW + kx * DIL] * wk[ky * KSZ + kx];
        oplane[o] = acc;
    }
}

// ---------------- pointwise 64x64 matvec, IN-PLACE, + bn partials -------------
__global__ __launch_bounds__(256, 2) void pw_kernel(
    const float* __restrict__ pw_w, const float* __restrict__ pw_b,
    float* __restrict__ y, float* __restrict__ partials)
{
    __shared__ float D[64][64];
    __shared__ float4 sW[1024];
    __shared__ float sred[128];
    int t = threadIdx.x;
    int swz = (blockIdx.x & 7) * 784 + (blockIdx.x >> 3);
    int b = swz / 784;
    int lane = t & 63, og = t >> 6;
    int p0 = (swz % 784) * 64;
    for (int i = t; i < 1024; i += 256) sW[i] = ((const float4*)pw_w)[i];

    float* ybase = y + (size_t)b * 64 * PPIX + p0;
    for (int i = t; i < 1024; i += 256) {
        int cc = i >> 4, q = i & 15;
        float4 v = *(const float4*)(ybase + (size_t)cc * PPIX + 4 * q);
        ((float4*)&D[cc][0])[q] = v;
    }
    __syncthreads();   // all reads complete before any in-place write

    float d[64];
    #pragma unroll
    for (int cq = 0; cq < 64; cq++) d[cq] = D[cq][lane];

    #pragma unroll
    for (int j = 0; j < 16; j++) {
        int o = og * 16 + j;
        float acc = pw_b[o];
        #pragma unroll
        for (int c4 = 0; c4 < 16; c4++) {
            float4 wv = sW[o * 16 + c4];
            acc += wv.x * d[4 * c4] + wv.y * d[4 * c4 + 1]
                 + wv.z * d[4 * c4 + 2] + wv.w * d[4 * c4 + 3];
        }
        ybase[(size_t)o * PPIX + lane] = acc;
        float s = acc, s2 = acc * acc;
        #pragma unroll
        for (int off = 32; off > 0; off >>= 1) {
            s += __shfl_down(s, off);
            s2 += __shfl_down(s2, off);
        }
        if (lane == 0) { sred[2 * o] = s; sred[2 * o + 1] = s2; }
    }
    __syncthreads();
    if (t < 128) partials[(size_t)blockIdx.x * 128 + t] = sred[t];
}

// ---------------- bn finalize: tree-reduce partials, one block per channel ----
__global__ __launch_bounds__(256) void bnfin_kernel(
    const float* __restrict__ partials,
    const float* __restrict__ g, const float* __restrict__ be,
    float* __restrict__ bnp)
{
    int c = blockIdx.x; // 0..63
    int t = threadIdx.x;
    float s = 0.f, s2 = 0.f;
    for (int blk = t; blk < NBLK; blk += 256) {
        s  += partials[(size_t)blk * 128 + 2 * c];
        s2 += partials[(size_t)blk * 128 + 2 * c + 1];
    }
    #pragma unroll
    for (int off = 32; off > 0; off >>= 1) {
        s += __shfl_down(s, off);
        s2 += __shfl_down(s2, off);
    }
    __shared__ float wsm[8];
    int lane = t & 63, wv = t >> 6;
    if (lane == 0) { wsm[wv] = s; wsm[4 + wv] = s2; }
    __syncthreads();
    if (t == 0) {
        s = wsm[0] + wsm[1] + wsm[2] + wsm[3];
        s2 = wsm[4] + wsm[5] + wsm[6] + wsm[7];
        const float inv_n = 1.f / (float)NPIX;
        float mu = s * inv_n;
        float var = s2 * inv_n - mu * mu;
        float sc = g[c] * rsqrtf(var + 1e-5f);
        bnp[c] = sc;
        bnp[64 + c] = be[c] - mu * sc;
    }
}

// ---------------- K_global: per (b,c) spatial mean of relu(bn(y2)) ------------
__global__ __launch_bounds__(256) void kglobal_kernel(
    const float* __restrict__ y2, const float* __restrict__ bnp2,
    float* __restrict__ kg)
{
    int bc = blockIdx.x; // 0..511
    int c = bc & 63;
    int t = threadIdx.x;
    const float* row = y2 + (size_t)bc * PPIX;
    float sc = bnp2[c], sh = bnp2[64 + c];
    float s = 0.f;
    for (int i = t; i < PPIX; i += 256) s += fmaxf(sc * row[i] + sh, 0.f);
    #pragma unroll
    for (int off = 32; off > 0; off >>= 1) s += __shfl_down(s, off);
    __shared__ float wsum[4];
    int lane = t & 63, wv = t >> 6;
    if (lane == 0) wsum[wv] = s;
    __syncthreads();
    if (t == 0) kg[bc] = (wsum[0] + wsum[1] + wsum[2] + wsum[3]) * (1.f / (float)PPIX);
}

// ---------------- final: aggregate + V + QV + out + x_proj --------------------
__global__ __launch_bounds__(256, 2) void final_kernel(
    const float* __restrict__ x, const float* __restrict__ w_in,
    const float* __restrict__ b_in,
    const float* __restrict__ y0, const float* __restrict__ y1,
    const float* __restrict__ y2,
    const float* __restrict__ bnp, const float* __restrict__ kg,
    const float* __restrict__ val_w, const float* __restrict__ val_b,
    const float* __restrict__ out_w, const float* __restrict__ out_b,
    const float* __restrict__ coeffs, float* __restrict__ out)
{
    __shared__ float KF[64][64];
    __shared__ float4 sVW[1024];
    __shared__ float4 sOW[1024];
    int t = threadIdx.x;
    int blk = blockIdx.x;
    int b = blk / 784;
    int lane = t & 63, og = t >> 6;
    int p = (blk % 784) * 64 + lane;
    for (int i = t; i < 1024; i += 256) {
        sVW[i] = ((const float4*)val_w)[i];
        sOW[i] = ((const float4*)out_w)[i];
    }

    float xv = x[b * PPIX + p];
    float g0 = xv * w_in[128] + b_in[128];
    float g1 = xv * w_in[129] + b_in[129];
    float g2 = xv * w_in[130] + b_in[130];
    float g3 = xv * w_in[131] + b_in[131];
    float mx = fmaxf(fmaxf(g0, g1), fmaxf(g2, g3));
    float e0 = expf(g0 - mx), e1 = expf(g1 - mx), e2 = expf(g2 - mx), e3 = expf(g3 - mx);
    float inv = 1.f / (e0 + e1 + e2 + e3);
    float G0 = e0 * inv, G1 = e1 * inv, G2 = e2 * inv, G3 = e3 * inv;

    #pragma unroll
    for (int j = 0; j < 16; j++) {
        int c = og * 16 + j;
        size_t idx = (size_t)(b * 64 + c) * PPIX + p;
        float f0 = fmaxf(bnp[c] * y0[idx] + bnp[64 + c], 0.f);
        float f1 = fmaxf(bnp[128 + c] * y1[idx] + bnp[192 + c], 0.f);
        float f2 = fmaxf(bnp[256 + c] * y2[idx] + bnp[320 + c], 0.f);
        KF[c][lane] = G0 * f0 + G1 * f1 + G2 * f2 + G3 * kg[b * 64 + c];
    }
    __syncthreads();

    float kf[64];
    #pragma unroll
    for (int c = 0; c < 64; c++) kf[c] = KF[c][lane];

    float V[16];
    #pragma unroll
    for (int j = 0; j < 16; j++) {
        int o = og * 16 + j;
        float acc = val_b[o];
        #pragma unroll
        for (int c4 = 0; c4 < 16; c4++) {
            float4 wv = sVW[o * 16 + c4];
            acc += wv.x * kf[4 * c4] + wv.y * kf[4 * c4 + 1]
                 + wv.z * kf[4 * c4 + 2] + wv.w * kf[4 * c4 + 3];
        }
        V[j] = acc;
    }
    __syncthreads();
    #pragma unroll
    for (int j = 0; j < 16; j++) {
        int o = og * 16 + j;
        float q = xv * w_in[o] + b_in[o];
        KF[o][lane] = q * V[j];
    }
    __syncthreads();

    float tq[64];
    #pragma unroll
    for (int c = 0; c < 64; c++) tq[c] = KF[c][lane];

    #pragma unroll
    for (int j = 0; j < 16; j++) {
        int o = og * 16 + j;
        float acc = out_b[o];
        #pragma unroll
        for (int c4 = 0; c4 < 16; c4++) {
            float4 wv = sOW[o * 16 + c4];
            acc += wv.x * tq[4 * c4] + wv.y * tq[4 * c4 + 1]
                 + wv.z * tq[4 * c4 + 2] + wv.w * tq[4 * c4 + 3];
        }
        out[(size_t)(b * 64 + o) * PPIX + p] = acc + xv * coeffs[32 + o] + coeffs[96 + o];
    }
}

extern "C" void kernel_launch(void* const* d_in, const int* in_sizes, int n_in,
                              void* d_out, int out_size, void* d_ws, size_t ws_size,
                              hipStream_t stream)
{
    (void)in_sizes; (void)n_in; (void)out_size; (void)ws_size;
    const float* x      = (const float*)d_in[0];
    const float* w_in   = (const float*)d_in[1];
    const float* b_in   = (const float*)d_in[2];
    const float* dw0    = (const float*)d_in[3];
    const float* pw0_w  = (const float*)d_in[4];
    const float* pw0_b  = (const float*)d_in[5];
    const float* bn0_g  = (const float*)d_in[6];
    const float* bn0_b  = (const float*)d_in[7];
    const float* dw1    = (const float*)d_in[8];
    const float* pw1_w  = (const float*)d_in[9];
    const float* pw1_b  = (const float*)d_in[10];
    const float* bn1_g  = (const float*)d_in[11];
    const float* bn1_b  = (const float*)d_in[12];
    const float* dw2    = (const float*)d_in[13];
    const float* pw2_w  = (const float*)d_in[14];
    const float* pw2_b  = (const float*)d_in[15];
    const float* bn2_g  = (const float*)d_in[16];
    const float* bn2_b  = (const float*)d_in[17];
    const float* imp_w1 = (const float*)d_in[18];
    const float* imp_b1 = (const float*)d_in[19];
    const float* imp_w2 = (const float*)d_in[20];
    const float* imp_b2 = (const float*)d_in[21];
    const float* val_w  = (const float*)d_in[22];
    const float* val_b  = (const float*)d_in[23];
    const float* out_w  = (const float*)d_in[24];
    const float* out_b  = (const float*)d_in[25];
    const float* fin_w  = (const float*)d_in[26];
    const float* fin_b  = (const float*)d_in[27];

    float* ws   = (float*)d_ws;
    float* y0   = ws;
    float* y1   = ws + (size_t)NELEM;
    float* imp  = ws + (size_t)2 * NELEM;
    float* mask = imp + NPIX;
    float* partials = mask + NPIX;                // 6272*128
    float* bnp   = partials + (size_t)NBLK * 128; // 3*128
    float* kg    = bnp + 384;                     // 512
    float* coeffs = kg + 512;                     // 160
    unsigned int* ghist = (unsigned int*)(coeffs + 160);   // 8*256
    unsigned int* pfx   = ghist + 2048;                    // 8
    int* rem            = (int*)(pfx + 8);                 // 8
    int* blocktie       = rem + 8;                         // 8*49
    float* y2 = (float*)d_out;

    prep_kernel<<<1, 256, 0, stream>>>(w_in, b_in, imp_w1, imp_b1, fin_w, fin_b,
                                       coeffs, ghist, pfx, rem);
    imp_kernel<<<NPIX / 256, 256, 0, stream>>>(x, coeffs, imp_w2, imp_b2, imp);

    for (int shift = 24; shift >= 0; shift -= 8) {
        topk_hist<<<BATCH * NCHUNK, 256, 0, stream>>>(imp, pfx, ghist, shift);
        topk_select<<<BATCH, 256, 0, stream>>>(ghist, pfx, rem, shift);
    }
    topk_mask1<<<BATCH * NCHUNK, 256, 0, stream>>>(imp, pfx, mask, blocktie);
    topk_mask2<<<BATCH, 256, 0, stream>>>(imp, pfx, rem, blocktie, mask);

    level0_kernel<<<NBLK, 256, 0, stream>>>(x, mask, w_in, b_in, dw0, pw0_w, pw0_b,
                                            y0, partials);
    bnfin_kernel<<<64, 256, 0, stream>>>(partials, bn0_g, bn0_b, bnp);

    dw_kernel<5, 2><<<NDWBLK, 256, 0, stream>>>(y0, bnp, dw1, y1);
    pw_kernel<<<NBLK, 256, 0, stream>>>(pw1_w, pw1_b, y1, partials);
    bnfin_kernel<<<64, 256, 0, stream>>>(partials, bn1_g, bn1_b, bnp + 128);

    dw_kernel<7, 4><<<NDWBLK, 256, 0, stream>>>(y1, bnp + 128, dw2, y2);
    pw_kernel<<<NBLK, 256, 0, stream>>>(pw2_w, pw2_b, y2, partials);
    bnfin_kernel<<<64, 256, 0, stream>>>(partials, bn2_g, bn2_b, bnp + 256);

    kglobal_kernel<<<512, 256, 0, stream>>>(y2, bnp + 256, kg);
    final_kernel<<<NBLK, 256, 0, stream>>>(x, w_in, b_in, y0, y1, y2, bnp, kg,
                                           val_w, val_b, out_w, out_b, coeffs, y2);
}

// Round 6
// 593.519 us; speedup vs baseline: 14.5592x; 1.6844x over previous
//
#include <hip/hip_runtime.h>

#define HDIM 224
#define WDIM 224
#define PPIX 50176      // 224*224
#define BATCH 8
#define NPIX 401408     // 8*50176
#define KTOP 15052      // max(int(0.3*224*224), 64)
#define NELEM 25690112  // 8*64*50176
#define NBLK 6272       // 8*784 strip grid
#define NBAND 14        // 224/16
#define NDWBLK 7168     // 8*64*14
#define NCHUNK 49       // PPIX / 1024

typedef __attribute__((ext_vector_type(8))) short bf8_t;
typedef __attribute__((ext_vector_type(4))) float f4_t;
#define MFMA_BF16 __builtin_amdgcn_mfma_f32_16x16x32_bf16

// round-to-nearest-even f32 -> bf16
__device__ inline unsigned short f2bf(float f) {
    unsigned int u = __float_as_uint(f);
    return (unsigned short)((u + 0x7FFFu + ((u >> 16) & 1u)) >> 16);
}

// stage a 64x64 fp32 matrix into swizzled bf16 LDS ([row][72] shorts, 144B rows,
// byte-in-row = 2*col XOR ((row&7)<<4)). 256 threads.
__device__ inline void stage_w64(const float* __restrict__ W, char* sWc, int t) {
    int o = t >> 2, c0 = (t & 3) * 16;
    const float4* src = (const float4*)(W + o * 64 + c0);
    float4 v0 = src[0], v1 = src[1], v2 = src[2], v3 = src[3];
    bf8_t p0, p1;
    p0[0] = (short)f2bf(v0.x); p0[1] = (short)f2bf(v0.y);
    p0[2] = (short)f2bf(v0.z); p0[3] = (short)f2bf(v0.w);
    p0[4] = (short)f2bf(v1.x); p0[5] = (short)f2bf(v1.y);
    p0[6] = (short)f2bf(v1.z); p0[7] = (short)f2bf(v1.w);
    p1[0] = (short)f2bf(v2.x); p1[1] = (short)f2bf(v2.y);
    p1[2] = (short)f2bf(v2.z); p1[3] = (short)f2bf(v2.w);
    p1[4] = (short)f2bf(v3.x); p1[5] = (short)f2bf(v3.y);
    p1[6] = (short)f2bf(v3.z); p1[7] = (short)f2bf(v3.w);
    int sw = (o & 7) << 4;
    *(bf8_t*)(sWc + o * 144 + ((2 * c0) ^ sw)) = p0;
    *(bf8_t*)(sWc + o * 144 + ((2 * c0 + 16) ^ sw)) = p1;
}

// C[64o x 64p] = W(64x64, sWc) @ P([p][c] transposed, sPc); wave wv owns rows m0..m0+15.
// A layout: m=lane&15, k=8*(lane>>4)+j ; B: n=lane&15, k=8*(lane>>4)+j ;
// C/D: n=lane&15, m=(lane>>4)*4+reg  [C/D HW-verified; A/B CDNA3-pattern]
__device__ inline void mfma64(const char* sWc, const char* sPc, int l, int m0, f4_t acc[4]) {
    int lr = l & 15, lg = l >> 4, sw = (lr & 7) << 4;
    const char* arow = sWc + (m0 + lr) * 144;
    bf8_t a0 = *(const bf8_t*)(arow + ((16 * lg) ^ sw));
    bf8_t a1 = *(const bf8_t*)(arow + ((64 + 16 * lg) ^ sw));
    #pragma unroll
    for (int nt = 0; nt < 4; nt++) {
        const char* prow = sPc + (nt * 16 + lr) * 144;
        bf8_t b0 = *(const bf8_t*)(prow + ((16 * lg) ^ sw));
        bf8_t b1 = *(const bf8_t*)(prow + ((64 + 16 * lg) ^ sw));
        f4_t c = {0.f, 0.f, 0.f, 0.f};
        c = MFMA_BF16(a0, b0, c, 0, 0, 0);
        c = MFMA_BF16(a1, b1, c, 0, 0, 0);
        acc[nt] = c;
    }
}

// ---------------- prep: tiny derived coefficients + topk state init ----------
__global__ __launch_bounds__(256) void prep_kernel(
    const float* __restrict__ w_in, const float* __restrict__ b_in,
    const float* __restrict__ imp_w1, const float* __restrict__ imp_b1,
    const float* __restrict__ fin_w, const float* __restrict__ fin_b,
    float* __restrict__ coeffs, unsigned int* __restrict__ ghist,
    unsigned int* __restrict__ pfx, int* __restrict__ rem)
{
    int t = threadIdx.x;
    if (t < 16) {
        float a = 0.f, d = 0.f;
        for (int c = 0; c < 64; c++) {
            a += imp_w1[t * 64 + c] * w_in[64 + c];
            d += imp_w1[t * 64 + c] * b_in[64 + c];
        }
        coeffs[t] = a;
        coeffs[16 + t] = d + imp_b1[t];
    }
    if (t < 64) {
        float a = 0.f, d = 0.f;
        for (int c = 0; c < 64; c++) {
            a += fin_w[t * 64 + c] * w_in[c];
            d += fin_w[t * 64 + c] * b_in[c];
        }
        coeffs[32 + t] = a;
        coeffs[96 + t] = d + fin_b[t];
    }
    for (int i = t; i < 2048; i += 256) ghist[i] = 0u;
    if (t < BATCH) { pfx[t] = 0u; rem[t] = KTOP; }
}

// ---------------- importance map: sigmoid(conv3x3(relu(x*a+d), w2)+b2) --------
__global__ __launch_bounds__(256) void imp_kernel(
    const float* __restrict__ x, const float* __restrict__ coeffs,
    const float* __restrict__ imp_w2, const float* __restrict__ imp_b2,
    float* __restrict__ imp)
{
    int idx = blockIdx.x * 256 + threadIdx.x;
    int b = idx / PPIX, p = idx % PPIX;
    int h = p / WDIM, w = p % WDIM;
    float acc = imp_b2[0];
    #pragma unroll
    for (int ky = 0; ky < 3; ky++) {
        int hh = h + ky - 1;
        float okh = (hh >= 0 && hh < HDIM) ? 1.f : 0.f;
        int hc = min(max(hh, 0), HDIM - 1);
        #pragma unroll
        for (int kx = 0; kx < 3; kx++) {
            int ww = w + kx - 1;
            float ok = okh * ((ww >= 0 && ww < WDIM) ? 1.f : 0.f);
            int wc = min(max(ww, 0), WDIM - 1);
            float xv = x[b * PPIX + hc * WDIM + wc] * ok;
            #pragma unroll
            for (int c = 0; c < 16; c++) {
                float r = fmaxf(xv * coeffs[c] + coeffs[16 + c] * ok, 0.f);
                acc += r * imp_w2[c * 9 + ky * 3 + kx];
            }
        }
    }
    imp[idx] = 1.f / (1.f + expf(-acc));
}

// ---------------- parallel exact top-k: radix histogram pass ------------------
__global__ __launch_bounds__(256) void topk_hist(
    const float* __restrict__ imp, const unsigned int* __restrict__ pfx,
    unsigned int* __restrict__ ghist, int shift)
{
    int b = blockIdx.x / NCHUNK, ch = blockIdx.x % NCHUNK;
    int t = threadIdx.x;
    __shared__ unsigned int hist[256];
    hist[t] = 0u;
    __syncthreads();
    unsigned int prefix = pfx[b];
    unsigned int himask = (shift == 24) ? 0u : (0xFFFFFFFFu << (shift + 8));
    float4 v = ((const float4*)(imp + b * PPIX + ch * 1024))[t];
    unsigned int bb[4] = {__float_as_uint(v.x), __float_as_uint(v.y),
                          __float_as_uint(v.z), __float_as_uint(v.w)};
    #pragma unroll
    for (int k = 0; k < 4; k++)
        if ((bb[k] & himask) == prefix)
            atomicAdd(&hist[(bb[k] >> shift) & 255u], 1u);
    __syncthreads();
    unsigned int c = hist[t];
    if (c) atomicAdd(&ghist[b * 256 + t], c);
}

// ---------------- top-k: select bin, update prefix/remaining, zero hist -------
__global__ __launch_bounds__(256) void topk_select(
    unsigned int* __restrict__ ghist, unsigned int* __restrict__ pfx,
    int* __restrict__ rem, int shift)
{
    int b = blockIdx.x;
    int t = threadIdx.x;
    __shared__ unsigned int h[256];
    h[t] = ghist[b * 256 + t];
    ghist[b * 256 + t] = 0u;
    __syncthreads();
    if (t == 0) {
        int r = rem[b];
        unsigned int bsel = 0u;
        for (int bin = 255; bin >= 0; bin--) {
            int c = (int)h[bin];
            if (c >= r) { bsel = (unsigned int)bin; break; }
            r -= c;
        }
        rem[b] = r;
        pfx[b] |= bsel << shift;
    }
}

// ---------------- top-k: write mask for >T, count ties per chunk --------------
__global__ __launch_bounds__(256) void topk_mask1(
    const float* __restrict__ imp, const unsigned int* __restrict__ pfx,
    float* __restrict__ mask, int* __restrict__ blocktie)
{
    int b = blockIdx.x / NCHUNK, ch = blockIdx.x % NCHUNK;
    int t = threadIdx.x;
    unsigned int T = pfx[b];
    float4 v = ((const float4*)(imp + b * PPIX + ch * 1024))[t];
    unsigned int bb[4] = {__float_as_uint(v.x), __float_as_uint(v.y),
                          __float_as_uint(v.z), __float_as_uint(v.w)};
    float4 mo;
    float* mp = &mo.x;
    int cnt = 0;
    #pragma unroll
    for (int k = 0; k < 4; k++) {
        mp[k] = (bb[k] > T) ? 1.f : 0.f;
        cnt += (bb[k] == T) ? 1 : 0;
    }
    ((float4*)(mask + b * PPIX + ch * 1024))[t] = mo;
    #pragma unroll
    for (int off = 32; off > 0; off >>= 1) cnt += __shfl_down(cnt, off);
    __shared__ int ws4[4];
    int lane = t & 63, wv = t >> 6;
    if (lane == 0) ws4[wv] = cnt;
    __syncthreads();
    if (t == 0) blocktie[b * NCHUNK + ch] = ws4[0] + ws4[1] + ws4[2] + ws4[3];
}

// ---------------- top-k: set first `rem` ties in index order ------------------
__global__ __launch_bounds__(256) void topk_mask2(
    const float* __restrict__ imp, const unsigned int* __restrict__ pfx,
    const int* __restrict__ rem_, const int* __restrict__ blocktie,
    float* __restrict__ mask)
{
    int b = blockIdx.x;
    int t = threadIdx.x, lane = t & 63, wv = t >> 6;
    unsigned int T = pfx[b];
    int rem = rem_[b];
    __shared__ int sbase[NCHUNK], scnt[NCHUNK];
    if (t == 0) {
        int s = 0;
        for (int i = 0; i < NCHUNK; i++) {
            sbase[i] = s;
            int c = blocktie[b * NCHUNK + i];
            scnt[i] = c;
            s += c;
        }
    }
    __syncthreads();
    __shared__ int wtot[4];
    for (int ch = 0; ch < NCHUNK; ch++) {
        if (scnt[ch] == 0) continue;
        int base = sbase[ch];
        if (base >= rem) break;
        for (int g = 0; g < 4; g++) {
            int i = b * PPIX + ch * 1024 + g * 256 + t;
            int flag = (__float_as_uint(imp[i]) == T) ? 1 : 0;
            unsigned long long bal = __ballot(flag);
            if (lane == 0) wtot[wv] = __popcll(bal);
            __syncthreads();
            int wbase = 0, tot = 0;
            for (int q = 0; q < 4; q++) { int c = wtot[q]; if (q < wv) wbase += c; tot += c; }
            if (flag && base + wbase + __popcll(bal & ((1ull << lane) - 1ull)) < rem)
                mask[i] = 1.f;
            base += tot;
            __syncthreads();
        }
    }
}

// ---------------- level 0: masked dwconv3x3 -> MFMA 1x1, y0 + partials --------
__global__ __launch_bounds__(256, 4) void level0_kernel(
    const float* __restrict__ x, const float* __restrict__ mask,
    const float* __restrict__ w_in, const float* __restrict__ b_in,
    const float* __restrict__ dw_w, const float* __restrict__ pw_w,
    const float* __restrict__ pw_b,
    float* __restrict__ y_out, float* __restrict__ partials)
{
    __shared__ __align__(16) short sW[64 * 72];
    __shared__ __align__(16) short sP[64 * 72];
    __shared__ float sred[128];
    __shared__ float sBias[64];
    char* sWc = (char*)sW; char* sPc = (char*)sP;
    int t = threadIdx.x;
    int swz = (blockIdx.x & 7) * 784 + (blockIdx.x >> 3);
    int b = swz / 784;
    int l = t & 63, og = t >> 6;
    int p = (swz % 784) * 64 + l;
    int p0 = (swz % 784) * 64;
    int h = p / WDIM, w = p % WDIM;
    stage_w64(pw_w, sWc, t);
    if (t < 64) sBias[t] = pw_b[t];

    int rowoff[3]; float okhf[3];
    int wcs[3]; float okwf[3];
    #pragma unroll
    for (int k = 0; k < 3; k++) {
        int hh = h + k - 1;
        okhf[k] = (hh >= 0 && hh < HDIM) ? 1.f : 0.f;
        rowoff[k] = min(max(hh, 0), HDIM - 1) * WDIM;
        int ww = w + k - 1;
        okwf[k] = (ww >= 0 && ww < WDIM) ? 1.f : 0.f;
        wcs[k] = min(max(ww, 0), WDIM - 1);
    }
    float mv[9], mxv[9];
    const float* mb = mask + b * PPIX;
    const float* xb = x + b * PPIX;
    #pragma unroll
    for (int ky = 0; ky < 3; ky++) {
        #pragma unroll
        for (int kx = 0; kx < 3; kx++) {
            int a = rowoff[ky] + wcs[kx];
            float mm = mb[a] * (okhf[ky] * okwf[kx]);
            mv[ky * 3 + kx] = mm;
            mxv[ky * 3 + kx] = mm * xb[a];
        }
    }
    int swl = (l & 7) << 4;
    #pragma unroll
    for (int j = 0; j < 16; j += 2) {
        float dcv[2];
        #pragma unroll
        for (int e = 0; e < 2; e++) {
            int c = og * 16 + j + e;
            float wk = w_in[64 + c], bk = b_in[64 + c];
            const float* dwr = dw_w + c * 9;
            float a0 = 0.f, a1 = 0.f;
            #pragma unroll
            for (int tp = 0; tp < 9; tp++) {
                float dv = dwr[tp];
                a0 += dv * mxv[tp];
                a1 += dv * mv[tp];
            }
            dcv[e] = wk * a0 + bk * a1;
        }
        int c = og * 16 + j;
        unsigned int pk = (unsigned int)f2bf(dcv[0]) | ((unsigned int)f2bf(dcv[1]) << 16);
        *(unsigned int*)(sPc + l * 144 + ((2 * c) ^ swl)) = pk;
    }
    __syncthreads();

    int m0 = og * 16, lr = l & 15, lg = l >> 4;
    f4_t acc[4];
    mfma64(sWc, sPc, l, m0, acc);
    float* ybase = y_out + (size_t)b * 64 * PPIX + p0;
    #pragma unroll
    for (int r = 0; r < 4; r++) {
        int o = m0 + 4 * lg + r;
        float bias = sBias[o];
        float s = 0.f, s2 = 0.f;
        #pragma unroll
        for (int nt = 0; nt < 4; nt++) {
            float yv = acc[nt][r] + bias;
            ybase[(size_t)o * PPIX + nt * 16 + lr] = yv;
            s += yv; s2 += yv * yv;
        }
        #pragma unroll
        for (int m = 1; m < 16; m <<= 1) {
            s += __shfl_xor(s, m);
            s2 += __shfl_xor(s2, m);
        }
        if (lr == 0) { sred[2 * o] = s; sred[2 * o + 1] = s2; }
    }
    __syncthreads();
    if (t < 128) partials[(size_t)blockIdx.x * 128 + t] = sred[t];
}

// ---------------- dilated dwconv: LDS-staged band, relu(bn(prev)) input -------
template<int KSZ, int DIL>
__global__ __launch_bounds__(256, 4) void dw_kernel(
    const float* __restrict__ in, const float* __restrict__ bnp,
    const float* __restrict__ dw_w, float* __restrict__ out)
{
    constexpr int PAD = (KSZ / 2) * DIL;
    constexpr int BH = 16;
    constexpr int LR = BH + 2 * PAD;
    constexpr int SW = WDIM + 2 * PAD;
    __shared__ float sIn[LR * SW];

    int t = threadIdx.x;
    int swz = (blockIdx.x & 7) * (NDWBLK / 8) + (blockIdx.x >> 3);
    int bc = swz / NBAND, band = swz % NBAND;
    int c = bc & 63;
    int r0 = band * BH;
    float sc = bnp[c], sh = bnp[64 + c];
    const float* plane = in + (size_t)bc * PPIX;

    for (int i = t; i < LR * SW; i += 256) sIn[i] = 0.f;
    __syncthreads();
    for (int i = t; i < LR * 56; i += 256) {
        int sr = i / 56, q = i % 56;
        int gr = r0 - PAD + sr;
        if (gr >= 0 && gr < HDIM) {
            float4 v = ((const float4*)(plane + gr * WDIM))[q];
            float* drow = sIn + sr * SW + PAD + 4 * q;
            drow[0] = fmaxf(sc * v.x + sh, 0.f);
            drow[1] = fmaxf(sc * v.y + sh, 0.f);
            drow[2] = fmaxf(sc * v.z + sh, 0.f);
            drow[3] = fmaxf(sc * v.w + sh, 0.f);
        }
    }
    __syncthreads();

    const float* dwr = dw_w + c * KSZ * KSZ;
    float wk[KSZ * KSZ];
    #pragma unroll
    for (int i = 0; i < KSZ * KSZ; i++) wk[i] = dwr[i];

    float* oplane = out + (size_t)bc * PPIX + r0 * WDIM;
    for (int oi = 0; oi < (BH * WDIM) / 256; oi++) {
        int o = oi * 256 + t;
        int orow = o / WDIM, ocol = o % WDIM;
        const float* sbase = sIn + orow * SW + ocol;
        float acc = 0.f;
        #pragma unroll
        for (int ky = 0; ky < KSZ; ky++)
            #pragma unroll
            for (int kx = 0; kx < KSZ; kx++)
                acc += sbase[(ky * DIL) * SW + kx * DIL] * wk[ky * KSZ + kx];
        oplane[o] = acc;
    }
}

// ---------------- pointwise 64x64 MFMA matvec, IN-PLACE, + bn partials --------
__global__ __launch_bounds__(256, 4) void pw_kernel(
    const float* __restrict__ pw_w, const float* __restrict__ pw_b,
    float* __restrict__ y, float* __restrict__ partials)
{
    __shared__ __align__(16) short sW[64 * 72];
    __shared__ __align__(16) short sP[64 * 72];
    __shared__ float sred[128];
    __shared__ float sBias[64];
    char* sWc = (char*)sW; char* sPc = (char*)sP;
    int t = threadIdx.x;
    int swz = (blockIdx.x & 7) * 784 + (blockIdx.x >> 3);
    int b = swz / 784;
    int p0 = (swz % 784) * 64;
    stage_w64(pw_w, sWc, t);
    if (t < 64) sBias[t] = pw_b[t];

    float* ybase = y + (size_t)b * 64 * PPIX + p0;
    for (int i = t; i < 1024; i += 256) {
        int c = i >> 4, q = i & 15;
        float4 v = *(const float4*)(ybase + (size_t)c * PPIX + 4 * q);
        int c2 = 2 * c;
        int rb = 4 * q;
        *(unsigned short*)(sPc + (rb + 0) * 144 + (c2 ^ (((rb + 0) & 7) << 4))) = f2bf(v.x);
        *(unsigned short*)(sPc + (rb + 1) * 144 + (c2 ^ (((rb + 1) & 7) << 4))) = f2bf(v.y);
        *(unsigned short*)(sPc + (rb + 2) * 144 + (c2 ^ (((rb + 2) & 7) << 4))) = f2bf(v.z);
        *(unsigned short*)(sPc + (rb + 3) * 144 + (c2 ^ (((rb + 3) & 7) << 4))) = f2bf(v.w);
    }
    __syncthreads();   // all in-place reads complete before any write

    int l = t & 63, wv = t >> 6, m0 = wv * 16;
    int lr = l & 15, lg = l >> 4;
    f4_t acc[4];
    mfma64(sWc, sPc, l, m0, acc);
    #pragma unroll
    for (int r = 0; r < 4; r++) {
        int o = m0 + 4 * lg + r;
        float bias = sBias[o];
        float s = 0.f, s2 = 0.f;
        #pragma unroll
        for (int nt = 0; nt < 4; nt++) {
            float yv = acc[nt][r] + bias;
            ybase[(size_t)o * PPIX + nt * 16 + lr] = yv;
            s += yv; s2 += yv * yv;
        }
        #pragma unroll
        for (int m = 1; m < 16; m <<= 1) {
            s += __shfl_xor(s, m);
            s2 += __shfl_xor(s2, m);
        }
        if (lr == 0) { sred[2 * o] = s; sred[2 * o + 1] = s2; }
    }
    __syncthreads();
    if (t < 128) partials[(size_t)blockIdx.x * 128 + t] = sred[t];
}

// ---------------- bn finalize: tree-reduce partials, one block per channel ----
__global__ __launch_bounds__(256) void bnfin_kernel(
    const float* __restrict__ partials,
    const float* __restrict__ g, const float* __restrict__ be,
    float* __restrict__ bnp)
{
    int c = blockIdx.x;
    int t = threadIdx.x;
    float s = 0.f, s2 = 0.f;
    for (int blk = t; blk < NBLK; blk += 256) {
        s  += partials[(size_t)blk * 128 + 2 * c];
        s2 += partials[(size_t)blk * 128 + 2 * c + 1];
    }
    #pragma unroll
    for (int off = 32; off > 0; off >>= 1) {
        s += __shfl_down(s, off);
        s2 += __shfl_down(s2, off);
    }
    __shared__ float wsm[8];
    int lane = t & 63, wv = t >> 6;
    if (lane == 0) { wsm[wv] = s; wsm[4 + wv] = s2; }
    __syncthreads();
    if (t == 0) {
        s = wsm[0] + wsm[1] + wsm[2] + wsm[3];
        s2 = wsm[4] + wsm[5] + wsm[6] + wsm[7];
        const float inv_n = 1.f / (float)NPIX;
        float mu = s * inv_n;
        float var = s2 * inv_n - mu * mu;
        float sc = g[c] * rsqrtf(var + 1e-5f);
        bnp[c] = sc;
        bnp[64 + c] = be[c] - mu * sc;
    }
}

// ---------------- K_global: per (b,c) spatial mean of relu(bn(y2)) ------------
__global__ __launch_bounds__(256) void kglobal_kernel(
    const float* __restrict__ y2, const float* __restrict__ bnp2,
    float* __restrict__ kg)
{
    int bc = blockIdx.x;
    int c = bc & 63;
    int t = threadIdx.x;
    const float* row = y2 + (size_t)bc * PPIX;
    float sc = bnp2[c], sh = bnp2[64 + c];
    float s = 0.f;
    for (int i = t; i < PPIX; i += 256) s += fmaxf(sc * row[i] + sh, 0.f);
    #pragma unroll
    for (int off = 32; off > 0; off >>= 1) s += __shfl_down(s, off);
    __shared__ float wsum[4];
    int lane = t & 63, wv = t >> 6;
    if (lane == 0) wsum[wv] = s;
    __syncthreads();
    if (t == 0) kg[bc] = (wsum[0] + wsum[1] + wsum[2] + wsum[3]) * (1.f / (float)PPIX);
}

// ---------------- final: aggregate + MFMA V + QV + MFMA O + x_proj ------------
__global__ __launch_bounds__(256, 4) void final_kernel(
    const float* __restrict__ x, const float* __restrict__ w_in,
    const float* __restrict__ b_in,
    const float* __restrict__ y0, const float* __restrict__ y1,
    const float* __restrict__ y2,
    const float* __restrict__ bnp, const float* __restrict__ kg,
    const float* __restrict__ val_w, const float* __restrict__ val_b,
    const float* __restrict__ out_w, const float* __restrict__ out_b,
    const float* __restrict__ coeffs, float* __restrict__ out)
{
    __shared__ __align__(16) short sVW[64 * 72];
    __shared__ __align__(16) short sOW[64 * 72];
    __shared__ __align__(16) short sP[64 * 72];
    __shared__ float sxv[64], sQW[64], sQB[64], sVB[64], sOB[64], sC1[64], sC2[64];
    char* sVWc = (char*)sVW; char* sOWc = (char*)sOW; char* sPc = (char*)sP;
    int t = threadIdx.x;
    int blk = blockIdx.x;
    int b = blk / 784;
    int l = t & 63, wv = t >> 6;
    int p0 = (blk % 784) * 64;
    stage_w64(val_w, sVWc, t);
    stage_w64(out_w, sOWc, t);
    if (t < 64) {
        sQW[t] = w_in[t]; sQB[t] = b_in[t];
        sVB[t] = val_b[t]; sOB[t] = out_b[t];
        sC1[t] = coeffs[32 + t]; sC2[t] = coeffs[96 + t];
    }

    float xv = x[b * PPIX + p0 + l];
    if (wv == 0) sxv[l] = xv;
    float g0 = xv * w_in[128] + b_in[128];
    float g1 = xv * w_in[129] + b_in[129];
    float g2 = xv * w_in[130] + b_in[130];
    float g3 = xv * w_in[131] + b_in[131];
    float mx = fmaxf(fmaxf(g0, g1), fmaxf(g2, g3));
    float e0 = expf(g0 - mx), e1 = expf(g1 - mx), e2 = expf(g2 - mx), e3 = expf(g3 - mx);
    float inv = 1.f / (e0 + e1 + e2 + e3);
    float G0 = e0 * inv, G1 = e1 * inv, G2 = e2 * inv, G3 = e3 * inv;

    int swl = (l & 7) << 4;
    #pragma unroll
    for (int j = 0; j < 16; j += 2) {
        float kfv[2];
        #pragma unroll
        for (int e = 0; e < 2; e++) {
            int c = wv * 16 + j + e;
            size_t idx = (size_t)(b * 64 + c) * PPIX + p0 + l;
            float f0 = fmaxf(bnp[c] * y0[idx] + bnp[64 + c], 0.f);
            float f1 = fmaxf(bnp[128 + c] * y1[idx] + bnp[192 + c], 0.f);
            float f2 = fmaxf(bnp[256 + c] * y2[idx] + bnp[320 + c], 0.f);
            kfv[e] = G0 * f0 + G1 * f1 + G2 * f2 + G3 * kg[b * 64 + c];
        }
        int c = wv * 16 + j;
        unsigned int pk = (unsigned int)f2bf(kfv[0]) | ((unsigned int)f2bf(kfv[1]) << 16);
        *(unsigned int*)(sPc + l * 144 + ((2 * c) ^ swl)) = pk;
    }
    __syncthreads();

    int m0 = wv * 16, lr = l & 15, lg = l >> 4;
    int sw = (lr & 7) << 4;
    f4_t accV[4];
    mfma64(sVWc, sPc, l, m0, accV);
    __syncthreads();   // all P reads done before tq overwrite

    #pragma unroll
    for (int nt = 0; nt < 4; nt++) {
        float xvp = sxv[nt * 16 + lr];
        #pragma unroll
        for (int r = 0; r < 4; r++) {
            int o = m0 + 4 * lg + r;
            float V = accV[nt][r] + sVB[o];
            float q = xvp * sQW[o] + sQB[o];
            *(unsigned short*)(sPc + (nt * 16 + lr) * 144 + ((2 * o) ^ sw)) = f2bf(q * V);
        }
    }
    __syncthreads();

    f4_t accO[4];
    mfma64(sOWc, sPc, l, m0, accO);
    #pragma unroll
    for (int nt = 0; nt < 4; nt++) {
        float xvp = sxv[nt * 16 + lr];
        #pragma unroll
        for (int r = 0; r < 4; r++) {
            int o = m0 + 4 * lg + r;
            out[(size_t)(b * 64 + o) * PPIX + p0 + nt * 16 + lr] =
                accO[nt][r] + sOB[o] + xvp * sC1[o] + sC2[o];
        }
    }
}

extern "C" void kernel_launch(void* const* d_in, const int* in_sizes, int n_in,
                              void* d_out, int out_size, void* d_ws, size_t ws_size,
                              hipStream_t stream)
{
    (void)in_sizes; (void)n_in; (void)out_size; (void)ws_size;
    const float* x      = (const float*)d_in[0];
    const float* w_in   = (const float*)d_in[1];
    const float* b_in   = (const float*)d_in[2];
    const float* dw0    = (const float*)d_in[3];
    const float* pw0_w  = (const float*)d_in[4];
    const float* pw0_b  = (const float*)d_in[5];
    const float* bn0_g  = (const float*)d_in[6];
    const float* bn0_b  = (const float*)d_in[7];
    const float* dw1    = (const float*)d_in[8];
    const float* pw1_w  = (const float*)d_in[9];
    const float* pw1_b  = (const float*)d_in[10];
    const float* bn1_g  = (const float*)d_in[11];
    const float* bn1_b  = (const float*)d_in[12];
    const float* dw2    = (const float*)d_in[13];
    const float* pw2_w  = (const float*)d_in[14];
    const float* pw2_b  = (const float*)d_in[15];
    const float* bn2_g  = (const float*)d_in[16];
    const float* bn2_b  = (const float*)d_in[17];
    const float* imp_w1 = (const float*)d_in[18];
    const float* imp_b1 = (const float*)d_in[19];
    const float* imp_w2 = (const float*)d_in[20];
    const float* imp_b2 = (const float*)d_in[21];
    const float* val_w  = (const float*)d_in[22];
    const float* val_b  = (const float*)d_in[23];
    const float* out_w  = (const float*)d_in[24];
    const float* out_b  = (const float*)d_in[25];
    const float* fin_w  = (const float*)d_in[26];
    const float* fin_b  = (const float*)d_in[27];

    float* ws   = (float*)d_ws;
    float* y0   = ws;
    float* y1   = ws + (size_t)NELEM;
    float* imp  = ws + (size_t)2 * NELEM;
    float* mask = imp + NPIX;
    float* partials = mask + NPIX;                // 6272*128
    float* bnp   = partials + (size_t)NBLK * 128; // 3*128
    float* kg    = bnp + 384;                     // 512
    float* coeffs = kg + 512;                     // 160
    unsigned int* ghist = (unsigned int*)(coeffs + 160);   // 8*256
    unsigned int* pfx   = ghist + 2048;                    // 8
    int* rem            = (int*)(pfx + 8);                 // 8
    int* blocktie       = rem + 8;                         // 8*49
    float* y2 = (float*)d_out;

    prep_kernel<<<1, 256, 0, stream>>>(w_in, b_in, imp_w1, imp_b1, fin_w, fin_b,
                                       coeffs, ghist, pfx, rem);
    imp_kernel<<<NPIX / 256, 256, 0, stream>>>(x, coeffs, imp_w2, imp_b2, imp);

    for (int shift = 24; shift >= 0; shift -= 8) {
        topk_hist<<<BATCH * NCHUNK, 256, 0, stream>>>(imp, pfx, ghist, shift);
        topk_select<<<BATCH, 256, 0, stream>>>(ghist, pfx, rem, shift);
    }
    topk_mask1<<<BATCH * NCHUNK, 256, 0, stream>>>(imp, pfx, mask, blocktie);
    topk_mask2<<<BATCH, 256, 0, stream>>>(imp, pfx, rem, blocktie, mask);

    level0_kernel<<<NBLK, 256, 0, stream>>>(x, mask, w_in, b_in, dw0, pw0_w, pw0_b,
                                            y0, partials);
    bnfin_kernel<<<64, 256, 0, stream>>>(partials, bn0_g, bn0_b, bnp);

    dw_kernel<5, 2><<<NDWBLK, 256, 0, stream>>>(y0, bnp, dw1, y1);
    pw_kernel<<<NBLK, 256, 0, stream>>>(pw1_w, pw1_b, y1, partials);
    bnfin_kernel<<<64, 256, 0, stream>>>(partials, bn1_g, bn1_b, bnp + 128);

    dw_kernel<7, 4><<<NDWBLK, 256, 0, stream>>>(y1, bnp + 128, dw2, y2);
    pw_kernel<<<NBLK, 256, 0, stream>>>(pw2_w, pw2_b, y2, partials);
    bnfin_kernel<<<64, 256, 0, stream>>>(partials, bn2_g, bn2_b, bnp + 256);

    kglobal_kernel<<<512, 256, 0, stream>>>(y2, bnp + 256, kg);
    final_kernel<<<NBLK, 256, 0, stream>>>(x, w_in, b_in, y0, y1, y2, bnp, kg,
                                           val_w, val_b, out_w, out_b, coeffs, y2);
}

// Round 7
// 568.509 us; speedup vs baseline: 15.1997x; 1.0440x over previous
//
#include <hip/hip_runtime.h>

#define HDIM 224
#define WDIM 224
#define PPIX 50176      // 224*224
#define BATCH 8
#define NPIX 401408     // 8*50176
#define KTOP 15052      // max(int(0.3*224*224), 64)
#define NELEM 25690112  // 8*64*50176
#define NBLK 6272       // 8*784 strip grid
#define NBAND 14        // 224/16
#define NDWBLK 7168     // 8*64*14
#define NCHUNK 49       // PPIX / 1024

typedef __attribute__((ext_vector_type(8))) short bf8_t;
typedef __attribute__((ext_vector_type(4))) float f4_t;
#define MFMA_BF16 __builtin_amdgcn_mfma_f32_16x16x32_bf16

// round-to-nearest-even f32 -> bf16
__device__ inline unsigned short f2bf(float f) {
    unsigned int u = __float_as_uint(f);
    return (unsigned short)((u + 0x7FFFu + ((u >> 16) & 1u)) >> 16);
}

// stage a 64x64 fp32 matrix into swizzled bf16 LDS ([row][72] shorts, 144B rows,
// byte-in-row = 2*col XOR ((row&7)<<4)). 256 threads.
__device__ inline void stage_w64(const float* __restrict__ W, char* sWc, int t) {
    int o = t >> 2, c0 = (t & 3) * 16;
    const float4* src = (const float4*)(W + o * 64 + c0);
    float4 v0 = src[0], v1 = src[1], v2 = src[2], v3 = src[3];
    bf8_t p0, p1;
    p0[0] = (short)f2bf(v0.x); p0[1] = (short)f2bf(v0.y);
    p0[2] = (short)f2bf(v0.z); p0[3] = (short)f2bf(v0.w);
    p0[4] = (short)f2bf(v1.x); p0[5] = (short)f2bf(v1.y);
    p0[6] = (short)f2bf(v1.z); p0[7] = (short)f2bf(v1.w);
    p1[0] = (short)f2bf(v2.x); p1[1] = (short)f2bf(v2.y);
    p1[2] = (short)f2bf(v2.z); p1[3] = (short)f2bf(v2.w);
    p1[4] = (short)f2bf(v3.x); p1[5] = (short)f2bf(v3.y);
    p1[6] = (short)f2bf(v3.z); p1[7] = (short)f2bf(v3.w);
    int sw = (o & 7) << 4;
    *(bf8_t*)(sWc + o * 144 + ((2 * c0) ^ sw)) = p0;
    *(bf8_t*)(sWc + o * 144 + ((2 * c0 + 16) ^ sw)) = p1;
}

// C[64o x 64p] = W(64x64, sWc) @ P([p][c] transposed, sPc); wave wv owns rows m0..m0+15.
__device__ inline void mfma64(const char* sWc, const char* sPc, int l, int m0, f4_t acc[4]) {
    int lr = l & 15, lg = l >> 4, sw = (lr & 7) << 4;
    const char* arow = sWc + (m0 + lr) * 144;
    bf8_t a0 = *(const bf8_t*)(arow + ((16 * lg) ^ sw));
    bf8_t a1 = *(const bf8_t*)(arow + ((64 + 16 * lg) ^ sw));
    #pragma unroll
    for (int nt = 0; nt < 4; nt++) {
        const char* prow = sPc + (nt * 16 + lr) * 144;
        bf8_t b0 = *(const bf8_t*)(prow + ((16 * lg) ^ sw));
        bf8_t b1 = *(const bf8_t*)(prow + ((64 + 16 * lg) ^ sw));
        f4_t c = {0.f, 0.f, 0.f, 0.f};
        c = MFMA_BF16(a0, b0, c, 0, 0, 0);
        c = MFMA_BF16(a1, b1, c, 0, 0, 0);
        acc[nt] = c;
    }
}

// ---------------- prep: tiny derived coefficients + topk state init ----------
__global__ __launch_bounds__(256) void prep_kernel(
    const float* __restrict__ w_in, const float* __restrict__ b_in,
    const float* __restrict__ imp_w1, const float* __restrict__ imp_b1,
    const float* __restrict__ fin_w, const float* __restrict__ fin_b,
    float* __restrict__ coeffs, unsigned int* __restrict__ ghist,
    unsigned int* __restrict__ pfx, int* __restrict__ rem)
{
    int t = threadIdx.x;
    if (t < 16) {
        float a = 0.f, d = 0.f;
        for (int c = 0; c < 64; c++) {
            a += imp_w1[t * 64 + c] * w_in[64 + c];
            d += imp_w1[t * 64 + c] * b_in[64 + c];
        }
        coeffs[t] = a;
        coeffs[16 + t] = d + imp_b1[t];
    }
    if (t < 64) {
        float a = 0.f, d = 0.f;
        for (int c = 0; c < 64; c++) {
            a += fin_w[t * 64 + c] * w_in[c];
            d += fin_w[t * 64 + c] * b_in[c];
        }
        coeffs[32 + t] = a;
        coeffs[96 + t] = d + fin_b[t];
    }
    for (int i = t; i < 2048; i += 256) ghist[i] = 0u;
    if (t < BATCH) { pfx[t] = 0u; rem[t] = KTOP; }
}

// ---------------- importance map: sigmoid(conv3x3(relu(x*a+d), w2)+b2) --------
__global__ __launch_bounds__(256) void imp_kernel(
    const float* __restrict__ x, const float* __restrict__ coeffs,
    const float* __restrict__ imp_w2, const float* __restrict__ imp_b2,
    float* __restrict__ imp)
{
    int idx = blockIdx.x * 256 + threadIdx.x;
    int b = idx / PPIX, p = idx % PPIX;
    int h = p / WDIM, w = p % WDIM;
    float acc = imp_b2[0];
    #pragma unroll
    for (int ky = 0; ky < 3; ky++) {
        int hh = h + ky - 1;
        float okh = (hh >= 0 && hh < HDIM) ? 1.f : 0.f;
        int hc = min(max(hh, 0), HDIM - 1);
        #pragma unroll
        for (int kx = 0; kx < 3; kx++) {
            int ww = w + kx - 1;
            float ok = okh * ((ww >= 0 && ww < WDIM) ? 1.f : 0.f);
            int wc = min(max(ww, 0), WDIM - 1);
            float xv = x[b * PPIX + hc * WDIM + wc] * ok;
            #pragma unroll
            for (int c = 0; c < 16; c++) {
                float r = fmaxf(xv * coeffs[c] + coeffs[16 + c] * ok, 0.f);
                acc += r * imp_w2[c * 9 + ky * 3 + kx];
            }
        }
    }
    imp[idx] = 1.f / (1.f + expf(-acc));
}

// ---------------- parallel exact top-k: radix histogram pass ------------------
__global__ __launch_bounds__(256) void topk_hist(
    const float* __restrict__ imp, const unsigned int* __restrict__ pfx,
    unsigned int* __restrict__ ghist, int shift)
{
    int b = blockIdx.x / NCHUNK, ch = blockIdx.x % NCHUNK;
    int t = threadIdx.x;
    __shared__ unsigned int hist[256];
    hist[t] = 0u;
    __syncthreads();
    unsigned int prefix = pfx[b];
    unsigned int himask = (shift == 24) ? 0u : (0xFFFFFFFFu << (shift + 8));
    float4 v = ((const float4*)(imp + b * PPIX + ch * 1024))[t];
    unsigned int bb[4] = {__float_as_uint(v.x), __float_as_uint(v.y),
                          __float_as_uint(v.z), __float_as_uint(v.w)};
    #pragma unroll
    for (int k = 0; k < 4; k++)
        if ((bb[k] & himask) == prefix)
            atomicAdd(&hist[(bb[k] >> shift) & 255u], 1u);
    __syncthreads();
    unsigned int c = hist[t];
    if (c) atomicAdd(&ghist[b * 256 + t], c);
}

// ---------------- top-k: select bin, update prefix/remaining, zero hist -------
__global__ __launch_bounds__(256) void topk_select(
    unsigned int* __restrict__ ghist, unsigned int* __restrict__ pfx,
    int* __restrict__ rem, int shift)
{
    int b = blockIdx.x;
    int t = threadIdx.x;
    __shared__ unsigned int h[256];
    h[t] = ghist[b * 256 + t];
    ghist[b * 256 + t] = 0u;
    __syncthreads();
    if (t == 0) {
        int r = rem[b];
        unsigned int bsel = 0u;
        for (int bin = 255; bin >= 0; bin--) {
            int c = (int)h[bin];
            if (c >= r) { bsel = (unsigned int)bin; break; }
            r -= c;
        }
        rem[b] = r;
        pfx[b] |= bsel << shift;
    }
}

// ---------------- top-k: write mask for >T, count ties per chunk --------------
__global__ __launch_bounds__(256) void topk_mask1(
    const float* __restrict__ imp, const unsigned int* __restrict__ pfx,
    float* __restrict__ mask, int* __restrict__ blocktie)
{
    int b = blockIdx.x / NCHUNK, ch = blockIdx.x % NCHUNK;
    int t = threadIdx.x;
    unsigned int T = pfx[b];
    float4 v = ((const float4*)(imp + b * PPIX + ch * 1024))[t];
    unsigned int bb[4] = {__float_as_uint(v.x), __float_as_uint(v.y),
                          __float_as_uint(v.z), __float_as_uint(v.w)};
    float4 mo;
    float* mp = &mo.x;
    int cnt = 0;
    #pragma unroll
    for (int k = 0; k < 4; k++) {
        mp[k] = (bb[k] > T) ? 1.f : 0.f;
        cnt += (bb[k] == T) ? 1 : 0;
    }
    ((float4*)(mask + b * PPIX + ch * 1024))[t] = mo;
    #pragma unroll
    for (int off = 32; off > 0; off >>= 1) cnt += __shfl_down(cnt, off);
    __shared__ int ws4[4];
    int lane = t & 63, wv = t >> 6;
    if (lane == 0) ws4[wv] = cnt;
    __syncthreads();
    if (t == 0) blocktie[b * NCHUNK + ch] = ws4[0] + ws4[1] + ws4[2] + ws4[3];
}

// ---------------- top-k: set first `rem` ties in index order ------------------
__global__ __launch_bounds__(256) void topk_mask2(
    const float* __restrict__ imp, const unsigned int* __restrict__ pfx,
    const int* __restrict__ rem_, const int* __restrict__ blocktie,
    float* __restrict__ mask)
{
    int b = blockIdx.x;
    int t = threadIdx.x, lane = t & 63, wv = t >> 6;
    unsigned int T = pfx[b];
    int rem = rem_[b];
    __shared__ int sbase[NCHUNK], scnt[NCHUNK];
    if (t == 0) {
        int s = 0;
        for (int i = 0; i < NCHUNK; i++) {
            sbase[i] = s;
            int c = blocktie[b * NCHUNK + i];
            scnt[i] = c;
            s += c;
        }
    }
    __syncthreads();
    __shared__ int wtot[4];
    for (int ch = 0; ch < NCHUNK; ch++) {
        if (scnt[ch] == 0) continue;
        int base = sbase[ch];
        if (base >= rem) break;
        for (int g = 0; g < 4; g++) {
            int i = b * PPIX + ch * 1024 + g * 256 + t;
            int flag = (__float_as_uint(imp[i]) == T) ? 1 : 0;
            unsigned long long bal = __ballot(flag);
            if (lane == 0) wtot[wv] = __popcll(bal);
            __syncthreads();
            int wbase = 0, tot = 0;
            for (int q = 0; q < 4; q++) { int c = wtot[q]; if (q < wv) wbase += c; tot += c; }
            if (flag && base + wbase + __popcll(bal & ((1ull << lane) - 1ull)) < rem)
                mask[i] = 1.f;
            base += tot;
            __syncthreads();
        }
    }
}

// ---------------- level 0: masked dwconv3x3 -> MFMA 1x1, y0 + partials --------
__global__ __launch_bounds__(256, 4) void level0_kernel(
    const float* __restrict__ x, const float* __restrict__ mask,
    const float* __restrict__ w_in, const float* __restrict__ b_in,
    const float* __restrict__ dw_w, const float* __restrict__ pw_w,
    const float* __restrict__ pw_b,
    float* __restrict__ y_out, float* __restrict__ partials)
{
    __shared__ __align__(16) short sW[64 * 72];
    __shared__ __align__(16) short sP[64 * 72];
    __shared__ float sred[128];
    __shared__ float sBias[64];
    char* sWc = (char*)sW; char* sPc = (char*)sP;
    int t = threadIdx.x;
    int swz = (blockIdx.x & 7) * 784 + (blockIdx.x >> 3);
    int b = swz / 784;
    int l = t & 63, og = t >> 6;
    int p = (swz % 784) * 64 + l;
    int p0 = (swz % 784) * 64;
    int h = p / WDIM, w = p % WDIM;
    stage_w64(pw_w, sWc, t);
    if (t < 64) sBias[t] = pw_b[t];

    int rowoff[3]; float okhf[3];
    int wcs[3]; float okwf[3];
    #pragma unroll
    for (int k = 0; k < 3; k++) {
        int hh = h + k - 1;
        okhf[k] = (hh >= 0 && hh < HDIM) ? 1.f : 0.f;
        rowoff[k] = min(max(hh, 0), HDIM - 1) * WDIM;
        int ww = w + k - 1;
        okwf[k] = (ww >= 0 && ww < WDIM) ? 1.f : 0.f;
        wcs[k] = min(max(ww, 0), WDIM - 1);
    }
    float mv[9], mxv[9];
    const float* mb = mask + b * PPIX;
    const float* xb = x + b * PPIX;
    #pragma unroll
    for (int ky = 0; ky < 3; ky++) {
        #pragma unroll
        for (int kx = 0; kx < 3; kx++) {
            int a = rowoff[ky] + wcs[kx];
            float mm = mb[a] * (okhf[ky] * okwf[kx]);
            mv[ky * 3 + kx] = mm;
            mxv[ky * 3 + kx] = mm * xb[a];
        }
    }
    int swl = (l & 7) << 4;
    #pragma unroll
    for (int j = 0; j < 16; j += 2) {
        float dcv[2];
        #pragma unroll
        for (int e = 0; e < 2; e++) {
            int c = og * 16 + j + e;
            float wk = w_in[64 + c], bk = b_in[64 + c];
            const float* dwr = dw_w + c * 9;
            float a0 = 0.f, a1 = 0.f;
            #pragma unroll
            for (int tp = 0; tp < 9; tp++) {
                float dv = dwr[tp];
                a0 += dv * mxv[tp];
                a1 += dv * mv[tp];
            }
            dcv[e] = wk * a0 + bk * a1;
        }
        int c = og * 16 + j;
        unsigned int pk = (unsigned int)f2bf(dcv[0]) | ((unsigned int)f2bf(dcv[1]) << 16);
        *(unsigned int*)(sPc + l * 144 + ((2 * c) ^ swl)) = pk;
    }
    __syncthreads();

    int m0 = og * 16, lr = l & 15, lg = l >> 4;
    f4_t acc[4];
    mfma64(sWc, sPc, l, m0, acc);
    float* ybase = y_out + (size_t)b * 64 * PPIX + p0;
    #pragma unroll
    for (int r = 0; r < 4; r++) {
        int o = m0 + 4 * lg + r;
        float bias = sBias[o];
        float s = 0.f, s2 = 0.f;
        #pragma unroll
        for (int nt = 0; nt < 4; nt++) {
            float yv = acc[nt][r] + bias;
            ybase[(size_t)o * PPIX + nt * 16 + lr] = yv;
            s += yv; s2 += yv * yv;
        }
        #pragma unroll
        for (int m = 1; m < 16; m <<= 1) {
            s += __shfl_xor(s, m);
            s2 += __shfl_xor(s2, m);
        }
        if (lr == 0) { sred[2 * o] = s; sred[2 * o + 1] = s2; }
    }
    __syncthreads();
    if (t < 128) partials[(size_t)blockIdx.x * 128 + t] = sred[t];
}

// ---------------- dilated dwconv: register-sliding, 16 outputs/thread in x ----
// block = (b, c, 16-row band); LDS staged band with bn+relu applied; each
// compute thread owns a 16-wide x-strip of one row; per ky one SEG-float
// segment (ds_read_b128) serves all KSZ taps x 16 outputs.
template<int KSZ, int DIL>
__global__ __launch_bounds__(256, 3) void dw_kernel(
    const float* __restrict__ in, const float* __restrict__ bnp,
    const float* __restrict__ dw_w, float* __restrict__ out)
{
    constexpr int PAD = (KSZ / 2) * DIL;      // 12 (7,4) / 4 (5,2)
    constexpr int BH = 16;
    constexpr int LR = BH + 2 * PAD;          // 40 / 24
    constexpr int SW = WDIM + 2 * PAD + 4;    // 252 / 236 (bank-spread pad, %4==0)
    constexpr int SEG = 16 + 2 * PAD;         // 40 / 24 floats per thread-row
    __shared__ float sIn[LR * SW];

    int t = threadIdx.x;
    int swz = (blockIdx.x & 7) * (NDWBLK / 8) + (blockIdx.x >> 3);
    int bc = swz / NBAND, band = swz % NBAND;
    int c = bc & 63;
    int r0 = band * BH;
    float sc = bnp[c], sh = bnp[64 + c];
    const float* plane = in + (size_t)bc * PPIX;

    // zero only the pad columns: [0,PAD) and [PAD+WDIM, SW)
    constexpr int PADC = SW - WDIM;
    for (int i = t; i < LR * PADC; i += 256) {
        int r = i / PADC, cc = i % PADC;
        int col = (cc < PAD) ? cc : (cc + WDIM);
        sIn[r * SW + col] = 0.f;
    }
    // stage rows with bn+relu; OOB rows write zeros (no separate clear pass)
    for (int i = t; i < LR * 56; i += 256) {
        int sr = i / 56, q = i % 56;
        int gr = r0 - PAD + sr;
        float4 o4 = {0.f, 0.f, 0.f, 0.f};
        if (gr >= 0 && gr < HDIM) {
            float4 v = ((const float4*)(plane + gr * WDIM))[q];
            o4.x = fmaxf(sc * v.x + sh, 0.f);
            o4.y = fmaxf(sc * v.y + sh, 0.f);
            o4.z = fmaxf(sc * v.z + sh, 0.f);
            o4.w = fmaxf(sc * v.w + sh, 0.f);
        }
        *(float4*)(sIn + sr * SW + PAD + 4 * q) = o4;
    }
    __syncthreads();

    if (t >= 224) return;   // no barriers below

    // block-uniform depthwise weights -> scalar (SGPR) loads
    const float* dwr = dw_w + c * KSZ * KSZ;
    float wk[KSZ * KSZ];
    #pragma unroll
    for (int i = 0; i < KSZ * KSZ; i++) wk[i] = dwr[i];

    int xs = t % 14, row = t / 14;     // 14 strips x 16 rows
    int x0 = xs * 16;
    float acc[16];
    #pragma unroll
    for (int j = 0; j < 16; j++) acc[j] = 0.f;
    #pragma unroll
    for (int ky = 0; ky < KSZ; ky++) {
        const float4* srow = (const float4*)(sIn + (row + ky * DIL) * SW + x0);
        float s[SEG];
        #pragma unroll
        for (int i = 0; i < SEG / 4; i++) ((float4*)s)[i] = srow[i];
        #pragma unroll
        for (int kx = 0; kx < KSZ; kx++) {
            float wv = wk[ky * KSZ + kx];
            #pragma unroll
            for (int j = 0; j < 16; j++)
                acc[j] += s[j + DIL * kx] * wv;
        }
    }
    float* orow = out + (size_t)bc * PPIX + (r0 + row) * WDIM + x0;
    #pragma unroll
    for (int i = 0; i < 4; i++) {
        float4 ov = {acc[4 * i], acc[4 * i + 1], acc[4 * i + 2], acc[4 * i + 3]};
        ((float4*)orow)[i] = ov;
    }
}

// ---------------- pointwise 64x64 MFMA matvec, IN-PLACE, + bn partials --------
__global__ __launch_bounds__(256, 4) void pw_kernel(
    const float* __restrict__ pw_w, const float* __restrict__ pw_b,
    float* __restrict__ y, float* __restrict__ partials)
{
    __shared__ __align__(16) short sW[64 * 72];
    __shared__ __align__(16) short sP[64 * 72];
    __shared__ float sred[128];
    __shared__ float sBias[64];
    char* sWc = (char*)sW; char* sPc = (char*)sP;
    int t = threadIdx.x;
    int swz = (blockIdx.x & 7) * 784 + (blockIdx.x >> 3);
    int b = swz / 784;
    int p0 = (swz % 784) * 64;
    stage_w64(pw_w, sWc, t);
    if (t < 64) sBias[t] = pw_b[t];

    float* ybase = y + (size_t)b * 64 * PPIX + p0;
    for (int i = t; i < 1024; i += 256) {
        int c = i >> 4, q = i & 15;
        float4 v = *(const float4*)(ybase + (size_t)c * PPIX + 4 * q);
        int c2 = 2 * c;
        int rb = 4 * q;
        *(unsigned short*)(sPc + (rb + 0) * 144 + (c2 ^ (((rb + 0) & 7) << 4))) = f2bf(v.x);
        *(unsigned short*)(sPc + (rb + 1) * 144 + (c2 ^ (((rb + 1) & 7) << 4))) = f2bf(v.y);
        *(unsigned short*)(sPc + (rb + 2) * 144 + (c2 ^ (((rb + 2) & 7) << 4))) = f2bf(v.z);
        *(unsigned short*)(sPc + (rb + 3) * 144 + (c2 ^ (((rb + 3) & 7) << 4))) = f2bf(v.w);
    }
    __syncthreads();   // all in-place reads complete before any write

    int l = t & 63, wv = t >> 6, m0 = wv * 16;
    int lr = l & 15, lg = l >> 4;
    f4_t acc[4];
    mfma64(sWc, sPc, l, m0, acc);
    #pragma unroll
    for (int r = 0; r < 4; r++) {
        int o = m0 + 4 * lg + r;
        float bias = sBias[o];
        float s = 0.f, s2 = 0.f;
        #pragma unroll
        for (int nt = 0; nt < 4; nt++) {
            float yv = acc[nt][r] + bias;
            ybase[(size_t)o * PPIX + nt * 16 + lr] = yv;
            s += yv; s2 += yv * yv;
        }
        #pragma unroll
        for (int m = 1; m < 16; m <<= 1) {
            s += __shfl_xor(s, m);
            s2 += __shfl_xor(s2, m);
        }
        if (lr == 0) { sred[2 * o] = s; sred[2 * o + 1] = s2; }
    }
    __syncthreads();
    if (t < 128) partials[(size_t)blockIdx.x * 128 + t] = sred[t];
}

// ---------------- bn finalize: tree-reduce partials, one block per channel ----
__global__ __launch_bounds__(256) void bnfin_kernel(
    const float* __restrict__ partials,
    const float* __restrict__ g, const float* __restrict__ be,
    float* __restrict__ bnp)
{
    int c = blockIdx.x;
    int t = threadIdx.x;
    float s = 0.f, s2 = 0.f;
    for (int blk = t; blk < NBLK; blk += 256) {
        s  += partials[(size_t)blk * 128 + 2 * c];
        s2 += partials[(size_t)blk * 128 + 2 * c + 1];
    }
    #pragma unroll
    for (int off = 32; off > 0; off >>= 1) {
        s += __shfl_down(s, off);
        s2 += __shfl_down(s2, off);
    }
    __shared__ float wsm[8];
    int lane = t & 63, wv = t >> 6;
    if (lane == 0) { wsm[wv] = s; wsm[4 + wv] = s2; }
    __syncthreads();
    if (t == 0) {
        s = wsm[0] + wsm[1] + wsm[2] + wsm[3];
        s2 = wsm[4] + wsm[5] + wsm[6] + wsm[7];
        const float inv_n = 1.f / (float)NPIX;
        float mu = s * inv_n;
        float var = s2 * inv_n - mu * mu;
        float sc = g[c] * rsqrtf(var + 1e-5f);
        bnp[c] = sc;
        bnp[64 + c] = be[c] - mu * sc;
    }
}

// ---------------- K_global: per (b,c) spatial mean of relu(bn(y2)) ------------
__global__ __launch_bounds__(256) void kglobal_kernel(
    const float* __restrict__ y2, const float* __restrict__ bnp2,
    float* __restrict__ kg)
{
    int bc = blockIdx.x;
    int c = bc & 63;
    int t = threadIdx.x;
    const float* row = y2 + (size_t)bc * PPIX;
    float sc = bnp2[c], sh = bnp2[64 + c];
    float s = 0.f;
    for (int i = t; i < PPIX; i += 256) s += fmaxf(sc * row[i] + sh, 0.f);
    #pragma unroll
    for (int off = 32; off > 0; off >>= 1) s += __shfl_down(s, off);
    __shared__ float wsum[4];
    int lane = t & 63, wv = t >> 6;
    if (lane == 0) wsum[wv] = s;
    __syncthreads();
    if (t == 0) kg[bc] = (wsum[0] + wsum[1] + wsum[2] + wsum[3]) * (1.f / (float)PPIX);
}

// ---------------- final: aggregate + MFMA V + QV + MFMA O + x_proj ------------
__global__ __launch_bounds__(256, 4) void final_kernel(
    const float* __restrict__ x, const float* __restrict__ w_in,
    const float* __restrict__ b_in,
    const float* __restrict__ y0, const float* __restrict__ y1,
    const float* __restrict__ y2,
    const float* __restrict__ bnp, const float* __restrict__ kg,
    const float* __restrict__ val_w, const float* __restrict__ val_b,
    const float* __restrict__ out_w, const float* __restrict__ out_b,
    const float* __restrict__ coeffs, float* __restrict__ out)
{
    __shared__ __align__(16) short sVW[64 * 72];
    __shared__ __align__(16) short sOW[64 * 72];
    __shared__ __align__(16) short sP[64 * 72];
    __shared__ float sxv[64], sQW[64], sQB[64], sVB[64], sOB[64], sC1[64], sC2[64];
    char* sVWc = (char*)sVW; char* sOWc = (char*)sOW; char* sPc = (char*)sP;
    int t = threadIdx.x;
    int blk = blockIdx.x;
    int b = blk / 784;
    int l = t & 63, wv = t >> 6;
    int p0 = (blk % 784) * 64;
    stage_w64(val_w, sVWc, t);
    stage_w64(out_w, sOWc, t);
    if (t < 64) {
        sQW[t] = w_in[t]; sQB[t] = b_in[t];
        sVB[t] = val_b[t]; sOB[t] = out_b[t];
        sC1[t] = coeffs[32 + t]; sC2[t] = coeffs[96 + t];
    }

    float xv = x[b * PPIX + p0 + l];
    if (wv == 0) sxv[l] = xv;
    float g0 = xv * w_in[128] + b_in[128];
    float g1 = xv * w_in[129] + b_in[129];
    float g2 = xv * w_in[130] + b_in[130];
    float g3 = xv * w_in[131] + b_in[131];
    float mx = fmaxf(fmaxf(g0, g1), fmaxf(g2, g3));
    float e0 = expf(g0 - mx), e1 = expf(g1 - mx), e2 = expf(g2 - mx), e3 = expf(g3 - mx);
    float inv = 1.f / (e0 + e1 + e2 + e3);
    float G0 = e0 * inv, G1 = e1 * inv, G2 = e2 * inv, G3 = e3 * inv;

    int swl = (l & 7) << 4;
    #pragma unroll
    for (int j = 0; j < 16; j += 2) {
        float kfv[2];
        #pragma unroll
        for (int e = 0; e < 2; e++) {
            int c = wv * 16 + j + e;
            size_t idx = (size_t)(b * 64 + c) * PPIX + p0 + l;
            float f0 = fmaxf(bnp[c] * y0[idx] + bnp[64 + c], 0.f);
            float f1 = fmaxf(bnp[128 + c] * y1[idx] + bnp[192 + c], 0.f);
            float f2 = fmaxf(bnp[256 + c] * y2[idx] + bnp[320 + c], 0.f);
            kfv[e] = G0 * f0 + G1 * f1 + G2 * f2 + G3 * kg[b * 64 + c];
        }
        int c = wv * 16 + j;
        unsigned int pk = (unsigned int)f2bf(kfv[0]) | ((unsigned int)f2bf(kfv[1]) << 16);
        *(unsigned int*)(sPc + l * 144 + ((2 * c) ^ swl)) = pk;
    }
    __syncthreads();

    int m0 = wv * 16, lr = l & 15, lg = l >> 4;
    int sw = (lr & 7) << 4;
    f4_t accV[4];
    mfma64(sVWc, sPc, l, m0, accV);
    __syncthreads();   // all P reads done before tq overwrite

    #pragma unroll
    for (int nt = 0; nt < 4; nt++) {
        float xvp = sxv[nt * 16 + lr];
        #pragma unroll
        for (int r = 0; r < 4; r++) {
            int o = m0 + 4 * lg + r;
            float V = accV[nt][r] + sVB[o];
            float q = xvp * sQW[o] + sQB[o];
            *(unsigned short*)(sPc + (nt * 16 + lr) * 144 + ((2 * o) ^ sw)) = f2bf(q * V);
        }
    }
    __syncthreads();

    f4_t accO[4];
    mfma64(sOWc, sPc, l, m0, accO);
    #pragma unroll
    for (int nt = 0; nt < 4; nt++) {
        float xvp = sxv[nt * 16 + lr];
        #pragma unroll
        for (int r = 0; r < 4; r++) {
            int o = m0 + 4 * lg + r;
            out[(size_t)(b * 64 + o) * PPIX + p0 + nt * 16 + lr] =
                accO[nt][r] + sOB[o] + xvp * sC1[o] + sC2[o];
        }
    }
}

extern "C" void kernel_launch(void* const* d_in, const int* in_sizes, int n_in,
                              void* d_out, int out_size, void* d_ws, size_t ws_size,
                              hipStream_t stream)
{
    (void)in_sizes; (void)n_in; (void)out_size; (void)ws_size;
    const float* x      = (const float*)d_in[0];
    const float* w_in   = (const float*)d_in[1];
    const float* b_in   = (const float*)d_in[2];
    const float* dw0    = (const float*)d_in[3];
    const float* pw0_w  = (const float*)d_in[4];
    const float* pw0_b  = (const float*)d_in[5];
    const float* bn0_g  = (const float*)d_in[6];
    const float* bn0_b  = (const float*)d_in[7];
    const float* dw1    = (const float*)d_in[8];
    const float* pw1_w  = (const float*)d_in[9];
    const float* pw1_b  = (const float*)d_in[10];
    const float* bn1_g  = (const float*)d_in[11];
    const float* bn1_b  = (const float*)d_in[12];
    const float* dw2    = (const float*)d_in[13];
    const float* pw2_w  = (const float*)d_in[14];
    const float* pw2_b  = (const float*)d_in[15];
    const float* bn2_g  = (const float*)d_in[16];
    const float* bn2_b  = (const float*)d_in[17];
    const float* imp_w1 = (const float*)d_in[18];
    const float* imp_b1 = (const float*)d_in[19];
    const float* imp_w2 = (const float*)d_in[20];
    const float* imp_b2 = (const float*)d_in[21];
    const float* val_w  = (const float*)d_in[22];
    const float* val_b  = (const float*)d_in[23];
    const float* out_w  = (const float*)d_in[24];
    const float* out_b  = (const float*)d_in[25];
    const float* fin_w  = (const float*)d_in[26];
    const float* fin_b  = (const float*)d_in[27];

    float* ws   = (float*)d_ws;
    float* y0   = ws;
    float* y1   = ws + (size_t)NELEM;
    float* imp  = ws + (size_t)2 * NELEM;
    float* mask = imp + NPIX;
    float* partials = mask + NPIX;                // 6272*128
    float* bnp   = partials + (size_t)NBLK * 128; // 3*128
    float* kg    = bnp + 384;                     // 512
    float* coeffs = kg + 512;                     // 160
    unsigned int* ghist = (unsigned int*)(coeffs + 160);   // 8*256
    unsigned int* pfx   = ghist + 2048;                    // 8
    int* rem            = (int*)(pfx + 8);                 // 8
    int* blocktie       = rem + 8;                         // 8*49
    float* y2 = (float*)d_out;

    prep_kernel<<<1, 256, 0, stream>>>(w_in, b_in, imp_w1, imp_b1, fin_w, fin_b,
                                       coeffs, ghist, pfx, rem);
    imp_kernel<<<NPIX / 256, 256, 0, stream>>>(x, coeffs, imp_w2, imp_b2, imp);

    for (int shift = 24; shift >= 0; shift -= 8) {
        topk_hist<<<BATCH * NCHUNK, 256, 0, stream>>>(imp, pfx, ghist, shift);
        topk_select<<<BATCH, 256, 0, stream>>>(ghist, pfx, rem, shift);
    }
    topk_mask1<<<BATCH * NCHUNK, 256, 0, stream>>>(imp, pfx, mask, blocktie);
    topk_mask2<<<BATCH, 256, 0, stream>>>(imp, pfx, rem, blocktie, mask);

    level0_kernel<<<NBLK, 256, 0, stream>>>(x, mask, w_in, b_in, dw0, pw0_w, pw0_b,
                                            y0, partials);
    bnfin_kernel<<<64, 256, 0, stream>>>(partials, bn0_g, bn0_b, bnp);

    dw_kernel<5, 2><<<NDWBLK, 256, 0, stream>>>(y0, bnp, dw1, y1);
    pw_kernel<<<NBLK, 256, 0, stream>>>(pw1_w, pw1_b, y1, partials);
    bnfin_kernel<<<64, 256, 0, stream>>>(partials, bn1_g, bn1_b, bnp + 128);

    dw_kernel<7, 4><<<NDWBLK, 256, 0, stream>>>(y1, bnp + 128, dw2, y2);
    pw_kernel<<<NBLK, 256, 0, stream>>>(pw2_w, pw2_b, y2, partials);
    bnfin_kernel<<<64, 256, 0, stream>>>(partials, bn2_g, bn2_b, bnp + 256);

    kglobal_kernel<<<512, 256, 0, stream>>>(y2, bnp + 256, kg);
    final_kernel<<<NBLK, 256, 0, stream>>>(x, w_in, b_in, y0, y1, y2, bnp, kg,
                                           val_w, val_b, out_w, out_b, coeffs, y2);
}

// Round 9
// 391.591 us; speedup vs baseline: 22.0668x; 1.4518x over previous
//
#include <hip/hip_runtime.h>

#define HDIM 224
#define WDIM 224
#define PPIX 50176      // 224*224
#define BATCH 8
#define NPIX 401408     // 8*50176
#define KTOP 15052      // max(int(0.3*224*224), 64)
#define NELEM 25690112  // 8*64*50176
#define NBLK 6272       // 8*784 strip grid
#define NBAND 14        // 224/16
#define NDWBLK 7168     // 8*64*14
#define NCHUNK 49       // PPIX / 1024

typedef __attribute__((ext_vector_type(8))) short bf8_t;
typedef __attribute__((ext_vector_type(4))) float f4_t;
typedef __attribute__((ext_vector_type(8))) unsigned short us8_t;
typedef __attribute__((ext_vector_type(4))) unsigned short us4_t;
#define MFMA_BF16 __builtin_amdgcn_mfma_f32_16x16x32_bf16

// round-to-nearest-even f32 -> bf16
__device__ inline unsigned short f2bf(float f) {
    unsigned int u = __float_as_uint(f);
    return (unsigned short)((u + 0x7FFFu + ((u >> 16) & 1u)) >> 16);
}
__device__ inline float bf2f(unsigned short u) {
    return __uint_as_float(((unsigned int)u) << 16);
}

// LDS 64x64 bf16 matrix: 128B rows = 8 chunks(16B); physical chunk = k ^ g(r),
// g(r) = (r ^ (r>>3)) & 7. All fragment reads / staged writes are bank-uniform.
__device__ inline int ldsg(int r) { return ((r >> 3) ^ r) & 7; }

// stage a 64x64 fp32 matrix into swizzled bf16 LDS. 256 threads.
__device__ inline void stage_w64(const float* __restrict__ W, char* sWc, int t) {
    int o = t >> 2, cq = t & 3, c0 = cq * 16;
    const float4* src = (const float4*)(W + o * 64 + c0);
    float4 v0 = src[0], v1 = src[1], v2 = src[2], v3 = src[3];
    bf8_t p0, p1;
    p0[0] = (short)f2bf(v0.x); p0[1] = (short)f2bf(v0.y);
    p0[2] = (short)f2bf(v0.z); p0[3] = (short)f2bf(v0.w);
    p0[4] = (short)f2bf(v1.x); p0[5] = (short)f2bf(v1.y);
    p0[6] = (short)f2bf(v1.z); p0[7] = (short)f2bf(v1.w);
    p1[0] = (short)f2bf(v2.x); p1[1] = (short)f2bf(v2.y);
    p1[2] = (short)f2bf(v2.z); p1[3] = (short)f2bf(v2.w);
    p1[4] = (short)f2bf(v3.x); p1[5] = (short)f2bf(v3.y);
    p1[6] = (short)f2bf(v3.z); p1[7] = (short)f2bf(v3.w);
    int g = ldsg(o);
    *(bf8_t*)(sWc + o * 128 + (((2 * cq) ^ g) << 4)) = p0;
    *(bf8_t*)(sWc + o * 128 + (((2 * cq + 1) ^ g) << 4)) = p1;
}

// C[64o x 64p] = W(64x64, sWc) @ P([p][c], sPc); wave owns rows m0..m0+15.
__device__ inline void mfma64(const char* sWc, const char* sPc, int l, int m0, f4_t acc[4]) {
    int lr = l & 15, lg = l >> 4;
    int ra = m0 + lr, ga = ldsg(ra);
    const char* abase = sWc + ra * 128;
    bf8_t a0 = *(const bf8_t*)(abase + ((lg ^ ga) << 4));
    bf8_t a1 = *(const bf8_t*)(abase + (((lg + 4) ^ ga) << 4));
    #pragma unroll
    for (int nt = 0; nt < 4; nt++) {
        int rb = nt * 16 + lr, gb = ldsg(rb);
        const char* bbase = sPc + rb * 128;
        bf8_t b0 = *(const bf8_t*)(bbase + ((lg ^ gb) << 4));
        bf8_t b1 = *(const bf8_t*)(bbase + (((lg + 4) ^ gb) << 4));
        f4_t c = {0.f, 0.f, 0.f, 0.f};
        c = MFMA_BF16(a0, b0, c, 0, 0, 0);
        c = MFMA_BF16(a1, b1, c, 0, 0, 0);
        acc[nt] = c;
    }
}

// ---------------- prep: tiny derived coefficients + topk state init ----------
__global__ __launch_bounds__(256) void prep_kernel(
    const float* __restrict__ w_in, const float* __restrict__ b_in,
    const float* __restrict__ imp_w1, const float* __restrict__ imp_b1,
    const float* __restrict__ fin_w, const float* __restrict__ fin_b,
    float* __restrict__ coeffs, unsigned int* __restrict__ ghist,
    unsigned int* __restrict__ pfx, int* __restrict__ rem)
{
    int t = threadIdx.x;
    if (t < 16) {
        float a = 0.f, d = 0.f;
        for (int c = 0; c < 64; c++) {
            a += imp_w1[t * 64 + c] * w_in[64 + c];
            d += imp_w1[t * 64 + c] * b_in[64 + c];
        }
        coeffs[t] = a;
        coeffs[16 + t] = d + imp_b1[t];
    }
    if (t < 64) {
        float a = 0.f, d = 0.f;
        for (int c = 0; c < 64; c++) {
            a += fin_w[t * 64 + c] * w_in[c];
            d += fin_w[t * 64 + c] * b_in[c];
        }
        coeffs[32 + t] = a;
        coeffs[96 + t] = d + fin_b[t];
    }
    for (int i = t; i < 2048; i += 256) ghist[i] = 0u;
    if (t < BATCH) { pfx[t] = 0u; rem[t] = KTOP; }
}

// ---------------- importance map: sigmoid(conv3x3(relu(x*a+d), w2)+b2) --------
__global__ __launch_bounds__(256) void imp_kernel(
    const float* __restrict__ x, const float* __restrict__ coeffs,
    const float* __restrict__ imp_w2, const float* __restrict__ imp_b2,
    float* __restrict__ imp)
{
    int idx = blockIdx.x * 256 + threadIdx.x;
    int b = idx / PPIX, p = idx % PPIX;
    int h = p / WDIM, w = p % WDIM;
    float acc = imp_b2[0];
    #pragma unroll
    for (int ky = 0; ky < 3; ky++) {
        int hh = h + ky - 1;
        float okh = (hh >= 0 && hh < HDIM) ? 1.f : 0.f;
        int hc = min(max(hh, 0), HDIM - 1);
        #pragma unroll
        for (int kx = 0; kx < 3; kx++) {
            int ww = w + kx - 1;
            float ok = okh * ((ww >= 0 && ww < WDIM) ? 1.f : 0.f);
            int wc = min(max(ww, 0), WDIM - 1);
            float xv = x[b * PPIX + hc * WDIM + wc] * ok;
            #pragma unroll
            for (int c = 0; c < 16; c++) {
                float r = fmaxf(xv * coeffs[c] + coeffs[16 + c] * ok, 0.f);
                acc += r * imp_w2[c * 9 + ky * 3 + kx];
            }
        }
    }
    imp[idx] = 1.f / (1.f + expf(-acc));
}

// ---------------- parallel exact top-k: radix histogram pass ------------------
__global__ __launch_bounds__(256) void topk_hist(
    const float* __restrict__ imp, const unsigned int* __restrict__ pfx,
    unsigned int* __restrict__ ghist, int shift)
{
    int b = blockIdx.x / NCHUNK, ch = blockIdx.x % NCHUNK;
    int t = threadIdx.x;
    __shared__ unsigned int hist[256];
    hist[t] = 0u;
    __syncthreads();
    unsigned int prefix = pfx[b];
    unsigned int himask = (shift == 24) ? 0u : (0xFFFFFFFFu << (shift + 8));
    float4 v = ((const float4*)(imp + b * PPIX + ch * 1024))[t];
    unsigned int bb[4] = {__float_as_uint(v.x), __float_as_uint(v.y),
                          __float_as_uint(v.z), __float_as_uint(v.w)};
    #pragma unroll
    for (int k = 0; k < 4; k++)
        if ((bb[k] & himask) == prefix)
            atomicAdd(&hist[(bb[k] >> shift) & 255u], 1u);
    __syncthreads();
    unsigned int c = hist[t];
    if (c) atomicAdd(&ghist[b * 256 + t], c);
}

// ---------------- top-k: select bin, update prefix/remaining, zero hist -------
__global__ __launch_bounds__(256) void topk_select(
    unsigned int* __restrict__ ghist, unsigned int* __restrict__ pfx,
    int* __restrict__ rem, int shift)
{
    int b = blockIdx.x;
    int t = threadIdx.x;
    __shared__ unsigned int h[256];
    h[t] = ghist[b * 256 + t];
    ghist[b * 256 + t] = 0u;
    __syncthreads();
    if (t == 0) {
        int r = rem[b];
        unsigned int bsel = 0u;
        for (int bin = 255; bin >= 0; bin--) {
            int c = (int)h[bin];
            if (c >= r) { bsel = (unsigned int)bin; break; }
            r -= c;
        }
        rem[b] = r;
        pfx[b] |= bsel << shift;
    }
}

// ---------------- top-k: write mask for >T, count ties per chunk --------------
__global__ __launch_bounds__(256) void topk_mask1(
    const float* __restrict__ imp, const unsigned int* __restrict__ pfx,
    float* __restrict__ mask, int* __restrict__ blocktie)
{
    int b = blockIdx.x / NCHUNK, ch = blockIdx.x % NCHUNK;
    int t = threadIdx.x;
    unsigned int T = pfx[b];
    float4 v = ((const float4*)(imp + b * PPIX + ch * 1024))[t];
    unsigned int bb[4] = {__float_as_uint(v.x), __float_as_uint(v.y),
                          __float_as_uint(v.z), __float_as_uint(v.w)};
    float4 mo;
    float* mp = &mo.x;
    int cnt = 0;
    #pragma unroll
    for (int k = 0; k < 4; k++) {
        mp[k] = (bb[k] > T) ? 1.f : 0.f;
        cnt += (bb[k] == T) ? 1 : 0;
    }
    ((float4*)(mask + b * PPIX + ch * 1024))[t] = mo;
    #pragma unroll
    for (int off = 32; off > 0; off >>= 1) cnt += __shfl_down(cnt, off);
    __shared__ int ws4[4];
    int lane = t & 63, wv = t >> 6;
    if (lane == 0) ws4[wv] = cnt;
    __syncthreads();
    if (t == 0) blocktie[b * NCHUNK + ch] = ws4[0] + ws4[1] + ws4[2] + ws4[3];
}

// ---------------- top-k: set first `rem` ties in index order ------------------
__global__ __launch_bounds__(256) void topk_mask2(
    const float* __restrict__ imp, const unsigned int* __restrict__ pfx,
    const int* __restrict__ rem_, const int* __restrict__ blocktie,
    float* __restrict__ mask)
{
    int b = blockIdx.x;
    int t = threadIdx.x, lane = t & 63, wv = t >> 6;
    unsigned int T = pfx[b];
    int rem = rem_[b];
    __shared__ int sbase[NCHUNK], scnt[NCHUNK];
    if (t == 0) {
        int s = 0;
        for (int i = 0; i < NCHUNK; i++) {
            sbase[i] = s;
            int c = blocktie[b * NCHUNK + i];
            scnt[i] = c;
            s += c;
        }
    }
    __syncthreads();
    __shared__ int wtot[4];
    for (int ch = 0; ch < NCHUNK; ch++) {
        if (scnt[ch] == 0) continue;
        int base = sbase[ch];
        if (base >= rem) break;
        for (int g = 0; g < 4; g++) {
            int i = b * PPIX + ch * 1024 + g * 256 + t;
            int flag = (__float_as_uint(imp[i]) == T) ? 1 : 0;
            unsigned long long bal = __ballot(flag);
            if (lane == 0) wtot[wv] = __popcll(bal);
            __syncthreads();
            int wbase = 0, tot = 0;
            for (int q = 0; q < 4; q++) { int c = wtot[q]; if (q < wv) wbase += c; tot += c; }
            if (flag && base + wbase + __popcll(bal & ((1ull << lane) - 1ull)) < rem)
                mask[i] = 1.f;
            base += tot;
            __syncthreads();
        }
    }
}

// ---------------- level 0: masked dwconv3x3 -> MFMA 1x1, y0(bf16) + partials --
__global__ __launch_bounds__(256, 4) void level0_kernel(
    const float* __restrict__ x, const float* __restrict__ mask,
    const float* __restrict__ w_in, const float* __restrict__ b_in,
    const float* __restrict__ dw_w, const float* __restrict__ pw_w,
    const float* __restrict__ pw_b,
    unsigned short* __restrict__ y_out, float* __restrict__ partials)
{
    __shared__ __align__(16) short sW[4096];
    __shared__ __align__(16) short sP[4096];
    __shared__ float sred[128];
    __shared__ float sBias[64];
    char* sWc = (char*)sW; char* sPc = (char*)sP;
    int t = threadIdx.x;
    int swz = (blockIdx.x & 7) * 784 + (blockIdx.x >> 3);
    int b = swz / 784;
    int l = t & 63, og = t >> 6;
    int p0 = (swz % 784) * 64;
    int p = p0 + l;
    int h = p / WDIM, w = p % WDIM;
    stage_w64(pw_w, sWc, t);
    if (t < 64) sBias[t] = pw_b[t];

    int rowoff[3]; float okhf[3];
    int wcs[3]; float okwf[3];
    #pragma unroll
    for (int k = 0; k < 3; k++) {
        int hh = h + k - 1;
        okhf[k] = (hh >= 0 && hh < HDIM) ? 1.f : 0.f;
        rowoff[k] = min(max(hh, 0), HDIM - 1) * WDIM;
        int ww = w + k - 1;
        okwf[k] = (ww >= 0 && ww < WDIM) ? 1.f : 0.f;
        wcs[k] = min(max(ww, 0), WDIM - 1);
    }
    float mv[9], mxv[9];
    const float* mb = mask + b * PPIX;
    const float* xb = x + b * PPIX;
    #pragma unroll
    for (int ky = 0; ky < 3; ky++) {
        #pragma unroll
        for (int kx = 0; kx < 3; kx++) {
            int a = rowoff[ky] + wcs[kx];
            float mm = mb[a] * (okhf[ky] * okwf[kx]);
            mv[ky * 3 + kx] = mm;
            mxv[ky * 3 + kx] = mm * xb[a];
        }
    }
    bf8_t pk0, pk1;
    #pragma unroll
    for (int j = 0; j < 16; j++) {
        int c = og * 16 + j;
        float wk = w_in[64 + c], bk = b_in[64 + c];
        const float* dwr = dw_w + c * 9;
        float a0 = 0.f, a1 = 0.f;
        #pragma unroll
        for (int tp = 0; tp < 9; tp++) {
            float dv = dwr[tp];
            a0 += dv * mxv[tp];
            a1 += dv * mv[tp];
        }
        unsigned short bv = f2bf(wk * a0 + bk * a1);
        if (j < 8) pk0[j] = (short)bv; else pk1[j - 8] = (short)bv;
    }
    int gl = ldsg(l);
    *(bf8_t*)(sPc + l * 128 + (((2 * og) ^ gl) << 4)) = pk0;
    *(bf8_t*)(sPc + l * 128 + (((2 * og + 1) ^ gl) << 4)) = pk1;
    __syncthreads();

    int m0 = og * 16, lr = l & 15, lg = l >> 4;
    f4_t acc[4];
    mfma64(sWc, sPc, l, m0, acc);
    unsigned short* ybase = y_out + (size_t)b * 64 * PPIX + p0;
    #pragma unroll
    for (int r = 0; r < 4; r++) {
        int o = m0 + 4 * lg + r;
        float bias = sBias[o];
        float s = 0.f, s2 = 0.f;
        #pragma unroll
        for (int nt = 0; nt < 4; nt++) {
            float yv = acc[nt][r] + bias;
            ybase[(size_t)o * PPIX + nt * 16 + lr] = f2bf(yv);
            s += yv; s2 += yv * yv;
        }
        #pragma unroll
        for (int m = 1; m < 16; m <<= 1) {
            s += __shfl_xor(s, m);
            s2 += __shfl_xor(s2, m);
        }
        if (lr == 0) { sred[2 * o] = s; sred[2 * o + 1] = s2; }
    }
    __syncthreads();
    if (t < 128) partials[(size_t)blockIdx.x * 128 + t] = sred[t];
}

// ---------------- dilated dwconv: bf16 in/out, register-sliding ---------------
template<int KSZ, int DIL>
__global__ __launch_bounds__(256, 3) void dw_kernel(
    const unsigned short* __restrict__ in, const float* __restrict__ bnp,
    const float* __restrict__ dw_w, unsigned short* __restrict__ out)
{
    constexpr int PAD = (KSZ / 2) * DIL;
    constexpr int BH = 16;
    constexpr int LR = BH + 2 * PAD;
    constexpr int SW = WDIM + 2 * PAD + 4;    // bank-spread pad, %4==0
    constexpr int SEG = 16 + 2 * PAD;
    __shared__ float sIn[LR * SW];

    int t = threadIdx.x;
    int swz = (blockIdx.x & 7) * (NDWBLK / 8) + (blockIdx.x >> 3);
    int bc = swz / NBAND, band = swz % NBAND;
    int c = bc & 63;
    int r0 = band * BH;
    float sc = bnp[c], sh = bnp[64 + c];
    const unsigned short* plane = in + (size_t)bc * PPIX;

    constexpr int PADC = SW - WDIM;
    for (int i = t; i < LR * PADC; i += 256) {
        int r = i / PADC, cc = i % PADC;
        int col = (cc < PAD) ? cc : (cc + WDIM);
        sIn[r * SW + col] = 0.f;
    }
    for (int i = t; i < LR * 28; i += 256) {
        int sr = i / 28, q = i % 28;
        int gr = r0 - PAD + sr;
        float4 a = {0.f, 0.f, 0.f, 0.f}, bq = {0.f, 0.f, 0.f, 0.f};
        if (gr >= 0 && gr < HDIM) {
            us8_t v = *(const us8_t*)(plane + gr * WDIM + 8 * q);
            a.x = fmaxf(sc * bf2f(v[0]) + sh, 0.f);
            a.y = fmaxf(sc * bf2f(v[1]) + sh, 0.f);
            a.z = fmaxf(sc * bf2f(v[2]) + sh, 0.f);
            a.w = fmaxf(sc * bf2f(v[3]) + sh, 0.f);
            bq.x = fmaxf(sc * bf2f(v[4]) + sh, 0.f);
            bq.y = fmaxf(sc * bf2f(v[5]) + sh, 0.f);
            bq.z = fmaxf(sc * bf2f(v[6]) + sh, 0.f);
            bq.w = fmaxf(sc * bf2f(v[7]) + sh, 0.f);
        }
        *(float4*)(sIn + sr * SW + PAD + 8 * q) = a;
        *(float4*)(sIn + sr * SW + PAD + 8 * q + 4) = bq;
    }
    __syncthreads();

    if (t < 224) {   // no barriers below; idle tail predicated, not returned
        const float* dwr = dw_w + c * KSZ * KSZ;
        float wk[KSZ * KSZ];
        #pragma unroll
        for (int i = 0; i < KSZ * KSZ; i++) wk[i] = dwr[i];

        int xs = t % 14, row = t / 14;
        int x0 = xs * 16;
        float acc[16];
        #pragma unroll
        for (int j = 0; j < 16; j++) acc[j] = 0.f;
        #pragma unroll
        for (int ky = 0; ky < KSZ; ky++) {
            const float4* srow = (const float4*)(sIn + (row + ky * DIL) * SW + x0);
            float s[SEG];
            #pragma unroll
            for (int i = 0; i < SEG / 4; i++) ((float4*)s)[i] = srow[i];
            #pragma unroll
            for (int kx = 0; kx < KSZ; kx++) {
                float wv = wk[ky * KSZ + kx];
                #pragma unroll
                for (int j = 0; j < 16; j++)
                    acc[j] += s[j + DIL * kx] * wv;
            }
        }
        us8_t o0, o1;
        #pragma unroll
        for (int j = 0; j < 8; j++) { o0[j] = f2bf(acc[j]); o1[j] = f2bf(acc[8 + j]); }
        unsigned short* orow = out + (size_t)bc * PPIX + (r0 + row) * WDIM + x0;
        *(us8_t*)orow = o0;
        *(us8_t*)(orow + 8) = o1;
    }
}

// ---------------- pointwise 64x64 MFMA matvec, OUT-OF-PLACE, + bn partials ----
__global__ __launch_bounds__(256, 4) void pw_kernel(
    const float* __restrict__ pw_w, const float* __restrict__ pw_b,
    const unsigned short* __restrict__ src_y, unsigned short* __restrict__ dst_y,
    float* __restrict__ partials)
{
    __shared__ __align__(16) short sW[4096];
    __shared__ __align__(16) short sP[4096];
    __shared__ float sred[128];
    __shared__ float sBias[64];
    char* sWc = (char*)sW; char* sPc = (char*)sP;
    int t = threadIdx.x;
    int swz = (blockIdx.x & 7) * 784 + (blockIdx.x >> 3);
    int b = swz / 784;
    int p0 = (swz % 784) * 64;
    stage_w64(pw_w, sWc, t);
    if (t < 64) sBias[t] = pw_b[t];

    const unsigned short* sbase_g = src_y + (size_t)b * 64 * PPIX + p0;
    unsigned short* dbase_g = dst_y + (size_t)b * 64 * PPIX + p0;
    {
        int c = t >> 2, pg = t & 3;
        const unsigned short* src = sbase_g + (size_t)c * PPIX + 16 * pg;
        us8_t v0 = *(const us8_t*)src;
        us8_t v1 = *(const us8_t*)(src + 8);
        int kc = c >> 3, cb = 2 * (c & 7);
        #pragma unroll
        for (int e = 0; e < 16; e++) {
            int r = 16 * pg + e;
            int gr = ldsg(r);
            unsigned short val = (e < 8) ? (unsigned short)v0[e] : (unsigned short)v1[e - 8];
            *(unsigned short*)(sPc + r * 128 + ((kc ^ gr) << 4) + cb) = val;
        }
    }
    __syncthreads();

    int l = t & 63, wv = t >> 6, m0 = wv * 16;
    int lr = l & 15, lg = l >> 4;
    f4_t acc[4];
    mfma64(sWc, sPc, l, m0, acc);
    #pragma unroll
    for (int r = 0; r < 4; r++) {
        int o = m0 + 4 * lg + r;
        float bias = sBias[o];
        float s = 0.f, s2 = 0.f;
        #pragma unroll
        for (int nt = 0; nt < 4; nt++) {
            float yv = acc[nt][r] + bias;
            dbase_g[(size_t)o * PPIX + nt * 16 + lr] = f2bf(yv);
            s += yv; s2 += yv * yv;
        }
        #pragma unroll
        for (int m = 1; m < 16; m <<= 1) {
            s += __shfl_xor(s, m);
            s2 += __shfl_xor(s2, m);
        }
        if (lr == 0) { sred[2 * o] = s; sred[2 * o + 1] = s2; }
    }
    __syncthreads();
    if (t < 128) partials[(size_t)blockIdx.x * 128 + t] = sred[t];
}

// ---------------- bn finalize: tree-reduce partials, one block per channel ----
__global__ __launch_bounds__(256) void bnfin_kernel(
    const float* __restrict__ partials,
    const float* __restrict__ g, const float* __restrict__ be,
    float* __restrict__ bnp)
{
    int c = blockIdx.x;
    int t = threadIdx.x;
    float s = 0.f, s2 = 0.f;
    for (int blk = t; blk < NBLK; blk += 256) {
        s  += partials[(size_t)blk * 128 + 2 * c];
        s2 += partials[(size_t)blk * 128 + 2 * c + 1];
    }
    #pragma unroll
    for (int off = 32; off > 0; off >>= 1) {
        s += __shfl_down(s, off);
        s2 += __shfl_down(s2, off);
    }
    __shared__ float wsm[8];
    int lane = t & 63, wv = t >> 6;
    if (lane == 0) { wsm[wv] = s; wsm[4 + wv] = s2; }
    __syncthreads();
    if (t == 0) {
        s = wsm[0] + wsm[1] + wsm[2] + wsm[3];
        s2 = wsm[4] + wsm[5] + wsm[6] + wsm[7];
        const float inv_n = 1.f / (float)NPIX;
        float mu = s * inv_n;
        float var = s2 * inv_n - mu * mu;
        float sc = g[c] * rsqrtf(var + 1e-5f);
        bnp[c] = sc;
        bnp[64 + c] = be[c] - mu * sc;
    }
}

// ---------------- K_global: per (b,c) spatial mean of relu(bn(y2)) ------------
__global__ __launch_bounds__(256) void kglobal_kernel(
    const unsigned short* __restrict__ y2, const float* __restrict__ bnp2,
    float* __restrict__ kg)
{
    int bc = blockIdx.x;
    int c = bc & 63;
    int t = threadIdx.x;
    const unsigned short* row = y2 + (size_t)bc * PPIX;
    float sc = bnp2[c], sh = bnp2[64 + c];
    float s = 0.f;
    for (int ii = t; ii < PPIX / 8; ii += 256) {
        us8_t v = *(const us8_t*)(row + 8 * ii);
        #pragma unroll
        for (int k = 0; k < 8; k++) s += fmaxf(sc * bf2f(v[k]) + sh, 0.f);
    }
    #pragma unroll
    for (int off = 32; off > 0; off >>= 1) s += __shfl_down(s, off);
    __shared__ float wsum[4];
    int lane = t & 63, wv = t >> 6;
    if (lane == 0) wsum[wv] = s;
    __syncthreads();
    if (t == 0) kg[bc] = (wsum[0] + wsum[1] + wsum[2] + wsum[3]) * (1.f / (float)PPIX);
}

// ---------------- final: aggregate + MFMA V + QV + MFMA O + x_proj ------------
__global__ __launch_bounds__(256, 4) void final_kernel(
    const float* __restrict__ x, const float* __restrict__ w_in,
    const float* __restrict__ b_in,
    const unsigned short* __restrict__ y0, const unsigned short* __restrict__ y1,
    const unsigned short* __restrict__ y2,
    const float* __restrict__ bnp, const float* __restrict__ kg,
    const float* __restrict__ val_w, const float* __restrict__ val_b,
    const float* __restrict__ out_w, const float* __restrict__ out_b,
    const float* __restrict__ coeffs, float* __restrict__ out)
{
    __shared__ __align__(16) short sVW[4096];
    __shared__ __align__(16) short sOW[4096];
    __shared__ __align__(16) short sP[4096];
    __shared__ float sxv[64], sQW[64], sQB[64], sVB[64], sOB[64], sC1[64], sC2[64];
    char* sVWc = (char*)sVW; char* sOWc = (char*)sOW; char* sPc = (char*)sP;
    int t = threadIdx.x;
    int blk = blockIdx.x;
    int b = blk / 784;
    int l = t & 63, wv = t >> 6;
    int p0 = (blk % 784) * 64;
    stage_w64(val_w, sVWc, t);
    stage_w64(out_w, sOWc, t);
    if (t < 64) {
        sQW[t] = w_in[t]; sQB[t] = b_in[t];
        sVB[t] = val_b[t]; sOB[t] = out_b[t];
        sC1[t] = coeffs[32 + t]; sC2[t] = coeffs[96 + t];
    }

    float xv = x[b * PPIX + p0 + l];
    if (wv == 0) sxv[l] = xv;
    float g0 = xv * w_in[128] + b_in[128];
    float g1 = xv * w_in[129] + b_in[129];
    float g2 = xv * w_in[130] + b_in[130];
    float g3 = xv * w_in[131] + b_in[131];
    float mx = fmaxf(fmaxf(g0, g1), fmaxf(g2, g3));
    float e0 = expf(g0 - mx), e1 = expf(g1 - mx), e2 = expf(g2 - mx), e3 = expf(g3 - mx);
    float inv = 1.f / (e0 + e1 + e2 + e3);
    float G0 = e0 * inv, G1 = e1 * inv, G2 = e2 * inv, G3 = e3 * inv;

    bf8_t pk0, pk1;
    #pragma unroll
    for (int j = 0; j < 16; j++) {
        int c = wv * 16 + j;
        size_t idx = (size_t)(b * 64 + c) * PPIX + p0 + l;
        float f0 = fmaxf(bnp[c] * bf2f(y0[idx]) + bnp[64 + c], 0.f);
        float f1 = fmaxf(bnp[128 + c] * bf2f(y1[idx]) + bnp[192 + c], 0.f);
        float f2 = fmaxf(bnp[256 + c] * bf2f(y2[idx]) + bnp[320 + c], 0.f);
        float kf = G0 * f0 + G1 * f1 + G2 * f2 + G3 * kg[b * 64 + c];
        unsigned short bv = f2bf(kf);
        if (j < 8) pk0[j] = (short)bv; else pk1[j - 8] = (short)bv;
    }
    int gl = ldsg(l);
    *(bf8_t*)(sPc + l * 128 + (((2 * wv) ^ gl) << 4)) = pk0;
    *(bf8_t*)(sPc + l * 128 + (((2 * wv + 1) ^ gl) << 4)) = pk1;
    __syncthreads();

    int m0 = wv * 16, lr = l & 15, lg = l >> 4;
    f4_t accV[4];
    mfma64(sVWc, sPc, l, m0, accV);
    __syncthreads();   // all P reads done before QV overwrite

    #pragma unroll
    for (int nt = 0; nt < 4; nt++) {
        float xvp = sxv[nt * 16 + lr];
        us4_t q4;
        #pragma unroll
        for (int r = 0; r < 4; r++) {
            int o = m0 + 4 * lg + r;
            float V = accV[nt][r] + sVB[o];
            float q = xvp * sQW[o] + sQB[o];
            q4[r] = f2bf(q * V);
        }
        int rb = nt * 16 + lr, gb = ldsg(rb);
        int kc = 2 * wv + (lg >> 1);
        *(us4_t*)(sPc + rb * 128 + ((kc ^ gb) << 4) + 8 * (lg & 1)) = q4;
    }
    __syncthreads();

    f4_t accO[4];
    mfma64(sOWc, sPc, l, m0, accO);
    #pragma unroll
    for (int nt = 0; nt < 4; nt++) {
        float xvp = sxv[nt * 16 + lr];
        #pragma unroll
        for (int r = 0; r < 4; r++) {
            int o = m0 + 4 * lg + r;
            out[(size_t)(b * 64 + o) * PPIX + p0 + nt * 16 + lr] =
                accO[nt][r] + sOB[o] + xvp * sC1[o] + sC2[o];
        }
    }
}

extern "C" void kernel_launch(void* const* d_in, const int* in_sizes, int n_in,
                              void* d_out, int out_size, void* d_ws, size_t ws_size,
                              hipStream_t stream)
{
    (void)in_sizes; (void)n_in; (void)out_size; (void)ws_size;
    const float* x      = (const float*)d_in[0];
    const float* w_in   = (const float*)d_in[1];
    const float* b_in   = (const float*)d_in[2];
    const float* dw0    = (const float*)d_in[3];
    const float* pw0_w  = (const float*)d_in[4];
    const float* pw0_b  = (const float*)d_in[5];
    const float* bn0_g  = (const float*)d_in[6];
    const float* bn0_b  = (const float*)d_in[7];
    const float* dw1    = (const float*)d_in[8];
    const float* pw1_w  = (const float*)d_in[9];
    const float* pw1_b  = (const float*)d_in[10];
    const float* bn1_g  = (const float*)d_in[11];
    const float* bn1_b  = (const float*)d_in[12];
    const float* dw2    = (const float*)d_in[13];
    const float* pw2_w  = (const float*)d_in[14];
    const float* pw2_b  = (const float*)d_in[15];
    const float* bn2_g  = (const float*)d_in[16];
    const float* bn2_b  = (const float*)d_in[17];
    const float* imp_w1 = (const float*)d_in[18];
    const float* imp_b1 = (const float*)d_in[19];
    const float* imp_w2 = (const float*)d_in[20];
    const float* imp_b2 = (const float*)d_in[21];
    const float* val_w  = (const float*)d_in[22];
    const float* val_b  = (const float*)d_in[23];
    const float* out_w  = (const float*)d_in[24];
    const float* out_b  = (const float*)d_in[25];
    const float* fin_w  = (const float*)d_in[26];
    const float* fin_b  = (const float*)d_in[27];

    unsigned short* y0 = (unsigned short*)d_ws;
    unsigned short* y1 = y0 + (size_t)NELEM;
    unsigned short* y2 = y1 + (size_t)NELEM;
    unsigned short* yt = y2 + (size_t)NELEM;           // dwconv temp
    float* imp  = (float*)(yt + (size_t)NELEM);
    float* mask = imp + NPIX;
    float* partials = mask + NPIX;                // 6272*128
    float* bnp   = partials + (size_t)NBLK * 128; // 3*128
    float* kg    = bnp + 384;                     // 512
    float* coeffs = kg + 512;                     // 160
    unsigned int* ghist = (unsigned int*)(coeffs + 160);   // 8*256
    unsigned int* pfx   = ghist + 2048;                    // 8
    int* rem            = (int*)(pfx + 8);                 // 8
    int* blocktie       = rem + 8;                         // 8*49
    float* outp = (float*)d_out;

    prep_kernel<<<1, 256, 0, stream>>>(w_in, b_in, imp_w1, imp_b1, fin_w, fin_b,
                                       coeffs, ghist, pfx, rem);
    imp_kernel<<<NPIX / 256, 256, 0, stream>>>(x, coeffs, imp_w2, imp_b2, imp);

    for (int shift = 24; shift >= 0; shift -= 8) {
        topk_hist<<<BATCH * NCHUNK, 256, 0, stream>>>(imp, pfx, ghist, shift);
        topk_select<<<BATCH, 256, 0, stream>>>(ghist, pfx, rem, shift);
    }
    topk_mask1<<<BATCH * NCHUNK, 256, 0, stream>>>(imp, pfx, mask, blocktie);
    topk_mask2<<<BATCH, 256, 0, stream>>>(imp, pfx, rem, blocktie, mask);

    level0_kernel<<<NBLK, 256, 0, stream>>>(x, mask, w_in, b_in, dw0, pw0_w, pw0_b,
                                            y0, partials);
    bnfin_kernel<<<64, 256, 0, stream>>>(partials, bn0_g, bn0_b, bnp);

    dw_kernel<5, 2><<<NDWBLK, 256, 0, stream>>>(y0, bnp, dw1, yt);
    pw_kernel<<<NBLK, 256, 0, stream>>>(pw1_w, pw1_b, yt, y1, partials);
    bnfin_kernel<<<64, 256, 0, stream>>>(partials, bn1_g, bn1_b, bnp + 128);

    dw_kernel<7, 4><<<NDWBLK, 256, 0, stream>>>(y1, bnp + 128, dw2, yt);
    pw_kernel<<<NBLK, 256, 0, stream>>>(pw2_w, pw2_b, yt, y2, partials);
    bnfin_kernel<<<64, 256, 0, stream>>>(partials, bn2_g, bn2_b, bnp + 256);

    kglobal_kernel<<<512, 256, 0, stream>>>(y2, bnp + 256, kg);
    final_kernel<<<NBLK, 256, 0, stream>>>(x, w_in, b_in, y0, y1, y2, bnp, kg,
                                           val_w, val_b, out_w, out_b, coeffs, outp);
}